// Round 11
// baseline (388.225 us; speedup 1.0000x reference)
//
#include <hip/hip_runtime.h>
#include <stdint.h>

// Problem constants (fixed by setup_inputs)
#define B_ 4
#define L_ 4096
#define DM 1024
#define H_ 16
#define D_ 64
#define BH (B_*H_)      // 64
#define N_ (B_*L_)      // 16384
#define CS 128          // chunk size for causal attention
#define NC (L_/CS)      // 32
#define SC 64           // chunk size for normalizer scans
#define NSC (L_/SC)     // 64
#define EPSF 1e-6f

typedef unsigned short u16;
typedef unsigned int   u32;
typedef __attribute__((ext_vector_type(8))) short s16x8;
typedef __attribute__((ext_vector_type(4))) float f32x4;

__device__ __forceinline__ float bf2f(u16 u){
  union { u32 i; float f; } v; v.i = ((u32)u) << 16; return v.f;
}
__device__ __forceinline__ u16 f2bf(float f){
  union { float f; u32 i; } v; v.f = f;
  u32 i = v.i;
  return (u16)((i + 0x7fffu + ((i >> 16) & 1u)) >> 16);  // RNE
}
__device__ __forceinline__ void gload16(const void* g, void* l){
  __builtin_amdgcn_global_load_lds(
      (const __attribute__((address_space(1))) u32*)g,
      (__attribute__((address_space(3))) u32*)l, 16, 0, 0);
}
__device__ __forceinline__ f32x4 mfma16(s16x8 a, s16x8 b, f32x4 c){
  return __builtin_amdgcn_mfma_f32_16x16x32_bf16(a, b, c, 0, 0, 0);
}
__device__ __forceinline__ float sigmoidf_(float x){ return 1.0f/(1.0f+__expf(-x)); }

// ---------------- fp32 -> bf16 convert ----------------
__global__ void cvt_kernel(const float* __restrict__ in, u16* __restrict__ out, int n4){
  int i = blockIdx.x * blockDim.x + threadIdx.x;
  if (i >= n4) return;
  float4 v = ((const float4*)in)[i];
  union { u16 s[4]; uint2 u; } o;
  o.s[0]=f2bf(v.x); o.s[1]=f2bf(v.y); o.s[2]=f2bf(v.z); o.s[3]=f2bf(v.w);
  ((uint2*)out)[i] = o.u;
}

// ---------------- 4x W [K][N] fp32 -> WT [N][K] bf16 (one launch) ----------------
__global__ __launch_bounds__(256) void transpose_w4_kernel(
    const float* __restrict__ Wq, const float* __restrict__ Wk,
    const float* __restrict__ Wv, const float* __restrict__ Wo,
    u16* __restrict__ wqkvT, u16* __restrict__ woT){
  __shared__ float t[64][65];
  int z = blockIdx.z;
  const float* W = (z==0) ? Wq : (z==1) ? Wk : (z==2) ? Wv : Wo;
  u16* WT = (z<3) ? (wqkvT + (size_t)z*DM*DM) : woT;
  int n0 = blockIdx.x * 64, k0 = blockIdx.y * 64;
  int tx = threadIdx.x & 63, ty = threadIdx.x >> 6;
  #pragma unroll
  for (int s = 0; s < 64; s += 4)
    t[ty + s][tx] = W[(size_t)(k0 + ty + s) * DM + n0 + tx];
  __syncthreads();
  #pragma unroll
  for (int s = 0; s < 64; s += 4)
    WT[(size_t)(n0 + ty + s) * DM + k0 + tx] = f2bf(t[tx][ty + s]);
}

// ---------------- 128x128 m97-structure MFMA GEMM (K=1024), conflict-free LDS ----------------
// 4 waves (2x2), BK=32, single-buffered 16KB LDS -> high occupancy (TLP hides the
// barrier drain; guide m103: 128-tile 912 TF > 256-tile 792 at this structure).
// Both-sides XOR swizzle: physical K-chunk = logical ^ ((row>>1)&3) — staged via
// pre-swizzled GLOBAL source (linear gload_lds dest), read via swizzled offset.
// Residual 2-way conflict is free (m136). R2's unswizzled version: 8-way, 505 TF.
template<int QKV>
__global__ __launch_bounds__(256) void gemm128_kernel(
    const u16* __restrict__ A, const u16* __restrict__ BT,
    const float* __restrict__ biasq, const float* __restrict__ biask, const float* __restrict__ biasv,
    u16* __restrict__ oq, u16* __restrict__ ok, u16* __restrict__ ov,
    float* __restrict__ outf,
    float* __restrict__ sumQ, float* __restrict__ sumK, int NBY)
{
  __shared__ __align__(16) u16 As[128*32];
  __shared__ __align__(16) u16 Bs[128*32];
  int tid = threadIdx.x;
  int wave = tid >> 6, lane = tid & 63;
  int wr = wave >> 1, wc = wave & 1;          // 2x2 wave grid
  // XCD-bijective block swizzle (nwg % 8 == 0: 3072 and 1024)
  int nwg = gridDim.x, q8 = nwg >> 3, id = blockIdx.x;
  int id2 = (id & 7) * q8 + (id >> 3);
  int bx = id2 / NBY, by = id2 % NBY;
  int m0 = bx * 128, n0 = by * 128;
  // staging: thread t covers row r0 = t>>2 (64 rows/pass, 2 passes), physical
  // chunk t&3; source chunk pre-swizzled so LDS[r][p] = logical p^((r>>1)&3).
  // ((r0+64)>>1)&3 == (r0>>1)&3, so both passes share srcq.
  int r0 = tid >> 2;
  int srcq = (tid & 3) ^ ((tid >> 3) & 3);
  const u16* aptr0 = A  + (size_t)(m0 + r0)      * 1024 + srcq * 8;
  const u16* aptr1 = A  + (size_t)(m0 + 64 + r0) * 1024 + srcq * 8;
  const u16* bptr0 = BT + (size_t)(n0 + r0)      * 1024 + srcq * 8;
  const u16* bptr1 = BT + (size_t)(n0 + 64 + r0) * 1024 + srcq * 8;
  u16* asd0 = &As[tid*8]; u16* asd1 = &As[2048 + tid*8];
  u16* bsd0 = &Bs[tid*8]; u16* bsd1 = &Bs[2048 + tid*8];

  f32x4 acc[4][4];
  #pragma unroll
  for (int i=0;i<4;i++)
    #pragma unroll
    for (int j=0;j<4;j++) acc[i][j] = (f32x4){0.f,0.f,0.f,0.f};

  int fr = lane & 15, q = lane >> 4;
  // logical chunk q lives at physical q ^ ((row>>1)&3); (row>>1)&3 == (fr>>1)&3
  // for row = {wr,wc}*64 + mi*16 + fr  (64 and 16 are ≡0 mod 4 after >>1... 16>>1=8≡0 mod 4)
  int csw = (q ^ ((fr >> 1) & 3)) << 4;       // byte offset of 16B chunk
  int abase = (wr*64 + fr) * 64 + csw;        // + mi*1024
  int bbase = (wc*64 + fr) * 64 + csw;        // + ni*1024

  for (int kb = 0; kb < 32; kb++){
    __syncthreads();
    gload16(aptr0, asd0); gload16(aptr1, asd1);
    gload16(bptr0, bsd0); gload16(bptr1, bsd1);
    aptr0 += 32; aptr1 += 32; bptr0 += 32; bptr1 += 32;
    __syncthreads();
    s16x8 af[4], bfr[4];
    #pragma unroll
    for (int mi=0;mi<4;mi++) af[mi]  = *(const s16x8*)((const char*)As + abase + mi*1024);
    #pragma unroll
    for (int ni=0;ni<4;ni++) bfr[ni] = *(const s16x8*)((const char*)Bs + bbase + ni*1024);
    #pragma unroll
    for (int mi=0;mi<4;mi++)
      #pragma unroll
      for (int ni=0;ni<4;ni++)
        acc[mi][ni] = mfma16(af[mi], bfr[ni], acc[mi][ni]);
  }

  // epilogue
  int colblk = n0 + wc*64;                        // 64-aligned
  int which  = QKV ? (colblk >> 10) : 0;          // 0=q 1=k 2=v
  int cl0    = QKV ? (colblk & 1023) : colblk;
  const float* bias = QKV ? (which==0 ? biasq : (which==1 ? biask : biasv)) : biasq;
  u16* outp = QKV ? (which==0 ? oq : (which==1 ? ok : ov)) : (u16*)0;
  float csum[4] = {0.f,0.f,0.f,0.f};
  #pragma unroll
  for (int mi = 0; mi < 4; mi++){
    int row = m0 + wr*64 + mi*16 + (lane>>4)*4;
    #pragma unroll
    for (int ni = 0; ni < 4; ni++){
      int cl = cl0 + ni*16 + fr;
      float bv = bias[cl];
      #pragma unroll
      for (int r = 0; r < 4; r++){
        float val = acc[mi][ni][r] + bv;
        if (QKV){
          if (which < 2) val = sigmoidf_(val);
          outp[(size_t)(row + r) * 1024 + cl] = f2bf(val);
          if (which < 2) csum[ni] += val;
        } else {
          outf[(size_t)(row + r) * 1024 + cl] = val;
        }
      }
    }
  }
  if (QKV && which < 2){
    float* sums = (which==0) ? sumQ : sumK;
    int bh = (m0 >> 12) * H_ + ((colblk & 1023) >> 6);
    int sc = ((m0 & 4095) >> 6) + wr;   // 64-row scan chunk of this wave
    #pragma unroll
    for (int ni = 0; ni < 4; ni++){
      float s = csum[ni];
      s += __shfl_xor(s, 16);
      s += __shfl_xor(s, 32);
      if (lane < 16) sums[((size_t)bh*NSC + sc)*64 + ni*16 + fr] = s;
    }
  }
}

// ---------------- exclusive scan over scan-chunk axis (2 arrays, in place) ----------------
// Register-group scan: 64 serial dependent latencies -> 4.
__global__ __launch_bounds__(64) void scan2_kernel(float* __restrict__ A, float* __restrict__ Bv){
  int bh = blockIdx.x, d = threadIdx.x;
  float ra = 0.f, rb = 0.f;
  for (int g = 0; g < NSC; g += 16){
    float ta[16], tb[16];
    #pragma unroll
    for (int j = 0; j < 16; j++){
      size_t o = ((size_t)bh * NSC + g + j) * 64 + d;
      ta[j] = A[o]; tb[j] = Bv[o];
    }
    #pragma unroll
    for (int j = 0; j < 16; j++){
      size_t o = ((size_t)bh * NSC + g + j) * 64 + d;
      A[o] = ra; Bv[o] = rb;
      ra += ta[j]; rb += tb[j];
    }
  }
}

// ---------------- fused sink_incoming/source_outgoing + mod chunk sums ----------------
// bf16 LDS cumsums for occupancy (R9, measured good). P3 reads q/k rows back
// from LDS (written from P2's registers) instead of a third global pass.
__global__ __launch_bounds__(64) void siso_fused_kernel(
    const u16* __restrict__ q, const u16* __restrict__ k,
    const float* __restrict__ sumQx, const float* __restrict__ sumKx,
    float* __restrict__ si, float* __restrict__ so,
    float* __restrict__ sumQsi, float* __restrict__ sumKso)
{
  __shared__ u16 cq[64*64];
  __shared__ u16 ck[64*64];
  __shared__ float siv[64], sov[64];
  int bhc = blockIdx.x; int bh = bhc >> 6, sc = bhc & 63;
  int b = bh >> 4, h = bh & 15;
  int lane = threadIdx.x;
  size_t gbase = ((size_t)(b*L_ + sc*SC))*DM + h*D_;
  size_t lb = (size_t)bh*L_ + sc*SC;
  {
    float runQ = sumQx[bhc*64 + lane];
    float runK = sumKx[bhc*64 + lane];
    for (int l = 0; l < SC; l++){
      runQ += bf2f(q[gbase + (size_t)l*DM + lane]);
      runK += bf2f(k[gbase + (size_t)l*DM + lane]);
      int sw = lane ^ (l & 31);
      cq[l*64 + sw] = f2bf(runQ);
      ck[l*64 + sw] = f2bf(runK);
    }
  }
  __syncthreads();
  {
    int l = lane;
    const u16* qrow = q + gbase + (size_t)l*DM;
    const u16* krow = k + gbase + (size_t)l*DM;
    uint4 qr[8], kr[8];
    #pragma unroll
    for (int j=0;j<8;j++){ qr[j]=((const uint4*)qrow)[j]; kr[j]=((const uint4*)krow)[j]; }
    const u16* qp = (const u16*)qr; const u16* kp = (const u16*)kr;
    float a = 0.f, b2 = 0.f;
    #pragma unroll
    for (int d = 0; d < 64; d++){
      int sw = d ^ (l & 31);
      a  += (bf2f(qp[d])+EPSF) * (bf2f(ck[l*64+sw])+EPSF);
      b2 += (bf2f(kp[d])+EPSF) * (bf2f(cq[l*64+sw])+EPSF);
    }
    float n = (float)(sc*SC + l + 1);
    float vsi = n/a, vso = n/b2;
    si[lb+l] = vsi; so[lb+l] = vso;
    siv[l] = vsi;   sov[l] = vso;
    // cumsums dead; recycle cq/ck as row scratch for P3 (same swizzle)
    __syncthreads();
    #pragma unroll
    for (int d = 0; d < 64; d++){
      int sw = d ^ (l & 31);
      cq[l*64 + sw] = qp[d];
      ck[l*64 + sw] = kp[d];
    }
  }
  __syncthreads();
  {
    float sq = 0.f, sk = 0.f;
    for (int l = 0; l < SC; l++){
      int sw = lane ^ (l & 31);
      sq += bf2f(cq[l*64 + sw]) * siv[l];
      sk += bf2f(ck[l*64 + sw]) * sov[l];
    }
    sumQsi[bhc*64 + lane] = sq;
    sumKso[bhc*64 + lane] = sk;
  }
}

// ---------------- fused conserved_sink/source -> sall, csrc + exp chunk sums ----------------
__global__ __launch_bounds__(64) void cons_fused_kernel(
    const u16* __restrict__ q, const u16* __restrict__ k,
    const float* __restrict__ si, const float* __restrict__ so,
    const float* __restrict__ sumQsiX, const float* __restrict__ sumKsoX,
    float* __restrict__ csrc, float* __restrict__ sall, float* __restrict__ csSum)
{
  __shared__ u16 cq[64*64];
  __shared__ u16 ck[64*64];
  __shared__ float siv[64], sov[64];
  int bhc = blockIdx.x; int bh = bhc >> 6, sc = bhc & 63;
  int b = bh >> 4, h = bh & 15;
  int lane = threadIdx.x;
  size_t gbase = ((size_t)(b*L_ + sc*SC))*DM + h*D_;
  size_t lb = (size_t)bh*L_ + sc*SC;
  siv[lane] = si[lb + lane];
  sov[lane] = so[lb + lane];
  __syncthreads();
  {
    float runQ = sumQsiX[bhc*64 + lane];
    float runK = sumKsoX[bhc*64 + lane];
    for (int l = 0; l < SC; l++){
      runQ += bf2f(q[gbase + (size_t)l*DM + lane]) * siv[l];
      runK += bf2f(k[gbase + (size_t)l*DM + lane]) * sov[l];
      int sw = lane ^ (l & 31);
      cq[l*64 + sw] = f2bf(runQ);
      ck[l*64 + sw] = f2bf(runK);
    }
  }
  __syncthreads();
  {
    int l = lane;
    const u16* qrow = q + gbase + (size_t)l*DM;
    const u16* krow = k + gbase + (size_t)l*DM;
    uint4 qr[8], kr[8];
    #pragma unroll
    for (int j=0;j<8;j++){ qr[j]=((const uint4*)qrow)[j]; kr[j]=((const uint4*)krow)[j]; }
    const u16* qp = (const u16*)qr; const u16* kp = (const u16*)kr;
    float a = 0.f, b2 = 0.f;
    #pragma unroll
    for (int d = 0; d < 64; d++){
      int sw = d ^ (l & 31);
      a  += (bf2f(qp[d])+EPSF) * (bf2f(ck[l*64+sw])+EPSF);
      b2 += (bf2f(kp[d])+EPSF) * (bf2f(cq[l*64+sw])+EPSF);
    }
    float inv = 1.0f / (float)(sc*SC + l + 1);
    sall[lb+l] = sigmoidf_(a * inv);
    float cs = b2 * inv;
    csrc[lb+l] = cs;
    float e = __expf(cs);
    #pragma unroll
    for (int off = 32; off > 0; off >>= 1) e += __shfl_xor(e, off);
    if (lane == 0) csSum[bhc] = e;
  }
}

// ---------------- source_competition (csOff via wave-parallel reduce of csSum) ----------------
__global__ __launch_bounds__(64) void scomp_kernel(
    const float* __restrict__ csrc, const float* __restrict__ csSum,
    float* __restrict__ scomp){
  int bhc = blockIdx.x; int bh = bhc >> 6, sc = bhc & 63;
  int lane = threadIdx.x;
  float v2 = (lane < sc) ? csSum[bh*NSC + lane] : 0.f;
  #pragma unroll
  for (int o = 32; o > 0; o >>= 1) v2 += __shfl_xor(v2, o);
  float off = v2;
  size_t idx = (size_t)bh * L_ + sc * SC + lane;
  float cs = __expf(csrc[idx]);
  float run = cs;
  #pragma unroll
  for (int o = 1; o < 64; o <<= 1){
    float t = __shfl_up(run, o);
    if (lane >= o) run += t;
  }
  scomp[idx] = cs / (off + run) * (float)(sc*SC + lane + 1);
}

// ---------------- per-chunk VK sums: VK[m][d] = sum_l v[l][m]*scomp[l]*k[l][d] ----------------
__global__ __launch_bounds__(256) void vk_chunk_kernel(
    const u16* __restrict__ k, const u16* __restrict__ v,
    const float* __restrict__ scomp, float* __restrict__ vkc){
  __shared__ float ks[32][64];
  __shared__ float vs[32][64];
  int bhc = blockIdx.x; int bh = bhc >> 5, c = bhc & 31;
  int b = bh >> 4, h = bh & 15;
  int tid = threadIdx.x;
  int m = tid >> 2, d0 = (tid & 3) * 16;
  float acc[16];
  #pragma unroll
  for (int j = 0; j < 16; j++) acc[j] = 0.f;
  size_t gbase = ((size_t)(b * L_ + c * CS)) * DM + h * D_;
  size_t sbase = (size_t)bh * L_ + c * CS;
  int r = tid >> 3, cc = (tid & 7) * 8;
  for (int s0 = 0; s0 < CS; s0 += 32){
    __syncthreads();
    float sc = scomp[sbase + s0 + r];
    uint4 ku = *(const uint4*)(k + gbase + (size_t)(s0 + r) * DM + cc);
    uint4 vu = *(const uint4*)(v + gbase + (size_t)(s0 + r) * DM + cc);
    const u16* kp = (const u16*)&ku; const u16* vp = (const u16*)&vu;
    #pragma unroll
    for (int j = 0; j < 8; j++){
      ks[r][cc + j] = bf2f(kp[j]);
      vs[r][cc + j] = bf2f(vp[j]) * sc;
    }
    __syncthreads();
    #pragma unroll
    for (int i = 0; i < 32; i++){
      float vm = vs[i][m];
      #pragma unroll
      for (int j4 = 0; j4 < 4; j4++){
        float4 kk = *(const float4*)&ks[i][d0 + j4*4];
        acc[j4*4+0] += vm * kk.x; acc[j4*4+1] += vm * kk.y;
        acc[j4*4+2] += vm * kk.z; acc[j4*4+3] += vm * kk.w;
      }
    }
  }
  float* outp = vkc + (size_t)bhc * (D_*D_) + m * D_ + d0;
  #pragma unroll
  for (int j = 0; j < 16; j++) outp[j] = acc[j];
}

// ---------------- exclusive scan of VK over chunks (in place) ----------------
// Register-group scan (16 at a time): 32 serial latencies -> 2.
__global__ __launch_bounds__(256) void vk_scan_kernel(float* __restrict__ vkc){
  int idx = blockIdx.x * 256 + threadIdx.x;   // over BH*4096
  int bh = idx >> 12;
  int e  = idx & 4095;
  size_t base = ((size_t)bh * NC) * 4096 + e;
  float run = 0.f;
  for (int g = 0; g < NC; g += 16){
    float tv[16];
    #pragma unroll
    for (int j = 0; j < 16; j++) tv[j] = vkc[base + (size_t)(g + j) * 4096];
    #pragma unroll
    for (int j = 0; j < 16; j++){
      vkc[base + (size_t)(g + j) * 4096] = run;
      run += tv[j];
    }
  }
}

// ---------------- causal attention per (bh, chunk) ----------------
// 64-wide masked-S strips (R10, measured good): 4 barriers, LDS 72KB, 2 blocks/CU.
__global__ __launch_bounds__(256) void attn_kernel(
    const u16* __restrict__ q, const u16* __restrict__ k, const u16* __restrict__ v,
    const float* __restrict__ si, const float* __restrict__ scomp, const float* __restrict__ salloc,
    const float* __restrict__ vkc, u16* __restrict__ attnout)
{
  __shared__ __align__(16) u16 qs[128*64];    // qmod rows [l][d]
  __shared__ __align__(16) u16 ks2[128*64];   // k rows    [j][d]
  __shared__ __align__(16) u16 vts[64*128];   // (v*scomp)^T [m][j]
  __shared__ __align__(16) u16 vks[64*64];    // VKprev [m][d]
  __shared__ __align__(16) u16 ss[128*64];    // masked S half [l][j-in-64]
  int bhc = blockIdx.x; int bh = bhc >> 5, c = bhc & 31;
  int b = bh >> 4, h = bh & 15;
  int tid = threadIdx.x, wave = tid >> 6, lane = tid & 63;
  size_t gbase = ((size_t)(b * L_ + c * CS)) * DM + h * D_;
  size_t sbase = (size_t)bh * L_ + c * CS;
  {
    int r = tid >> 1;
    int cc = (tid & 1) * 32;
    int l = c * CS + r;
    float qscale = si[sbase + r] / (float)(l + 1);
    float vscale = scomp[sbase + r];
    #pragma unroll
    for (int j = 0; j < 4; j++){
      uint4 qu = *(const uint4*)(q + gbase + (size_t)r * DM + cc + j*8);
      uint4 kuv = *(const uint4*)(k + gbase + (size_t)r * DM + cc + j*8);
      uint4 vu = *(const uint4*)(v + gbase + (size_t)r * DM + cc + j*8);
      const u16* qp = (const u16*)&qu; const u16* vp = (const u16*)&vu;
      u16 tmp[8];
      #pragma unroll
      for (int e = 0; e < 8; e++) tmp[e] = f2bf(bf2f(qp[e]) * qscale);
      *(uint4*)&qs[r*64 + cc + j*8] = *(uint4*)tmp;
      *(uint4*)&ks2[r*64 + cc + j*8] = kuv;
      #pragma unroll
      for (int e = 0; e < 8; e++) vts[(cc + j*8 + e)*128 + r] = f2bf(bf2f(vp[e]) * vscale);
    }
    const float* vkp = vkc + (size_t)bhc * (D_*D_) + tid * 16;
    u16 tv[16];
    #pragma unroll
    for (int e = 0; e < 16; e++) tv[e] = f2bf(vkp[e]);
    *(uint4*)&vks[tid*16]   = *(uint4*)&tv[0];
    *(uint4*)&vks[tid*16+8] = *(uint4*)&tv[8];
  }
  __syncthreads();
  int t0 = wave, t1 = 7 - wave;   // balanced l-tile pair per wave
  int fr = lane & 15, kg = (lane >> 4) * 8;
  f32x4 acc[2][4];
  #pragma unroll
  for (int i=0;i<2;i++)
    #pragma unroll
    for (int j=0;j<4;j++) acc[i][j] = (f32x4){0.f,0.f,0.f,0.f};
  s16x8 aq[2][2];
  #pragma unroll
  for (int ti = 0; ti < 2; ti++){
    int t = ti ? t1 : t0;
    #pragma unroll
    for (int kk = 0; kk < 2; kk++)
      aq[ti][kk] = *(const s16x8*)&qs[(t*16 + fr)*64 + kk*32 + kg];
  }
  // inter-chunk: qmod @ VKprev^T
  #pragma unroll
  for (int mt = 0; mt < 4; mt++){
    #pragma unroll
    for (int kk = 0; kk < 2; kk++){
      s16x8 bv = *(const s16x8*)&vks[(mt*16 + fr)*64 + kk*32 + kg];
      acc[0][mt] = mfma16(aq[0][kk], bv, acc[0][mt]);
      acc[1][mt] = mfma16(aq[1][kk], bv, acc[1][mt]);
    }
  }
  // intra-chunk, two 64-j halves
  for (int jt2 = 0; jt2 < 2; jt2++){
    __syncthreads();
    #pragma unroll
    for (int ti = 0; ti < 2; ti++){
      int t = ti ? t1 : t0;
      #pragma unroll
      for (int u = 0; u < 4; u++){
        int jj = jt2*4 + u;
        f32x4 sacc = (f32x4){0.f,0.f,0.f,0.f};
        if (jj <= t){
          #pragma unroll
          for (int kk = 0; kk < 2; kk++){
            s16x8 bkf = *(const s16x8*)&ks2[(jj*16 + fr)*64 + kk*32 + kg];
            sacc = mfma16(aq[ti][kk], bkf, sacc);
          }
        }
        int lrow = t*16 + (lane>>4)*4;
        int jcol = jj*16 + fr;
        #pragma unroll
        for (int r = 0; r < 4; r++){
          float sv = (jcol <= lrow + r) ? sacc[r] : 0.f;
          ss[(lrow + r)*64 + u*16 + fr] = f2bf(sv);
        }
      }
    }
    __syncthreads();
    #pragma unroll
    for (int ti = 0; ti < 2; ti++){
      int t = ti ? t1 : t0;
      #pragma unroll
      for (int ks = 0; ks < 2; ks++){
        if (jt2*64 + ks*32 <= t*16 + 15){
          s16x8 as = *(const s16x8*)&ss[(t*16 + fr)*64 + ks*32 + kg];
          #pragma unroll
          for (int mt = 0; mt < 4; mt++){
            s16x8 bvv = *(const s16x8*)&vts[(mt*16 + fr)*128 + jt2*64 + ks*32 + kg];
            acc[ti][mt] = mfma16(as, bvv, acc[ti][mt]);
          }
        }
      }
    }
  }
  // epilogue: * sink_allocation, write bf16 [B,L,DM]
  #pragma unroll
  for (int ti = 0; ti < 2; ti++){
    int t = ti ? t1 : t0;
    int lrow = t*16 + (lane>>4)*4;
    #pragma unroll
    for (int r = 0; r < 4; r++){
      float sa = salloc[sbase + lrow + r];
      size_t orow = ((size_t)(b * L_ + c * CS + lrow + r)) * DM + h * D_;
      #pragma unroll
      for (int mt = 0; mt < 4; mt++){
        attnout[orow + mt*16 + fr] = f2bf(acc[ti][mt][r] * sa);
      }
    }
  }
}

extern "C" void kernel_launch(void* const* d_in, const int* in_sizes, int n_in,
                              void* d_out, int out_size, void* d_ws, size_t ws_size,
                              hipStream_t stream){
  (void)in_sizes; (void)n_in; (void)out_size; (void)ws_size;
  const float* x  = (const float*)d_in[0];
  const float* Wq = (const float*)d_in[1];
  const float* bq = (const float*)d_in[2];
  const float* Wk = (const float*)d_in[3];
  const float* bk = (const float*)d_in[4];
  const float* Wv = (const float*)d_in[5];
  const float* bv = (const float*)d_in[6];
  const float* Wo = (const float*)d_in[7];
  const float* bo = (const float*)d_in[8];

  char* p = (char*)d_ws;
  auto carve = [&](size_t bytes) -> void* {
    void* r = (void*)p; p += (bytes + 255) & ~(size_t)255; return r;
  };
  u16* xb    = (u16*)carve((size_t)N_*DM*2);
  u16* wqkvT = (u16*)carve((size_t)3*DM*DM*2);
  u16* woT   = (u16*)carve((size_t)DM*DM*2);
  u16* qb  = (u16*)carve((size_t)N_*DM*2);
  u16* kb  = (u16*)carve((size_t)N_*DM*2);
  u16* vb  = (u16*)carve((size_t)N_*DM*2);
  u16* ao  = (u16*)carve((size_t)N_*DM*2);
  float* si   = (float*)carve((size_t)BH*L_*4);
  float* so   = (float*)carve((size_t)BH*L_*4);
  float* csrc = (float*)carve((size_t)BH*L_*4);
  float* sall = (float*)carve((size_t)BH*L_*4);
  float* scmp = (float*)carve((size_t)BH*L_*4);
  float* sumQ   = (float*)carve((size_t)BH*NSC*D_*4);
  float* sumK   = (float*)carve((size_t)BH*NSC*D_*4);
  float* sumQsi = (float*)carve((size_t)BH*NSC*D_*4);
  float* sumKso = (float*)carve((size_t)BH*NSC*D_*4);
  float* csSum  = (float*)carve((size_t)BH*NSC*4);
  float* vkc    = (float*)carve((size_t)BH*NC*(size_t)(D_*D_)*4);

  // 1. conversions
  cvt_kernel<<<(N_*DM/4 + 255)/256, 256, 0, stream>>>(x, xb, N_*DM/4);
  transpose_w4_kernel<<<dim3(DM/64, DM/64, 4), 256, 0, stream>>>(Wq, Wk, Wv, Wo, wqkvT, woT);
  // 2. fused q,k,v projection (one 16384x3072x1024 GEMM) + per-scan-chunk sums
  gemm128_kernel<1><<<dim3((N_/128)*(3*DM/128)), 256, 0, stream>>>(
      xb, wqkvT, bq, bk, bv, qb, kb, vb, nullptr, sumQ, sumK, 3*DM/128);
  // 3. normalizer pipeline
  scan2_kernel<<<BH, 64, 0, stream>>>(sumQ, sumK);
  siso_fused_kernel<<<BH*NSC, 64, 0, stream>>>(qb, kb, sumQ, sumK, si, so, sumQsi, sumKso);
  scan2_kernel<<<BH, 64, 0, stream>>>(sumQsi, sumKso);
  cons_fused_kernel<<<BH*NSC, 64, 0, stream>>>(qb, kb, si, so, sumQsi, sumKso, csrc, sall, csSum);
  scomp_kernel<<<BH*NSC, 64, 0, stream>>>(csrc, csSum, scmp);
  // 4. causal linear attention
  vk_chunk_kernel<<<BH*NC, 256, 0, stream>>>(kb, vb, scmp, vkc);
  vk_scan_kernel<<<(BH*D_*D_)/256, 256, 0, stream>>>(vkc);
  attn_kernel<<<BH*NC, 256, 0, stream>>>(qb, kb, vb, si, scmp, sall, vkc, ao);
  // 5. output projection
  gemm128_kernel<0><<<dim3((N_/128)*(DM/128)), 256, 0, stream>>>(
      ao, woT, bo, bo, bo, nullptr, nullptr, nullptr, (float*)d_out, nullptr, nullptr, DM/128);
}

// Round 12
// 337.603 us; speedup vs baseline: 1.1499x; 1.1499x over previous
//
#include <hip/hip_runtime.h>
#include <stdint.h>

// Problem constants (fixed by setup_inputs)
#define B_ 4
#define L_ 4096
#define DM 1024
#define H_ 16
#define D_ 64
#define BH (B_*H_)      // 64
#define N_ (B_*L_)      // 16384
#define CS 128          // chunk size for causal attention
#define NC (L_/CS)      // 32
#define SC 64           // chunk size for normalizer scans
#define NSC (L_/SC)     // 64
#define EPSF 1e-6f

typedef unsigned short u16;
typedef unsigned int   u32;
typedef __attribute__((ext_vector_type(8))) short s16x8;
typedef __attribute__((ext_vector_type(4))) float f32x4;

__device__ __forceinline__ float bf2f(u16 u){
  union { u32 i; float f; } v; v.i = ((u32)u) << 16; return v.f;
}
__device__ __forceinline__ u16 f2bf(float f){
  union { float f; u32 i; } v; v.f = f;
  u32 i = v.i;
  return (u16)((i + 0x7fffu + ((i >> 16) & 1u)) >> 16);  // RNE
}
__device__ __forceinline__ void gload16(const void* g, void* l){
  __builtin_amdgcn_global_load_lds(
      (const __attribute__((address_space(1))) u32*)g,
      (__attribute__((address_space(3))) u32*)l, 16, 0, 0);
}
__device__ __forceinline__ f32x4 mfma16(s16x8 a, s16x8 b, f32x4 c){
  return __builtin_amdgcn_mfma_f32_16x16x32_bf16(a, b, c, 0, 0, 0);
}
__device__ __forceinline__ float sigmoidf_(float x){ return 1.0f/(1.0f+__expf(-x)); }

// ---------------- fp32 -> bf16 convert ----------------
__global__ void cvt_kernel(const float* __restrict__ in, u16* __restrict__ out, int n4){
  int i = blockIdx.x * blockDim.x + threadIdx.x;
  if (i >= n4) return;
  float4 v = ((const float4*)in)[i];
  union { u16 s[4]; uint2 u; } o;
  o.s[0]=f2bf(v.x); o.s[1]=f2bf(v.y); o.s[2]=f2bf(v.z); o.s[3]=f2bf(v.w);
  ((uint2*)out)[i] = o.u;
}

// ---------------- 4x W [K][N] fp32 -> WT [N][K] bf16 (one launch) ----------------
__global__ __launch_bounds__(256) void transpose_w4_kernel(
    const float* __restrict__ Wq, const float* __restrict__ Wk,
    const float* __restrict__ Wv, const float* __restrict__ Wo,
    u16* __restrict__ wqkvT, u16* __restrict__ woT){
  __shared__ float t[64][65];
  int z = blockIdx.z;
  const float* W = (z==0) ? Wq : (z==1) ? Wk : (z==2) ? Wv : Wo;
  u16* WT = (z<3) ? (wqkvT + (size_t)z*DM*DM) : woT;
  int n0 = blockIdx.x * 64, k0 = blockIdx.y * 64;
  int tx = threadIdx.x & 63, ty = threadIdx.x >> 6;
  #pragma unroll
  for (int s = 0; s < 64; s += 4)
    t[ty + s][tx] = W[(size_t)(k0 + ty + s) * DM + n0 + tx];
  __syncthreads();
  #pragma unroll
  for (int s = 0; s < 64; s += 4)
    WT[(size_t)(n0 + ty + s) * DM + k0 + tx] = f2bf(t[tx][ty + s]);
}

// ---------------- 256x256 counted-vmcnt MFMA GEMM (K=1024 fixed) — R3/R10 structure ----------------
// Measured-best: 133.6-134.2 us (QKV), MfmaUtil ~32.5%, 0 bank conflicts.
// Parked: 8-phase (R4/R5 null) and 128^2 (R11: occupancy 31% but 145 us) both failed to beat it.
template<int QKV>
__global__ __launch_bounds__(512, 2) void gemm256_kernel(
    const u16* __restrict__ A, const u16* __restrict__ BT,
    const float* __restrict__ biasq, const float* __restrict__ biask, const float* __restrict__ biasv,
    u16* __restrict__ oq, u16* __restrict__ ok, u16* __restrict__ ov,
    float* __restrict__ outf,
    float* __restrict__ sumQ, float* __restrict__ sumK, int NBY)
{
  // LDS: A slot0 [0,32K), A slot1 [32K,64K), B slot0 [64K,96K), B slot1 [96K,128K)
  __shared__ __align__(16) u16 smem[65536];
  char* smb = (char*)smem;
  int tid = threadIdx.x;
  int wave = tid >> 6, lane = tid & 63;
  int wm = wave >> 2, wn = wave & 3;          // 2 x 4 wave grid
  int nwg = gridDim.x;
  int q8 = nwg >> 3;
  int id = blockIdx.x;
  int id2 = (id & 7) * q8 + (id >> 3);
  int bx = id2 / NBY, by = id2 % NBY;
  int m0 = bx * 256, n0 = by * 256;
  int srcq = (tid & 7) ^ ((tid >> 3) & 7);
  const u16* aRow = A  + (size_t)(m0 + (tid >> 3)) * 1024 + srcq * 8;
  const u16* bRow = BT + (size_t)(n0 + (tid >> 3)) * 1024 + srcq * 8;

  f32x4 acc[8][4];
  #pragma unroll
  for (int i=0;i<8;i++)
    #pragma unroll
    for (int j=0;j<4;j++) acc[i][j] = (f32x4){0.f,0.f,0.f,0.f};

  int fr = lane & 15, q = lane >> 4;
  int aoff0 = fr*128 + (((q ^ (lane&3)) + 4*((lane>>2)&1)) << 4);
  int aoff1 = fr*128 + (((q ^ (lane&3)) + 4*(1 ^ ((lane>>2)&1))) << 4);

  #define STAGE(s, t) { \
    _Pragma("unroll") \
    for (int i_ = 0; i_ < 4; i_++){ \
      gload16(aRow + (size_t)(t)*64 + (size_t)i_*65536, smb + (s)*32768 + i_*8192 + tid*16); \
      gload16(bRow + (size_t)(t)*64 + (size_t)i_*65536, smb + 65536 + (s)*32768 + i_*8192 + tid*16); \
    } }

  #define COMPUTE(s) { \
    const char* Ab_ = smb + (s)*32768 + wm*16384; \
    const char* Bb_ = smb + 65536 + (s)*32768 + wn*8192; \
    _Pragma("unroll") \
    for (int kk_ = 0; kk_ < 2; kk_++){ \
      int off_ = kk_ ? aoff1 : aoff0; \
      s16x8 af_[8], bf_[4]; \
      _Pragma("unroll") \
      for (int mi_ = 0; mi_ < 8; mi_++) af_[mi_] = *(const s16x8*)(Ab_ + mi_*2048 + off_); \
      _Pragma("unroll") \
      for (int ni_ = 0; ni_ < 4; ni_++) bf_[ni_] = *(const s16x8*)(Bb_ + ni_*2048 + off_); \
      _Pragma("unroll") \
      for (int mi_ = 0; mi_ < 8; mi_++) \
        _Pragma("unroll") \
        for (int ni_ = 0; ni_ < 4; ni_++) \
          acc[mi_][ni_] = mfma16(af_[mi_], bf_[ni_], acc[mi_][ni_]); \
    } }

  STAGE(0, 0)
  STAGE(1, 1)
  for (int t = 0; t < 14; t++){
    asm volatile("s_waitcnt vmcnt(8)" ::: "memory");
    __builtin_amdgcn_s_barrier();
    asm volatile("" ::: "memory");
    COMPUTE(t & 1)
    asm volatile("s_waitcnt lgkmcnt(0)" ::: "memory");
    __builtin_amdgcn_s_barrier();
    asm volatile("" ::: "memory");
    STAGE(t & 1, t + 2)
  }
  asm volatile("s_waitcnt vmcnt(8)" ::: "memory");
  __builtin_amdgcn_s_barrier();
  asm volatile("" ::: "memory");
  COMPUTE(0)
  asm volatile("s_waitcnt vmcnt(0)" ::: "memory");
  __builtin_amdgcn_s_barrier();
  asm volatile("" ::: "memory");
  COMPUTE(1)

  // epilogue
  int colblk = n0 + wn*64;
  int which  = QKV ? (colblk >> 10) : 0;          // 0=q 1=k 2=v
  int cl0    = QKV ? (colblk & 1023) : colblk;
  const float* bias = QKV ? (which==0 ? biasq : (which==1 ? biask : biasv)) : biasq;
  u16* outp = QKV ? (which==0 ? oq : (which==1 ? ok : ov)) : (u16*)0;
  float cs0[4] = {0.f,0.f,0.f,0.f}, cs1[4] = {0.f,0.f,0.f,0.f};
  #pragma unroll
  for (int mi = 0; mi < 8; mi++){
    int row = m0 + wm*128 + mi*16 + (lane>>4)*4;
    #pragma unroll
    for (int ni = 0; ni < 4; ni++){
      int cl = cl0 + ni*16 + fr;
      float bv = bias[cl];
      #pragma unroll
      for (int r = 0; r < 4; r++){
        float val = acc[mi][ni][r] + bv;
        if (QKV){
          if (which < 2) val = sigmoidf_(val);
          outp[(size_t)(row + r) * 1024 + cl] = f2bf(val);
          if (which < 2){ if (mi < 4) cs0[ni] += val; else cs1[ni] += val; }
        } else {
          outf[(size_t)(row + r) * 1024 + cl] = val;
        }
      }
    }
  }
  if (QKV && which < 2){
    float* sums = (which==0) ? sumQ : sumK;
    int bh = (m0 >> 12) * H_ + ((colblk & 1023) >> 6);
    int sc0 = ((m0 & 4095) >> 6) + wm*2;
    #pragma unroll
    for (int h2 = 0; h2 < 2; h2++){
      #pragma unroll
      for (int ni = 0; ni < 4; ni++){
        float s = h2 ? cs1[ni] : cs0[ni];
        s += __shfl_xor(s, 16);
        s += __shfl_xor(s, 32);
        if (lane < 16) sums[((size_t)bh*NSC + sc0 + h2)*64 + ni*16 + fr] = s;
      }
    }
  }
  #undef STAGE
  #undef COMPUTE
}

// ---------------- exclusive scan over scan-chunk axis (2 arrays, in place) ----------------
// Register-group scan: 64 serial dependent latencies -> 4.
__global__ __launch_bounds__(64) void scan2_kernel(float* __restrict__ A, float* __restrict__ Bv){
  int bh = blockIdx.x, d = threadIdx.x;
  float ra = 0.f, rb = 0.f;
  for (int g = 0; g < NSC; g += 16){
    float ta[16], tb[16];
    #pragma unroll
    for (int j = 0; j < 16; j++){
      size_t o = ((size_t)bh * NSC + g + j) * 64 + d;
      ta[j] = A[o]; tb[j] = Bv[o];
    }
    #pragma unroll
    for (int j = 0; j < 16; j++){
      size_t o = ((size_t)bh * NSC + g + j) * 64 + d;
      A[o] = ra; Bv[o] = rb;
      ra += ta[j]; rb += tb[j];
    }
  }
}

// ---------------- fused sink_incoming/source_outgoing + mod chunk sums ----------------
__global__ __launch_bounds__(64) void siso_fused_kernel(
    const u16* __restrict__ q, const u16* __restrict__ k,
    const float* __restrict__ sumQx, const float* __restrict__ sumKx,
    float* __restrict__ si, float* __restrict__ so,
    float* __restrict__ sumQsi, float* __restrict__ sumKso)
{
  __shared__ u16 cq[64*64];
  __shared__ u16 ck[64*64];
  __shared__ float siv[64], sov[64];
  int bhc = blockIdx.x; int bh = bhc >> 6, sc = bhc & 63;
  int b = bh >> 4, h = bh & 15;
  int lane = threadIdx.x;
  size_t gbase = ((size_t)(b*L_ + sc*SC))*DM + h*D_;
  size_t lb = (size_t)bh*L_ + sc*SC;
  {
    float runQ = sumQx[bhc*64 + lane];
    float runK = sumKx[bhc*64 + lane];
    for (int l = 0; l < SC; l++){
      runQ += bf2f(q[gbase + (size_t)l*DM + lane]);
      runK += bf2f(k[gbase + (size_t)l*DM + lane]);
      int sw = lane ^ (l & 31);
      cq[l*64 + sw] = f2bf(runQ);
      ck[l*64 + sw] = f2bf(runK);
    }
  }
  __syncthreads();
  {
    int l = lane;
    const u16* qrow = q + gbase + (size_t)l*DM;
    const u16* krow = k + gbase + (size_t)l*DM;
    uint4 qr[8], kr[8];
    #pragma unroll
    for (int j=0;j<8;j++){ qr[j]=((const uint4*)qrow)[j]; kr[j]=((const uint4*)krow)[j]; }
    const u16* qp = (const u16*)qr; const u16* kp = (const u16*)kr;
    float a = 0.f, b2 = 0.f;
    #pragma unroll
    for (int d = 0; d < 64; d++){
      int sw = d ^ (l & 31);
      a  += (bf2f(qp[d])+EPSF) * (bf2f(ck[l*64+sw])+EPSF);
      b2 += (bf2f(kp[d])+EPSF) * (bf2f(cq[l*64+sw])+EPSF);
    }
    float n = (float)(sc*SC + l + 1);
    float vsi = n/a, vso = n/b2;
    si[lb+l] = vsi; so[lb+l] = vso;
    siv[l] = vsi;   sov[l] = vso;
    // cumsums dead; recycle cq/ck as row scratch for P3 (same swizzle)
    __syncthreads();
    #pragma unroll
    for (int d = 0; d < 64; d++){
      int sw = d ^ (l & 31);
      cq[l*64 + sw] = qp[d];
      ck[l*64 + sw] = kp[d];
    }
  }
  __syncthreads();
  {
    float sq = 0.f, sk = 0.f;
    for (int l = 0; l < SC; l++){
      int sw = lane ^ (l & 31);
      sq += bf2f(cq[l*64 + sw]) * siv[l];
      sk += bf2f(ck[l*64 + sw]) * sov[l];
    }
    sumQsi[bhc*64 + lane] = sq;
    sumKso[bhc*64 + lane] = sk;
  }
}

// ---------------- fused conserved_sink/source -> sall, csrc + exp chunk sums ----------------
__global__ __launch_bounds__(64) void cons_fused_kernel(
    const u16* __restrict__ q, const u16* __restrict__ k,
    const float* __restrict__ si, const float* __restrict__ so,
    const float* __restrict__ sumQsiX, const float* __restrict__ sumKsoX,
    float* __restrict__ csrc, float* __restrict__ sall, float* __restrict__ csSum)
{
  __shared__ u16 cq[64*64];
  __shared__ u16 ck[64*64];
  __shared__ float siv[64], sov[64];
  int bhc = blockIdx.x; int bh = bhc >> 6, sc = bhc & 63;
  int b = bh >> 4, h = bh & 15;
  int lane = threadIdx.x;
  size_t gbase = ((size_t)(b*L_ + sc*SC))*DM + h*D_;
  size_t lb = (size_t)bh*L_ + sc*SC;
  siv[lane] = si[lb + lane];
  sov[lane] = so[lb + lane];
  __syncthreads();
  {
    float runQ = sumQsiX[bhc*64 + lane];
    float runK = sumKsoX[bhc*64 + lane];
    for (int l = 0; l < SC; l++){
      runQ += bf2f(q[gbase + (size_t)l*DM + lane]) * siv[l];
      runK += bf2f(k[gbase + (size_t)l*DM + lane]) * sov[l];
      int sw = lane ^ (l & 31);
      cq[l*64 + sw] = f2bf(runQ);
      ck[l*64 + sw] = f2bf(runK);
    }
  }
  __syncthreads();
  {
    int l = lane;
    const u16* qrow = q + gbase + (size_t)l*DM;
    const u16* krow = k + gbase + (size_t)l*DM;
    uint4 qr[8], kr[8];
    #pragma unroll
    for (int j=0;j<8;j++){ qr[j]=((const uint4*)qrow)[j]; kr[j]=((const uint4*)krow)[j]; }
    const u16* qp = (const u16*)qr; const u16* kp = (const u16*)kr;
    float a = 0.f, b2 = 0.f;
    #pragma unroll
    for (int d = 0; d < 64; d++){
      int sw = d ^ (l & 31);
      a  += (bf2f(qp[d])+EPSF) * (bf2f(ck[l*64+sw])+EPSF);
      b2 += (bf2f(kp[d])+EPSF) * (bf2f(cq[l*64+sw])+EPSF);
    }
    float inv = 1.0f / (float)(sc*SC + l + 1);
    sall[lb+l] = sigmoidf_(a * inv);
    float cs = b2 * inv;
    csrc[lb+l] = cs;
    float e = __expf(cs);
    #pragma unroll
    for (int off = 32; off > 0; off >>= 1) e += __shfl_xor(e, off);
    if (lane == 0) csSum[bhc] = e;
  }
}

// ---------------- source_competition (csOff via wave-parallel reduce of csSum) ----------------
__global__ __launch_bounds__(64) void scomp_kernel(
    const float* __restrict__ csrc, const float* __restrict__ csSum,
    float* __restrict__ scomp){
  int bhc = blockIdx.x; int bh = bhc >> 6, sc = bhc & 63;
  int lane = threadIdx.x;
  float v2 = (lane < sc) ? csSum[bh*NSC + lane] : 0.f;
  #pragma unroll
  for (int o = 32; o > 0; o >>= 1) v2 += __shfl_xor(v2, o);
  float off = v2;
  size_t idx = (size_t)bh * L_ + sc * SC + lane;
  float cs = __expf(csrc[idx]);
  float run = cs;
  #pragma unroll
  for (int o = 1; o < 64; o <<= 1){
    float t = __shfl_up(run, o);
    if (lane >= o) run += t;
  }
  scomp[idx] = cs / (off + run) * (float)(sc*SC + lane + 1);
}

// ---------------- per-chunk VK sums via MFMA: VK[m][d] = sum_l v[l][m]*scomp[l]*k[l][d] ----------------
// Matmul-shaped (M=N=64, K=128) -> MFMA (G10). Vt/Kt staged transposed into
// octet-XOR-swizzled LDS (write side = attn's vts pattern; read side = gemm's
// verified fragment pattern; residual 2-way conflict free per m136).
__global__ __launch_bounds__(256) void vk_chunk_kernel(
    const u16* __restrict__ k, const u16* __restrict__ v,
    const float* __restrict__ scomp, float* __restrict__ vkc){
  __shared__ __align__(16) u16 vt[64*128];   // (v*scomp)^T [m][l] swz
  __shared__ __align__(16) u16 kt[64*128];   // k^T [d][l] swz
  int bhc = blockIdx.x; int bh = bhc >> 5, c = bhc & 31;
  int b = bh >> 4, h = bh & 15;
  int tid = threadIdx.x, wave = tid >> 6, lane = tid & 63;
  size_t gbase = ((size_t)(b * L_ + c * CS)) * DM + h * D_;
  size_t sbase = (size_t)bh * L_ + c * CS;
  {
    int r = tid >> 1;            // source row l = 0..127
    int cc = (tid & 1) * 32;     // d-half
    float vscale = scomp[sbase + r];
    #pragma unroll
    for (int j = 0; j < 4; j++){
      uint4 ku = *(const uint4*)(k + gbase + (size_t)r * DM + cc + j*8);
      uint4 vu = *(const uint4*)(v + gbase + (size_t)r * DM + cc + j*8);
      const u16* kp = (const u16*)&ku; const u16* vp = (const u16*)&vu;
      #pragma unroll
      for (int e = 0; e < 8; e++){
        int m = cc + j*8 + e;
        int idx = m*128 + ((((r >> 3) ^ (m & 7)) << 3) | (r & 7));
        vt[idx] = f2bf(bf2f(vp[e]) * vscale);
        kt[idx] = kp[e];
      }
    }
  }
  __syncthreads();
  int fr = lane & 15, q = lane >> 4;
  int mt = wave;                 // m-tile (16 rows) per wave
  f32x4 acc[4];
  #pragma unroll
  for (int i = 0; i < 4; i++) acc[i] = (f32x4){0.f,0.f,0.f,0.f};
  #pragma unroll
  for (int ks = 0; ks < 4; ks++){
    int lc = ks*4 + q;           // logical 16B l-chunk
    int off = ((lc ^ (fr & 7)) << 3);   // phys chunk (row&7 == fr&7: tiles 16-aligned)
    s16x8 av = *(const s16x8*)&vt[(mt*16 + fr)*128 + off];
    #pragma unroll
    for (int nt = 0; nt < 4; nt++){
      s16x8 bk = *(const s16x8*)&kt[(nt*16 + fr)*128 + off];
      acc[nt] = mfma16(av, bk, acc[nt]);
    }
  }
  // C layout: row m = mt*16 + q*4 + r, col d = nt*16 + fr
  float* outp = vkc + (size_t)bhc * (D_*D_);
  #pragma unroll
  for (int nt = 0; nt < 4; nt++)
    #pragma unroll
    for (int r = 0; r < 4; r++)
      outp[(mt*16 + q*4 + r)*64 + nt*16 + fr] = acc[nt][r];
}

// ---------------- exclusive scan of VK over chunks: fp32 in -> bf16 prefix out ----------------
// Register-group scan (16 at a time). bf16 output = identical rounding attn applied anyway.
__global__ __launch_bounds__(256) void vk_scan_kernel(const float* __restrict__ vkc, u16* __restrict__ vkb){
  int idx = blockIdx.x * 256 + threadIdx.x;   // over BH*4096
  int bh = idx >> 12;
  int e  = idx & 4095;
  size_t base = ((size_t)bh * NC) * 4096 + e;
  float run = 0.f;
  for (int g = 0; g < NC; g += 16){
    float tv[16];
    #pragma unroll
    for (int j = 0; j < 16; j++) tv[j] = vkc[base + (size_t)(g + j) * 4096];
    #pragma unroll
    for (int j = 0; j < 16; j++){
      vkb[base + (size_t)(g + j) * 4096] = f2bf(run);
      run += tv[j];
    }
  }
}

// ---------------- causal attention per (bh, chunk) ----------------
// 64-wide masked-S strips (R10, measured good). VKprev read directly as bf16.
__global__ __launch_bounds__(256) void attn_kernel(
    const u16* __restrict__ q, const u16* __restrict__ k, const u16* __restrict__ v,
    const float* __restrict__ si, const float* __restrict__ scomp, const float* __restrict__ salloc,
    const u16* __restrict__ vkb, u16* __restrict__ attnout)
{
  __shared__ __align__(16) u16 qs[128*64];    // qmod rows [l][d]
  __shared__ __align__(16) u16 ks2[128*64];   // k rows    [j][d]
  __shared__ __align__(16) u16 vts[64*128];   // (v*scomp)^T [m][j]
  __shared__ __align__(16) u16 vks[64*64];    // VKprev [m][d]
  __shared__ __align__(16) u16 ss[128*64];    // masked S half [l][j-in-64]
  int bhc = blockIdx.x; int bh = bhc >> 5, c = bhc & 31;
  int b = bh >> 4, h = bh & 15;
  int tid = threadIdx.x, wave = tid >> 6, lane = tid & 63;
  size_t gbase = ((size_t)(b * L_ + c * CS)) * DM + h * D_;
  size_t sbase = (size_t)bh * L_ + c * CS;
  {
    int r = tid >> 1;
    int cc = (tid & 1) * 32;
    int l = c * CS + r;
    float qscale = si[sbase + r] / (float)(l + 1);
    float vscale = scomp[sbase + r];
    #pragma unroll
    for (int j = 0; j < 4; j++){
      uint4 qu = *(const uint4*)(q + gbase + (size_t)r * DM + cc + j*8);
      uint4 kuv = *(const uint4*)(k + gbase + (size_t)r * DM + cc + j*8);
      uint4 vu = *(const uint4*)(v + gbase + (size_t)r * DM + cc + j*8);
      const u16* qp = (const u16*)&qu; const u16* vp = (const u16*)&vu;
      u16 tmp[8];
      #pragma unroll
      for (int e = 0; e < 8; e++) tmp[e] = f2bf(bf2f(qp[e]) * qscale);
      *(uint4*)&qs[r*64 + cc + j*8] = *(uint4*)tmp;
      *(uint4*)&ks2[r*64 + cc + j*8] = kuv;
      #pragma unroll
      for (int e = 0; e < 8; e++) vts[(cc + j*8 + e)*128 + r] = f2bf(bf2f(vp[e]) * vscale);
    }
    const u16* vkp = vkb + (size_t)bhc * (D_*D_) + tid * 16;
    *(uint4*)&vks[tid*16]   = *(const uint4*)(vkp);
    *(uint4*)&vks[tid*16+8] = *(const uint4*)(vkp + 8);
  }
  __syncthreads();
  int t0 = wave, t1 = 7 - wave;   // balanced l-tile pair per wave
  int fr = lane & 15, kg = (lane >> 4) * 8;
  f32x4 acc[2][4];
  #pragma unroll
  for (int i=0;i<2;i++)
    #pragma unroll
    for (int j=0;j<4;j++) acc[i][j] = (f32x4){0.f,0.f,0.f,0.f};
  s16x8 aq[2][2];
  #pragma unroll
  for (int ti = 0; ti < 2; ti++){
    int t = ti ? t1 : t0;
    #pragma unroll
    for (int kk = 0; kk < 2; kk++)
      aq[ti][kk] = *(const s16x8*)&qs[(t*16 + fr)*64 + kk*32 + kg];
  }
  // inter-chunk: qmod @ VKprev^T
  #pragma unroll
  for (int mt = 0; mt < 4; mt++){
    #pragma unroll
    for (int kk = 0; kk < 2; kk++){
      s16x8 bv = *(const s16x8*)&vks[(mt*16 + fr)*64 + kk*32 + kg];
      acc[0][mt] = mfma16(aq[0][kk], bv, acc[0][mt]);
      acc[1][mt] = mfma16(aq[1][kk], bv, acc[1][mt]);
    }
  }
  // intra-chunk, two 64-j halves
  for (int jt2 = 0; jt2 < 2; jt2++){
    __syncthreads();
    #pragma unroll
    for (int ti = 0; ti < 2; ti++){
      int t = ti ? t1 : t0;
      #pragma unroll
      for (int u = 0; u < 4; u++){
        int jj = jt2*4 + u;
        f32x4 sacc = (f32x4){0.f,0.f,0.f,0.f};
        if (jj <= t){
          #pragma unroll
          for (int kk = 0; kk < 2; kk++){
            s16x8 bkf = *(const s16x8*)&ks2[(jj*16 + fr)*64 + kk*32 + kg];
            sacc = mfma16(aq[ti][kk], bkf, sacc);
          }
        }
        int lrow = t*16 + (lane>>4)*4;
        int jcol = jj*16 + fr;
        #pragma unroll
        for (int r = 0; r < 4; r++){
          float sv = (jcol <= lrow + r) ? sacc[r] : 0.f;
          ss[(lrow + r)*64 + u*16 + fr] = f2bf(sv);
        }
      }
    }
    __syncthreads();
    #pragma unroll
    for (int ti = 0; ti < 2; ti++){
      int t = ti ? t1 : t0;
      #pragma unroll
      for (int ks = 0; ks < 2; ks++){
        if (jt2*64 + ks*32 <= t*16 + 15){
          s16x8 as = *(const s16x8*)&ss[(t*16 + fr)*64 + ks*32 + kg];
          #pragma unroll
          for (int mt = 0; mt < 4; mt++){
            s16x8 bvv = *(const s16x8*)&vts[(mt*16 + fr)*128 + jt2*64 + ks*32 + kg];
            acc[ti][mt] = mfma16(as, bvv, acc[ti][mt]);
          }
        }
      }
    }
  }
  // epilogue: * sink_allocation, write bf16 [B,L,DM]
  #pragma unroll
  for (int ti = 0; ti < 2; ti++){
    int t = ti ? t1 : t0;
    int lrow = t*16 + (lane>>4)*4;
    #pragma unroll
    for (int r = 0; r < 4; r++){
      float sa = salloc[sbase + lrow + r];
      size_t orow = ((size_t)(b * L_ + c * CS + lrow + r)) * DM + h * D_;
      #pragma unroll
      for (int mt = 0; mt < 4; mt++){
        attnout[orow + mt*16 + fr] = f2bf(acc[ti][mt][r] * sa);
      }
    }
  }
}

extern "C" void kernel_launch(void* const* d_in, const int* in_sizes, int n_in,
                              void* d_out, int out_size, void* d_ws, size_t ws_size,
                              hipStream_t stream){
  (void)in_sizes; (void)n_in; (void)out_size; (void)ws_size;
  const float* x  = (const float*)d_in[0];
  const float* Wq = (const float*)d_in[1];
  const float* bq = (const float*)d_in[2];
  const float* Wk = (const float*)d_in[3];
  const float* bk = (const float*)d_in[4];
  const float* Wv = (const float*)d_in[5];
  const float* bv = (const float*)d_in[6];
  const float* Wo = (const float*)d_in[7];
  const float* bo = (const float*)d_in[8];

  char* p = (char*)d_ws;
  auto carve = [&](size_t bytes) -> void* {
    void* r = (void*)p; p += (bytes + 255) & ~(size_t)255; return r;
  };
  u16* xb    = (u16*)carve((size_t)N_*DM*2);
  u16* wqkvT = (u16*)carve((size_t)3*DM*DM*2);
  u16* woT   = (u16*)carve((size_t)DM*DM*2);
  u16* qb  = (u16*)carve((size_t)N_*DM*2);
  u16* kb  = (u16*)carve((size_t)N_*DM*2);
  u16* vb  = (u16*)carve((size_t)N_*DM*2);
  u16* ao  = (u16*)carve((size_t)N_*DM*2);
  float* si   = (float*)carve((size_t)BH*L_*4);
  float* so   = (float*)carve((size_t)BH*L_*4);
  float* csrc = (float*)carve((size_t)BH*L_*4);
  float* sall = (float*)carve((size_t)BH*L_*4);
  float* scmp = (float*)carve((size_t)BH*L_*4);
  float* sumQ   = (float*)carve((size_t)BH*NSC*D_*4);
  float* sumK   = (float*)carve((size_t)BH*NSC*D_*4);
  float* sumQsi = (float*)carve((size_t)BH*NSC*D_*4);
  float* sumKso = (float*)carve((size_t)BH*NSC*D_*4);
  float* csSum  = (float*)carve((size_t)BH*NSC*4);
  float* vkc    = (float*)carve((size_t)BH*NC*(size_t)(D_*D_)*4);
  u16*   vkb    = (u16*)carve((size_t)BH*NC*(size_t)(D_*D_)*2);

  // 1. conversions
  cvt_kernel<<<(N_*DM/4 + 255)/256, 256, 0, stream>>>(x, xb, N_*DM/4);
  transpose_w4_kernel<<<dim3(DM/64, DM/64, 4), 256, 0, stream>>>(Wq, Wk, Wv, Wo, wqkvT, woT);
  // 2. fused q,k,v projection (one 16384x3072x1024 GEMM) + per-scan-chunk sums
  gemm256_kernel<1><<<dim3((N_/256)*(3*DM/256)), 512, 0, stream>>>(
      xb, wqkvT, bq, bk, bv, qb, kb, vb, nullptr, sumQ, sumK, 3*DM/256);
  // 3. normalizer pipeline
  scan2_kernel<<<BH, 64, 0, stream>>>(sumQ, sumK);
  siso_fused_kernel<<<BH*NSC, 64, 0, stream>>>(qb, kb, sumQ, sumK, si, so, sumQsi, sumKso);
  scan2_kernel<<<BH, 64, 0, stream>>>(sumQsi, sumKso);
  cons_fused_kernel<<<BH*NSC, 64, 0, stream>>>(qb, kb, si, so, sumQsi, sumKso, csrc, sall, csSum);
  scomp_kernel<<<BH*NSC, 64, 0, stream>>>(csrc, csSum, scmp);
  // 4. causal linear attention
  vk_chunk_kernel<<<BH*NC, 256, 0, stream>>>(kb, vb, scmp, vkc);
  vk_scan_kernel<<<(BH*D_*D_)/256, 256, 0, stream>>>(vkc, vkb);
  attn_kernel<<<BH*NC, 256, 0, stream>>>(qb, kb, vb, si, scmp, sall, vkb, ao);
  // 5. output projection
  gemm256_kernel<0><<<dim3((N_/256)*(DM/256)), 512, 0, stream>>>(
      ao, woT, bo, bo, bo, nullptr, nullptr, nullptr, (float*)d_out, nullptr, nullptr, DM/256);
}

// Round 13
// 332.545 us; speedup vs baseline: 1.1674x; 1.0152x over previous
//
#include <hip/hip_runtime.h>
#include <stdint.h>

// Problem constants (fixed by setup_inputs)
#define B_ 4
#define L_ 4096
#define DM 1024
#define H_ 16
#define D_ 64
#define BH (B_*H_)      // 64
#define N_ (B_*L_)      // 16384
#define CS 128          // chunk size for causal attention
#define NC (L_/CS)      // 32
#define SC 64           // chunk size for normalizer scans
#define NSC (L_/SC)     // 64
#define EPSF 1e-6f

typedef unsigned short u16;
typedef unsigned int   u32;
typedef __attribute__((ext_vector_type(8))) short s16x8;
typedef __attribute__((ext_vector_type(4))) float f32x4;

__device__ __forceinline__ float bf2f(u16 u){
  union { u32 i; float f; } v; v.i = ((u32)u) << 16; return v.f;
}
__device__ __forceinline__ u16 f2bf(float f){
  union { float f; u32 i; } v; v.f = f;
  u32 i = v.i;
  return (u16)((i + 0x7fffu + ((i >> 16) & 1u)) >> 16);  // RNE
}
__device__ __forceinline__ void gload16(const void* g, void* l){
  __builtin_amdgcn_global_load_lds(
      (const __attribute__((address_space(1))) u32*)g,
      (__attribute__((address_space(3))) u32*)l, 16, 0, 0);
}
__device__ __forceinline__ f32x4 mfma16(s16x8 a, s16x8 b, f32x4 c){
  return __builtin_amdgcn_mfma_f32_16x16x32_bf16(a, b, c, 0, 0, 0);
}
__device__ __forceinline__ float sigmoidf_(float x){ return 1.0f/(1.0f+__expf(-x)); }

// ---------------- fp32 -> bf16 convert ----------------
__global__ void cvt_kernel(const float* __restrict__ in, u16* __restrict__ out, int n4){
  int i = blockIdx.x * blockDim.x + threadIdx.x;
  if (i >= n4) return;
  float4 v = ((const float4*)in)[i];
  union { u16 s[4]; uint2 u; } o;
  o.s[0]=f2bf(v.x); o.s[1]=f2bf(v.y); o.s[2]=f2bf(v.z); o.s[3]=f2bf(v.w);
  ((uint2*)out)[i] = o.u;
}

// ---------------- 4x W [K][N] fp32 -> WT [N][K] bf16 (one launch) ----------------
__global__ __launch_bounds__(256) void transpose_w4_kernel(
    const float* __restrict__ Wq, const float* __restrict__ Wk,
    const float* __restrict__ Wv, const float* __restrict__ Wo,
    u16* __restrict__ wqkvT, u16* __restrict__ woT){
  __shared__ float t[64][65];
  int z = blockIdx.z;
  const float* W = (z==0) ? Wq : (z==1) ? Wk : (z==2) ? Wv : Wo;
  u16* WT = (z<3) ? (wqkvT + (size_t)z*DM*DM) : woT;
  int n0 = blockIdx.x * 64, k0 = blockIdx.y * 64;
  int tx = threadIdx.x & 63, ty = threadIdx.x >> 6;
  #pragma unroll
  for (int s = 0; s < 64; s += 4)
    t[ty + s][tx] = W[(size_t)(k0 + ty + s) * DM + n0 + tx];
  __syncthreads();
  #pragma unroll
  for (int s = 0; s < 64; s += 4)
    WT[(size_t)(n0 + ty + s) * DM + k0 + tx] = f2bf(t[tx][ty + s]);
}

// ---------------- 256x256 counted-vmcnt MFMA GEMM (K=1024 fixed) — R3/R10 structure ----------------
// Measured-best: 133.6-134.2 us (QKV), MfmaUtil ~32.5%, 0 bank conflicts.
// Parked: 8-phase (R4/R5 null) and 128^2 (R11: occupancy 31% but 145 us) both failed to beat it.
template<int QKV>
__global__ __launch_bounds__(512, 2) void gemm256_kernel(
    const u16* __restrict__ A, const u16* __restrict__ BT,
    const float* __restrict__ biasq, const float* __restrict__ biask, const float* __restrict__ biasv,
    u16* __restrict__ oq, u16* __restrict__ ok, u16* __restrict__ ov,
    float* __restrict__ outf,
    float* __restrict__ sumQ, float* __restrict__ sumK, int NBY)
{
  // LDS: A slot0 [0,32K), A slot1 [32K,64K), B slot0 [64K,96K), B slot1 [96K,128K)
  __shared__ __align__(16) u16 smem[65536];
  char* smb = (char*)smem;
  int tid = threadIdx.x;
  int wave = tid >> 6, lane = tid & 63;
  int wm = wave >> 2, wn = wave & 3;          // 2 x 4 wave grid
  int nwg = gridDim.x;
  int q8 = nwg >> 3;
  int id = blockIdx.x;
  int id2 = (id & 7) * q8 + (id >> 3);
  int bx = id2 / NBY, by = id2 % NBY;
  int m0 = bx * 256, n0 = by * 256;
  int srcq = (tid & 7) ^ ((tid >> 3) & 7);
  const u16* aRow = A  + (size_t)(m0 + (tid >> 3)) * 1024 + srcq * 8;
  const u16* bRow = BT + (size_t)(n0 + (tid >> 3)) * 1024 + srcq * 8;

  f32x4 acc[8][4];
  #pragma unroll
  for (int i=0;i<8;i++)
    #pragma unroll
    for (int j=0;j<4;j++) acc[i][j] = (f32x4){0.f,0.f,0.f,0.f};

  int fr = lane & 15, q = lane >> 4;
  int aoff0 = fr*128 + (((q ^ (lane&3)) + 4*((lane>>2)&1)) << 4);
  int aoff1 = fr*128 + (((q ^ (lane&3)) + 4*(1 ^ ((lane>>2)&1))) << 4);

  #define STAGE(s, t) { \
    _Pragma("unroll") \
    for (int i_ = 0; i_ < 4; i_++){ \
      gload16(aRow + (size_t)(t)*64 + (size_t)i_*65536, smb + (s)*32768 + i_*8192 + tid*16); \
      gload16(bRow + (size_t)(t)*64 + (size_t)i_*65536, smb + 65536 + (s)*32768 + i_*8192 + tid*16); \
    } }

  #define COMPUTE(s) { \
    const char* Ab_ = smb + (s)*32768 + wm*16384; \
    const char* Bb_ = smb + 65536 + (s)*32768 + wn*8192; \
    _Pragma("unroll") \
    for (int kk_ = 0; kk_ < 2; kk_++){ \
      int off_ = kk_ ? aoff1 : aoff0; \
      s16x8 af_[8], bf_[4]; \
      _Pragma("unroll") \
      for (int mi_ = 0; mi_ < 8; mi_++) af_[mi_] = *(const s16x8*)(Ab_ + mi_*2048 + off_); \
      _Pragma("unroll") \
      for (int ni_ = 0; ni_ < 4; ni_++) bf_[ni_] = *(const s16x8*)(Bb_ + ni_*2048 + off_); \
      _Pragma("unroll") \
      for (int mi_ = 0; mi_ < 8; mi_++) \
        _Pragma("unroll") \
        for (int ni_ = 0; ni_ < 4; ni_++) \
          acc[mi_][ni_] = mfma16(af_[mi_], bf_[ni_], acc[mi_][ni_]); \
    } }

  STAGE(0, 0)
  STAGE(1, 1)
  for (int t = 0; t < 14; t++){
    asm volatile("s_waitcnt vmcnt(8)" ::: "memory");
    __builtin_amdgcn_s_barrier();
    asm volatile("" ::: "memory");
    COMPUTE(t & 1)
    asm volatile("s_waitcnt lgkmcnt(0)" ::: "memory");
    __builtin_amdgcn_s_barrier();
    asm volatile("" ::: "memory");
    STAGE(t & 1, t + 2)
  }
  asm volatile("s_waitcnt vmcnt(8)" ::: "memory");
  __builtin_amdgcn_s_barrier();
  asm volatile("" ::: "memory");
  COMPUTE(0)
  asm volatile("s_waitcnt vmcnt(0)" ::: "memory");
  __builtin_amdgcn_s_barrier();
  asm volatile("" ::: "memory");
  COMPUTE(1)

  // epilogue
  int colblk = n0 + wn*64;
  int which  = QKV ? (colblk >> 10) : 0;          // 0=q 1=k 2=v
  int cl0    = QKV ? (colblk & 1023) : colblk;
  const float* bias = QKV ? (which==0 ? biasq : (which==1 ? biask : biasv)) : biasq;
  u16* outp = QKV ? (which==0 ? oq : (which==1 ? ok : ov)) : (u16*)0;
  float cs0[4] = {0.f,0.f,0.f,0.f}, cs1[4] = {0.f,0.f,0.f,0.f};
  #pragma unroll
  for (int mi = 0; mi < 8; mi++){
    int row = m0 + wm*128 + mi*16 + (lane>>4)*4;
    #pragma unroll
    for (int ni = 0; ni < 4; ni++){
      int cl = cl0 + ni*16 + fr;
      float bv = bias[cl];
      #pragma unroll
      for (int r = 0; r < 4; r++){
        float val = acc[mi][ni][r] + bv;
        if (QKV){
          if (which < 2) val = sigmoidf_(val);
          outp[(size_t)(row + r) * 1024 + cl] = f2bf(val);
          if (which < 2){ if (mi < 4) cs0[ni] += val; else cs1[ni] += val; }
        } else {
          outf[(size_t)(row + r) * 1024 + cl] = val;
        }
      }
    }
  }
  if (QKV && which < 2){
    float* sums = (which==0) ? sumQ : sumK;
    int bh = (m0 >> 12) * H_ + ((colblk & 1023) >> 6);
    int sc0 = ((m0 & 4095) >> 6) + wm*2;
    #pragma unroll
    for (int h2 = 0; h2 < 2; h2++){
      #pragma unroll
      for (int ni = 0; ni < 4; ni++){
        float s = h2 ? cs1[ni] : cs0[ni];
        s += __shfl_xor(s, 16);
        s += __shfl_xor(s, 32);
        if (lane < 16) sums[((size_t)bh*NSC + sc0 + h2)*64 + ni*16 + fr] = s;
      }
    }
  }
  #undef STAGE
  #undef COMPUTE
}

// ---------------- exclusive scan over scan-chunk axis (2 arrays, in place) ----------------
// Register-group scan: 64 serial dependent latencies -> 4.
__global__ __launch_bounds__(64) void scan2_kernel(float* __restrict__ A, float* __restrict__ Bv){
  int bh = blockIdx.x, d = threadIdx.x;
  float ra = 0.f, rb = 0.f;
  for (int g = 0; g < NSC; g += 16){
    float ta[16], tb[16];
    #pragma unroll
    for (int j = 0; j < 16; j++){
      size_t o = ((size_t)bh * NSC + g + j) * 64 + d;
      ta[j] = A[o]; tb[j] = Bv[o];
    }
    #pragma unroll
    for (int j = 0; j < 16; j++){
      size_t o = ((size_t)bh * NSC + g + j) * 64 + d;
      A[o] = ra; Bv[o] = rb;
      ra += ta[j]; rb += tb[j];
    }
  }
}

// ---------------- fused sink_incoming/source_outgoing + mod chunk sums ----------------
__global__ __launch_bounds__(64) void siso_fused_kernel(
    const u16* __restrict__ q, const u16* __restrict__ k,
    const float* __restrict__ sumQx, const float* __restrict__ sumKx,
    float* __restrict__ si, float* __restrict__ so,
    float* __restrict__ sumQsi, float* __restrict__ sumKso)
{
  __shared__ u16 cq[64*64];
  __shared__ u16 ck[64*64];
  __shared__ float siv[64], sov[64];
  int bhc = blockIdx.x; int bh = bhc >> 6, sc = bhc & 63;
  int b = bh >> 4, h = bh & 15;
  int lane = threadIdx.x;
  size_t gbase = ((size_t)(b*L_ + sc*SC))*DM + h*D_;
  size_t lb = (size_t)bh*L_ + sc*SC;
  {
    float runQ = sumQx[bhc*64 + lane];
    float runK = sumKx[bhc*64 + lane];
    for (int l = 0; l < SC; l++){
      runQ += bf2f(q[gbase + (size_t)l*DM + lane]);
      runK += bf2f(k[gbase + (size_t)l*DM + lane]);
      int sw = lane ^ (l & 31);
      cq[l*64 + sw] = f2bf(runQ);
      ck[l*64 + sw] = f2bf(runK);
    }
  }
  __syncthreads();
  {
    int l = lane;
    const u16* qrow = q + gbase + (size_t)l*DM;
    const u16* krow = k + gbase + (size_t)l*DM;
    uint4 qr[8], kr[8];
    #pragma unroll
    for (int j=0;j<8;j++){ qr[j]=((const uint4*)qrow)[j]; kr[j]=((const uint4*)krow)[j]; }
    const u16* qp = (const u16*)qr; const u16* kp = (const u16*)kr;
    float a = 0.f, b2 = 0.f;
    #pragma unroll
    for (int d = 0; d < 64; d++){
      int sw = d ^ (l & 31);
      a  += (bf2f(qp[d])+EPSF) * (bf2f(ck[l*64+sw])+EPSF);
      b2 += (bf2f(kp[d])+EPSF) * (bf2f(cq[l*64+sw])+EPSF);
    }
    float n = (float)(sc*SC + l + 1);
    float vsi = n/a, vso = n/b2;
    si[lb+l] = vsi; so[lb+l] = vso;
    siv[l] = vsi;   sov[l] = vso;
    // cumsums dead; recycle cq/ck as row scratch for P3 (same swizzle)
    __syncthreads();
    #pragma unroll
    for (int d = 0; d < 64; d++){
      int sw = d ^ (l & 31);
      cq[l*64 + sw] = qp[d];
      ck[l*64 + sw] = kp[d];
    }
  }
  __syncthreads();
  {
    float sq = 0.f, sk = 0.f;
    for (int l = 0; l < SC; l++){
      int sw = lane ^ (l & 31);
      sq += bf2f(cq[l*64 + sw]) * siv[l];
      sk += bf2f(ck[l*64 + sw]) * sov[l];
    }
    sumQsi[bhc*64 + lane] = sq;
    sumKso[bhc*64 + lane] = sk;
  }
}

// ---------------- fused conserved_sink/source -> sall, csrc + exp chunk sums ----------------
__global__ __launch_bounds__(64) void cons_fused_kernel(
    const u16* __restrict__ q, const u16* __restrict__ k,
    const float* __restrict__ si, const float* __restrict__ so,
    const float* __restrict__ sumQsiX, const float* __restrict__ sumKsoX,
    float* __restrict__ csrc, float* __restrict__ sall, float* __restrict__ csSum)
{
  __shared__ u16 cq[64*64];
  __shared__ u16 ck[64*64];
  __shared__ float siv[64], sov[64];
  int bhc = blockIdx.x; int bh = bhc >> 6, sc = bhc & 63;
  int b = bh >> 4, h = bh & 15;
  int lane = threadIdx.x;
  size_t gbase = ((size_t)(b*L_ + sc*SC))*DM + h*D_;
  size_t lb = (size_t)bh*L_ + sc*SC;
  siv[lane] = si[lb + lane];
  sov[lane] = so[lb + lane];
  __syncthreads();
  {
    float runQ = sumQsiX[bhc*64 + lane];
    float runK = sumKsoX[bhc*64 + lane];
    for (int l = 0; l < SC; l++){
      runQ += bf2f(q[gbase + (size_t)l*DM + lane]) * siv[l];
      runK += bf2f(k[gbase + (size_t)l*DM + lane]) * sov[l];
      int sw = lane ^ (l & 31);
      cq[l*64 + sw] = f2bf(runQ);
      ck[l*64 + sw] = f2bf(runK);
    }
  }
  __syncthreads();
  {
    int l = lane;
    const u16* qrow = q + gbase + (size_t)l*DM;
    const u16* krow = k + gbase + (size_t)l*DM;
    uint4 qr[8], kr[8];
    #pragma unroll
    for (int j=0;j<8;j++){ qr[j]=((const uint4*)qrow)[j]; kr[j]=((const uint4*)krow)[j]; }
    const u16* qp = (const u16*)qr; const u16* kp = (const u16*)kr;
    float a = 0.f, b2 = 0.f;
    #pragma unroll
    for (int d = 0; d < 64; d++){
      int sw = d ^ (l & 31);
      a  += (bf2f(qp[d])+EPSF) * (bf2f(ck[l*64+sw])+EPSF);
      b2 += (bf2f(kp[d])+EPSF) * (bf2f(cq[l*64+sw])+EPSF);
    }
    float inv = 1.0f / (float)(sc*SC + l + 1);
    sall[lb+l] = sigmoidf_(a * inv);
    float cs = b2 * inv;
    csrc[lb+l] = cs;
    float e = __expf(cs);
    #pragma unroll
    for (int off = 32; off > 0; off >>= 1) e += __shfl_xor(e, off);
    if (lane == 0) csSum[bhc] = e;
  }
}

// ---------------- source_competition (csOff via wave-parallel reduce of csSum) ----------------
__global__ __launch_bounds__(64) void scomp_kernel(
    const float* __restrict__ csrc, const float* __restrict__ csSum,
    float* __restrict__ scomp){
  int bhc = blockIdx.x; int bh = bhc >> 6, sc = bhc & 63;
  int lane = threadIdx.x;
  float v2 = (lane < sc) ? csSum[bh*NSC + lane] : 0.f;
  #pragma unroll
  for (int o = 32; o > 0; o >>= 1) v2 += __shfl_xor(v2, o);
  float off = v2;
  size_t idx = (size_t)bh * L_ + sc * SC + lane;
  float cs = __expf(csrc[idx]);
  float run = cs;
  #pragma unroll
  for (int o = 1; o < 64; o <<= 1){
    float t = __shfl_up(run, o);
    if (lane >= o) run += t;
  }
  scomp[idx] = cs / (off + run) * (float)(sc*SC + lane + 1);
}

// ---------------- per-chunk VK sums via MFMA (R12, measured good) ----------------
__global__ __launch_bounds__(256) void vk_chunk_kernel(
    const u16* __restrict__ k, const u16* __restrict__ v,
    const float* __restrict__ scomp, float* __restrict__ vkc){
  __shared__ __align__(16) u16 vt[64*128];   // (v*scomp)^T [m][l] swz
  __shared__ __align__(16) u16 kt[64*128];   // k^T [d][l] swz
  int bhc = blockIdx.x; int bh = bhc >> 5, c = bhc & 31;
  int b = bh >> 4, h = bh & 15;
  int tid = threadIdx.x, wave = tid >> 6, lane = tid & 63;
  size_t gbase = ((size_t)(b * L_ + c * CS)) * DM + h * D_;
  size_t sbase = (size_t)bh * L_ + c * CS;
  {
    int r = tid >> 1;            // source row l = 0..127
    int cc = (tid & 1) * 32;     // d-half
    float vscale = scomp[sbase + r];
    #pragma unroll
    for (int j = 0; j < 4; j++){
      uint4 ku = *(const uint4*)(k + gbase + (size_t)r * DM + cc + j*8);
      uint4 vu = *(const uint4*)(v + gbase + (size_t)r * DM + cc + j*8);
      const u16* kp = (const u16*)&ku; const u16* vp = (const u16*)&vu;
      #pragma unroll
      for (int e = 0; e < 8; e++){
        int m = cc + j*8 + e;
        int idx = m*128 + ((((r >> 3) ^ (m & 7)) << 3) | (r & 7));
        vt[idx] = f2bf(bf2f(vp[e]) * vscale);
        kt[idx] = kp[e];
      }
    }
  }
  __syncthreads();
  int fr = lane & 15, q = lane >> 4;
  int mt = wave;                 // m-tile (16 rows) per wave
  f32x4 acc[4];
  #pragma unroll
  for (int i = 0; i < 4; i++) acc[i] = (f32x4){0.f,0.f,0.f,0.f};
  #pragma unroll
  for (int ks = 0; ks < 4; ks++){
    int lc = ks*4 + q;           // logical 16B l-chunk
    int off = ((lc ^ (fr & 7)) << 3);
    s16x8 av = *(const s16x8*)&vt[(mt*16 + fr)*128 + off];
    #pragma unroll
    for (int nt = 0; nt < 4; nt++){
      s16x8 bk = *(const s16x8*)&kt[(nt*16 + fr)*128 + off];
      acc[nt] = mfma16(av, bk, acc[nt]);
    }
  }
  float* outp = vkc + (size_t)bhc * (D_*D_);
  #pragma unroll
  for (int nt = 0; nt < 4; nt++)
    #pragma unroll
    for (int r = 0; r < 4; r++)
      outp[(mt*16 + q*4 + r)*64 + nt*16 + fr] = acc[nt][r];
}

// ---------------- exclusive scan of VK over chunks: fp32 in -> bf16 prefix out ----------------
__global__ __launch_bounds__(256) void vk_scan_kernel(const float* __restrict__ vkc, u16* __restrict__ vkb){
  int idx = blockIdx.x * 256 + threadIdx.x;   // over BH*4096
  int bh = idx >> 12;
  int e  = idx & 4095;
  size_t base = ((size_t)bh * NC) * 4096 + e;
  float run = 0.f;
  for (int g = 0; g < NC; g += 16){
    float tv[16];
    #pragma unroll
    for (int j = 0; j < 16; j++) tv[j] = vkc[base + (size_t)(g + j) * 4096];
    #pragma unroll
    for (int j = 0; j < 16; j++){
      vkb[base + (size_t)(g + j) * 4096] = f2bf(run);
      run += tv[j];
    }
  }
}

// ---------------- causal attention per (bh, chunk) ----------------
// All LDS tiles octet-XOR swizzled: storage invariant phys_chunk = logical ^ (row&7)
// (3-bit XOR, bit 3 preserved). Unswizzled row-major tiles put bank = f(chunk) only
// -> 16 lanes per 4-bank slot = 16-way serialization on every MFMA operand read (G4).
// Write side and read side use the same involution; arithmetic bit-identical.
__global__ __launch_bounds__(256) void attn_kernel(
    const u16* __restrict__ q, const u16* __restrict__ k, const u16* __restrict__ v,
    const float* __restrict__ si, const float* __restrict__ scomp, const float* __restrict__ salloc,
    const u16* __restrict__ vkb, u16* __restrict__ attnout)
{
  __shared__ __align__(16) u16 qs[128*64];    // qmod rows [l][d] swz
  __shared__ __align__(16) u16 ks2[128*64];   // k rows    [j][d] swz
  __shared__ __align__(16) u16 vts[64*128];   // (v*scomp)^T [m][j] swz
  __shared__ __align__(16) u16 vks[64*64];    // VKprev [m][d] swz
  __shared__ __align__(16) u16 ss[128*64];    // masked S half [l][j-in-64] swz
  int bhc = blockIdx.x; int bh = bhc >> 5, c = bhc & 31;
  int b = bh >> 4, h = bh & 15;
  int tid = threadIdx.x, wave = tid >> 6, lane = tid & 63;
  size_t gbase = ((size_t)(b * L_ + c * CS)) * DM + h * D_;
  size_t sbase = (size_t)bh * L_ + c * CS;
  {
    int r = tid >> 1;
    int cc = (tid & 1) * 32;
    int l = c * CS + r;
    float qscale = si[sbase + r] / (float)(l + 1);
    float vscale = scomp[sbase + r];
    #pragma unroll
    for (int j = 0; j < 4; j++){
      int d0 = cc + j*8;
      uint4 qu = *(const uint4*)(q + gbase + (size_t)r * DM + d0);
      uint4 kuv = *(const uint4*)(k + gbase + (size_t)r * DM + d0);
      uint4 vu = *(const uint4*)(v + gbase + (size_t)r * DM + d0);
      const u16* qp = (const u16*)&qu; const u16* vp = (const u16*)&vu;
      u16 tmp[8];
      #pragma unroll
      for (int e = 0; e < 8; e++) tmp[e] = f2bf(bf2f(qp[e]) * qscale);
      int csw = ((d0 >> 3) ^ (r & 7)) << 3;           // swizzled d-chunk
      *(uint4*)&qs[r*64 + csw]  = *(uint4*)tmp;
      *(uint4*)&ks2[r*64 + csw] = kuv;
      #pragma unroll
      for (int e = 0; e < 8; e++){
        int m = d0 + e;
        int jsw = (((r >> 3) ^ (m & 7)) << 3) | (r & 7);  // swizzled j position
        vts[m*128 + jsw] = f2bf(bf2f(vp[e]) * vscale);
      }
    }
    const u16* vkp = vkb + (size_t)bhc * (D_*D_) + tid * 16;
    int m = tid >> 2, dq = (tid & 3) * 2;               // two d-chunks per thread
    int o0 = ((dq     ^ (m & 7)) << 3);
    int o1 = (((dq+1) ^ (m & 7)) << 3);
    *(uint4*)&vks[m*64 + o0] = *(const uint4*)(vkp);
    *(uint4*)&vks[m*64 + o1] = *(const uint4*)(vkp + 8);
  }
  __syncthreads();
  int t0 = wave, t1 = 7 - wave;   // balanced l-tile pair per wave
  int fr = lane & 15, qh = lane >> 4;
  int f7 = fr & 7;
  f32x4 acc[2][4];
  #pragma unroll
  for (int i=0;i<2;i++)
    #pragma unroll
    for (int j=0;j<4;j++) acc[i][j] = (f32x4){0.f,0.f,0.f,0.f};
  s16x8 aq[2][2];
  #pragma unroll
  for (int ti = 0; ti < 2; ti++){
    int t = ti ? t1 : t0;
    #pragma unroll
    for (int kk = 0; kk < 2; kk++){
      int oc = (((kk*4 + qh) ^ f7) << 3);
      aq[ti][kk] = *(const s16x8*)&qs[(t*16 + fr)*64 + oc];
    }
  }
  // inter-chunk: qmod @ VKprev^T
  #pragma unroll
  for (int mt = 0; mt < 4; mt++){
    #pragma unroll
    for (int kk = 0; kk < 2; kk++){
      int oc = (((kk*4 + qh) ^ f7) << 3);
      s16x8 bv = *(const s16x8*)&vks[(mt*16 + fr)*64 + oc];
      acc[0][mt] = mfma16(aq[0][kk], bv, acc[0][mt]);
      acc[1][mt] = mfma16(aq[1][kk], bv, acc[1][mt]);
    }
  }
  // intra-chunk, two 64-j halves
  for (int jt2 = 0; jt2 < 2; jt2++){
    __syncthreads();
    #pragma unroll
    for (int ti = 0; ti < 2; ti++){
      int t = ti ? t1 : t0;
      #pragma unroll
      for (int u = 0; u < 4; u++){
        int jj = jt2*4 + u;
        f32x4 sacc = (f32x4){0.f,0.f,0.f,0.f};
        if (jj <= t){
          #pragma unroll
          for (int kk = 0; kk < 2; kk++){
            int oc = (((kk*4 + qh) ^ f7) << 3);
            s16x8 bkf = *(const s16x8*)&ks2[(jj*16 + fr)*64 + oc];
            sacc = mfma16(aq[ti][kk], bkf, sacc);
          }
        }
        int lrow = t*16 + qh*4;
        int jcol = jj*16 + fr;
        int cst = u*2 + (fr >> 3);          // strip-local logical chunk
        #pragma unroll
        for (int r = 0; r < 4; r++){
          float sv = (jcol <= lrow + r) ? sacc[r] : 0.f;
          int row = lrow + r;
          ss[row*64 + (((cst ^ (row & 7)) << 3) | f7)] = f2bf(sv);
        }
      }
    }
    __syncthreads();
    #pragma unroll
    for (int ti = 0; ti < 2; ti++){
      int t = ti ? t1 : t0;
      #pragma unroll
      for (int ks = 0; ks < 2; ks++){
        if (jt2*64 + ks*32 <= t*16 + 15){
          int ocs = (((ks*4 + qh) ^ f7) << 3);
          s16x8 as = *(const s16x8*)&ss[(t*16 + fr)*64 + ocs];
          #pragma unroll
          for (int mt = 0; mt < 4; mt++){
            int lc = jt2*8 + ks*4 + qh;
            int ocv = ((lc ^ f7) << 3);
            s16x8 bvv = *(const s16x8*)&vts[(mt*16 + fr)*128 + ocv];
            acc[ti][mt] = mfma16(as, bvv, acc[ti][mt]);
          }
        }
      }
    }
  }
  // epilogue: * sink_allocation, write bf16 [B,L,DM]
  #pragma unroll
  for (int ti = 0; ti < 2; ti++){
    int t = ti ? t1 : t0;
    int lrow = t*16 + qh*4;
    #pragma unroll
    for (int r = 0; r < 4; r++){
      float sa = salloc[sbase + lrow + r];
      size_t orow = ((size_t)(b * L_ + c * CS + lrow + r)) * DM + h * D_;
      #pragma unroll
      for (int mt = 0; mt < 4; mt++){
        attnout[orow + mt*16 + fr] = f2bf(acc[ti][mt][r] * sa);
      }
    }
  }
}

extern "C" void kernel_launch(void* const* d_in, const int* in_sizes, int n_in,
                              void* d_out, int out_size, void* d_ws, size_t ws_size,
                              hipStream_t stream){
  (void)in_sizes; (void)n_in; (void)out_size; (void)ws_size;
  const float* x  = (const float*)d_in[0];
  const float* Wq = (const float*)d_in[1];
  const float* bq = (const float*)d_in[2];
  const float* Wk = (const float*)d_in[3];
  const float* bk = (const float*)d_in[4];
  const float* Wv = (const float*)d_in[5];
  const float* bv = (const float*)d_in[6];
  const float* Wo = (const float*)d_in[7];
  const float* bo = (const float*)d_in[8];

  char* p = (char*)d_ws;
  auto carve = [&](size_t bytes) -> void* {
    void* r = (void*)p; p += (bytes + 255) & ~(size_t)255; return r;
  };
  u16* xb    = (u16*)carve((size_t)N_*DM*2);
  u16* wqkvT = (u16*)carve((size_t)3*DM*DM*2);
  u16* woT   = (u16*)carve((size_t)DM*DM*2);
  u16* qb  = (u16*)carve((size_t)N_*DM*2);
  u16* kb  = (u16*)carve((size_t)N_*DM*2);
  u16* vb  = (u16*)carve((size_t)N_*DM*2);
  u16* ao  = (u16*)carve((size_t)N_*DM*2);
  float* si   = (float*)carve((size_t)BH*L_*4);
  float* so   = (float*)carve((size_t)BH*L_*4);
  float* csrc = (float*)carve((size_t)BH*L_*4);
  float* sall = (float*)carve((size_t)BH*L_*4);
  float* scmp = (float*)carve((size_t)BH*L_*4);
  float* sumQ   = (float*)carve((size_t)BH*NSC*D_*4);
  float* sumK   = (float*)carve((size_t)BH*NSC*D_*4);
  float* sumQsi = (float*)carve((size_t)BH*NSC*D_*4);
  float* sumKso = (float*)carve((size_t)BH*NSC*D_*4);
  float* csSum  = (float*)carve((size_t)BH*NSC*4);
  float* vkc    = (float*)carve((size_t)BH*NC*(size_t)(D_*D_)*4);
  u16*   vkb    = (u16*)carve((size_t)BH*NC*(size_t)(D_*D_)*2);

  // 1. conversions
  cvt_kernel<<<(N_*DM/4 + 255)/256, 256, 0, stream>>>(x, xb, N_*DM/4);
  transpose_w4_kernel<<<dim3(DM/64, DM/64, 4), 256, 0, stream>>>(Wq, Wk, Wv, Wo, wqkvT, woT);
  // 2. fused q,k,v projection (one 16384x3072x1024 GEMM) + per-scan-chunk sums
  gemm256_kernel<1><<<dim3((N_/256)*(3*DM/256)), 512, 0, stream>>>(
      xb, wqkvT, bq, bk, bv, qb, kb, vb, nullptr, sumQ, sumK, 3*DM/256);
  // 3. normalizer pipeline
  scan2_kernel<<<BH, 64, 0, stream>>>(sumQ, sumK);
  siso_fused_kernel<<<BH*NSC, 64, 0, stream>>>(qb, kb, sumQ, sumK, si, so, sumQsi, sumKso);
  scan2_kernel<<<BH, 64, 0, stream>>>(sumQsi, sumKso);
  cons_fused_kernel<<<BH*NSC, 64, 0, stream>>>(qb, kb, si, so, sumQsi, sumKso, csrc, sall, csSum);
  scomp_kernel<<<BH*NSC, 64, 0, stream>>>(csrc, csSum, scmp);
  // 4. causal linear attention
  vk_chunk_kernel<<<BH*NC, 256, 0, stream>>>(kb, vb, scmp, vkc);
  vk_scan_kernel<<<(BH*D_*D_)/256, 256, 0, stream>>>(vkc, vkb);
  attn_kernel<<<BH*NC, 256, 0, stream>>>(qb, kb, vb, si, scmp, sall, vkb, ao);
  // 5. output projection
  gemm256_kernel<0><<<dim3((N_/256)*(DM/256)), 512, 0, stream>>>(
      ao, woT, bo, bo, bo, nullptr, nullptr, nullptr, (float*)d_out, nullptr, nullptr, DM/256);
}

// Round 14
// 327.833 us; speedup vs baseline: 1.1842x; 1.0144x over previous
//
#include <hip/hip_runtime.h>
#include <stdint.h>

// Problem constants (fixed by setup_inputs)
#define B_ 4
#define L_ 4096
#define DM 1024
#define H_ 16
#define D_ 64
#define BH (B_*H_)      // 64
#define N_ (B_*L_)      // 16384
#define CS 128          // chunk size for causal attention
#define NC (L_/CS)      // 32
#define SC 64           // chunk size for normalizer scans
#define NSC (L_/SC)     // 64
#define EPSF 1e-6f

typedef unsigned short u16;
typedef unsigned int   u32;
typedef __attribute__((ext_vector_type(8))) short s16x8;
typedef __attribute__((ext_vector_type(4))) float f32x4;

__device__ __forceinline__ float bf2f(u16 u){
  union { u32 i; float f; } v; v.i = ((u32)u) << 16; return v.f;
}
__device__ __forceinline__ u16 f2bf(float f){
  union { float f; u32 i; } v; v.f = f;
  u32 i = v.i;
  return (u16)((i + 0x7fffu + ((i >> 16) & 1u)) >> 16);  // RNE
}
__device__ __forceinline__ void gload16(const void* g, void* l){
  __builtin_amdgcn_global_load_lds(
      (const __attribute__((address_space(1))) u32*)g,
      (__attribute__((address_space(3))) u32*)l, 16, 0, 0);
}
__device__ __forceinline__ f32x4 mfma16(s16x8 a, s16x8 b, f32x4 c){
  return __builtin_amdgcn_mfma_f32_16x16x32_bf16(a, b, c, 0, 0, 0);
}
__device__ __forceinline__ float sigmoidf_(float x){ return 1.0f/(1.0f+__expf(-x)); }

// ---------------- fp32 -> bf16 convert ----------------
__global__ void cvt_kernel(const float* __restrict__ in, u16* __restrict__ out, int n4){
  int i = blockIdx.x * blockDim.x + threadIdx.x;
  if (i >= n4) return;
  float4 v = ((const float4*)in)[i];
  union { u16 s[4]; uint2 u; } o;
  o.s[0]=f2bf(v.x); o.s[1]=f2bf(v.y); o.s[2]=f2bf(v.z); o.s[3]=f2bf(v.w);
  ((uint2*)out)[i] = o.u;
}

// ---------------- 4x W [K][N] fp32 -> WT [N][K] bf16 (one launch) ----------------
__global__ __launch_bounds__(256) void transpose_w4_kernel(
    const float* __restrict__ Wq, const float* __restrict__ Wk,
    const float* __restrict__ Wv, const float* __restrict__ Wo,
    u16* __restrict__ wqkvT, u16* __restrict__ woT){
  __shared__ float t[64][65];
  int z = blockIdx.z;
  const float* W = (z==0) ? Wq : (z==1) ? Wk : (z==2) ? Wv : Wo;
  u16* WT = (z<3) ? (wqkvT + (size_t)z*DM*DM) : woT;
  int n0 = blockIdx.x * 64, k0 = blockIdx.y * 64;
  int tx = threadIdx.x & 63, ty = threadIdx.x >> 6;
  #pragma unroll
  for (int s = 0; s < 64; s += 4)
    t[ty + s][tx] = W[(size_t)(k0 + ty + s) * DM + n0 + tx];
  __syncthreads();
  #pragma unroll
  for (int s = 0; s < 64; s += 4)
    WT[(size_t)(n0 + ty + s) * DM + k0 + tx] = f2bf(t[tx][ty + s]);
}

// ---------------- 256x256 counted-vmcnt MFMA GEMM (K=1024 fixed) — R3/R10 structure ----------------
// Measured-best: 133.6-134.2 us (QKV), MfmaUtil ~32.5%, 0 bank conflicts. Parked.
template<int QKV>
__global__ __launch_bounds__(512, 2) void gemm256_kernel(
    const u16* __restrict__ A, const u16* __restrict__ BT,
    const float* __restrict__ biasq, const float* __restrict__ biask, const float* __restrict__ biasv,
    u16* __restrict__ oq, u16* __restrict__ ok, u16* __restrict__ ov,
    float* __restrict__ outf,
    float* __restrict__ sumQ, float* __restrict__ sumK, int NBY)
{
  // LDS: A slot0 [0,32K), A slot1 [32K,64K), B slot0 [64K,96K), B slot1 [96K,128K)
  __shared__ __align__(16) u16 smem[65536];
  char* smb = (char*)smem;
  int tid = threadIdx.x;
  int wave = tid >> 6, lane = tid & 63;
  int wm = wave >> 2, wn = wave & 3;          // 2 x 4 wave grid
  int nwg = gridDim.x;
  int q8 = nwg >> 3;
  int id = blockIdx.x;
  int id2 = (id & 7) * q8 + (id >> 3);
  int bx = id2 / NBY, by = id2 % NBY;
  int m0 = bx * 256, n0 = by * 256;
  int srcq = (tid & 7) ^ ((tid >> 3) & 7);
  const u16* aRow = A  + (size_t)(m0 + (tid >> 3)) * 1024 + srcq * 8;
  const u16* bRow = BT + (size_t)(n0 + (tid >> 3)) * 1024 + srcq * 8;

  f32x4 acc[8][4];
  #pragma unroll
  for (int i=0;i<8;i++)
    #pragma unroll
    for (int j=0;j<4;j++) acc[i][j] = (f32x4){0.f,0.f,0.f,0.f};

  int fr = lane & 15, q = lane >> 4;
  int aoff0 = fr*128 + (((q ^ (lane&3)) + 4*((lane>>2)&1)) << 4);
  int aoff1 = fr*128 + (((q ^ (lane&3)) + 4*(1 ^ ((lane>>2)&1))) << 4);

  #define STAGE(s, t) { \
    _Pragma("unroll") \
    for (int i_ = 0; i_ < 4; i_++){ \
      gload16(aRow + (size_t)(t)*64 + (size_t)i_*65536, smb + (s)*32768 + i_*8192 + tid*16); \
      gload16(bRow + (size_t)(t)*64 + (size_t)i_*65536, smb + 65536 + (s)*32768 + i_*8192 + tid*16); \
    } }

  #define COMPUTE(s) { \
    const char* Ab_ = smb + (s)*32768 + wm*16384; \
    const char* Bb_ = smb + 65536 + (s)*32768 + wn*8192; \
    _Pragma("unroll") \
    for (int kk_ = 0; kk_ < 2; kk_++){ \
      int off_ = kk_ ? aoff1 : aoff0; \
      s16x8 af_[8], bf_[4]; \
      _Pragma("unroll") \
      for (int mi_ = 0; mi_ < 8; mi_++) af_[mi_] = *(const s16x8*)(Ab_ + mi_*2048 + off_); \
      _Pragma("unroll") \
      for (int ni_ = 0; ni_ < 4; ni_++) bf_[ni_] = *(const s16x8*)(Bb_ + ni_*2048 + off_); \
      _Pragma("unroll") \
      for (int mi_ = 0; mi_ < 8; mi_++) \
        _Pragma("unroll") \
        for (int ni_ = 0; ni_ < 4; ni_++) \
          acc[mi_][ni_] = mfma16(af_[mi_], bf_[ni_], acc[mi_][ni_]); \
    } }

  STAGE(0, 0)
  STAGE(1, 1)
  for (int t = 0; t < 14; t++){
    asm volatile("s_waitcnt vmcnt(8)" ::: "memory");
    __builtin_amdgcn_s_barrier();
    asm volatile("" ::: "memory");
    COMPUTE(t & 1)
    asm volatile("s_waitcnt lgkmcnt(0)" ::: "memory");
    __builtin_amdgcn_s_barrier();
    asm volatile("" ::: "memory");
    STAGE(t & 1, t + 2)
  }
  asm volatile("s_waitcnt vmcnt(8)" ::: "memory");
  __builtin_amdgcn_s_barrier();
  asm volatile("" ::: "memory");
  COMPUTE(0)
  asm volatile("s_waitcnt vmcnt(0)" ::: "memory");
  __builtin_amdgcn_s_barrier();
  asm volatile("" ::: "memory");
  COMPUTE(1)

  // epilogue
  int colblk = n0 + wn*64;
  int which  = QKV ? (colblk >> 10) : 0;          // 0=q 1=k 2=v
  int cl0    = QKV ? (colblk & 1023) : colblk;
  const float* bias = QKV ? (which==0 ? biasq : (which==1 ? biask : biasv)) : biasq;
  u16* outp = QKV ? (which==0 ? oq : (which==1 ? ok : ov)) : (u16*)0;
  float cs0[4] = {0.f,0.f,0.f,0.f}, cs1[4] = {0.f,0.f,0.f,0.f};
  #pragma unroll
  for (int mi = 0; mi < 8; mi++){
    int row = m0 + wm*128 + mi*16 + (lane>>4)*4;
    #pragma unroll
    for (int ni = 0; ni < 4; ni++){
      int cl = cl0 + ni*16 + fr;
      float bv = bias[cl];
      #pragma unroll
      for (int r = 0; r < 4; r++){
        float val = acc[mi][ni][r] + bv;
        if (QKV){
          if (which < 2) val = sigmoidf_(val);
          outp[(size_t)(row + r) * 1024 + cl] = f2bf(val);
          if (which < 2){ if (mi < 4) cs0[ni] += val; else cs1[ni] += val; }
        } else {
          outf[(size_t)(row + r) * 1024 + cl] = val;
        }
      }
    }
  }
  if (QKV && which < 2){
    float* sums = (which==0) ? sumQ : sumK;
    int bh = (m0 >> 12) * H_ + ((colblk & 1023) >> 6);
    int sc0 = ((m0 & 4095) >> 6) + wm*2;
    #pragma unroll
    for (int h2 = 0; h2 < 2; h2++){
      #pragma unroll
      for (int ni = 0; ni < 4; ni++){
        float s = h2 ? cs1[ni] : cs0[ni];
        s += __shfl_xor(s, 16);
        s += __shfl_xor(s, 32);
        if (lane < 16) sums[((size_t)bh*NSC + sc0 + h2)*64 + ni*16 + fr] = s;
      }
    }
  }
  #undef STAGE
  #undef COMPUTE
}

// ---------------- exclusive scan over scan-chunk axis (2 arrays, in place) ----------------
__global__ __launch_bounds__(64) void scan2_kernel(float* __restrict__ A, float* __restrict__ Bv){
  int bh = blockIdx.x, d = threadIdx.x;
  float ra = 0.f, rb = 0.f;
  for (int g = 0; g < NSC; g += 16){
    float ta[16], tb[16];
    #pragma unroll
    for (int j = 0; j < 16; j++){
      size_t o = ((size_t)bh * NSC + g + j) * 64 + d;
      ta[j] = A[o]; tb[j] = Bv[o];
    }
    #pragma unroll
    for (int j = 0; j < 16; j++){
      size_t o = ((size_t)bh * NSC + g + j) * 64 + d;
      A[o] = ra; Bv[o] = rb;
      ra += ta[j]; rb += tb[j];
    }
  }
}

// ---------------- fused sink_incoming/source_outgoing + mod chunk sums ----------------
// 2-wave split (wave0=q, wave1=k): halves per-wave serial work, ~4.5 waves/SIMD.
// P0 stages the tile vectorized (uint4) into swizzled LDS; P1 column-cumsum IN PLACE
// (column d owned by lane d -> race-free); P2 row dots (global rows, L2-hot);
// P2b swaps raw rows back over dead cumsums; P3 column mod-sums from LDS.
__global__ __launch_bounds__(128) void siso_fused_kernel(
    const u16* __restrict__ q, const u16* __restrict__ k,
    const float* __restrict__ sumQx, const float* __restrict__ sumKx,
    float* __restrict__ si, float* __restrict__ so,
    float* __restrict__ sumQsi, float* __restrict__ sumKso)
{
  __shared__ u16 cq[64*64];
  __shared__ u16 ck[64*64];
  __shared__ float siv[64], sov[64];
  int bhc = blockIdx.x; int bh = bhc >> 6, sc = bhc & 63;
  int b = bh >> 4, h = bh & 15;
  int tid = threadIdx.x, w = tid >> 6, lane = tid & 63;
  size_t gbase = ((size_t)(b*L_ + sc*SC))*DM + h*D_;
  size_t lb = (size_t)bh*L_ + sc*SC;
  const u16* src = w ? k : q;
  u16* ldsT = w ? ck : cq;
  // P0: stage raw tile, swizzled
  {
    int r8 = lane >> 3, c8 = (lane & 7) * 8;
    #pragma unroll
    for (int j = 0; j < 8; j++){
      int l = j*8 + r8;
      uint4 u = *(const uint4*)(src + gbase + (size_t)l*DM + c8);
      const u16* up = (const u16*)&u;
      #pragma unroll
      for (int e = 0; e < 8; e++)
        ldsT[l*64 + ((c8 + e) ^ (l & 31))] = up[e];
    }
  }
  __syncthreads();
  // P1: column cumsum in place (lane = d)
  {
    float run = w ? sumKx[bhc*64 + lane] : sumQx[bhc*64 + lane];
    for (int l = 0; l < SC; l++){
      int sw = lane ^ (l & 31);
      run += bf2f(ldsT[l*64 + sw]);
      ldsT[l*64 + sw] = f2bf(run);
    }
  }
  __syncthreads();
  // P2: row dots. wave0: (q+eps)·(ck+eps) -> si ; wave1: (k+eps)·(cq+eps) -> so
  uint4 rowreg[8];
  {
    int l = lane;
    const u16* row = src + gbase + (size_t)l*DM;
    #pragma unroll
    for (int j=0;j<8;j++) rowreg[j] = ((const uint4*)row)[j];
    const u16* rp = (const u16*)rowreg;
    const u16* other = w ? cq : ck;
    float acc = 0.f;
    #pragma unroll
    for (int d = 0; d < 64; d++){
      int sw = d ^ (l & 31);
      acc += (bf2f(rp[d])+EPSF) * (bf2f(other[l*64+sw])+EPSF);
    }
    float n = (float)(sc*SC + l + 1);
    float vv = n / acc;
    if (w == 0){ si[lb+l] = vv; siv[l] = vv; }
    else       { so[lb+l] = vv; sov[l] = vv; }
  }
  __syncthreads();
  // P2b: raw rows back over dead cumsums
  {
    int l = lane;
    const u16* rp = (const u16*)rowreg;
    #pragma unroll
    for (int d = 0; d < 64; d++)
      ldsT[l*64 + (d ^ (l & 31))] = rp[d];
  }
  __syncthreads();
  // P3: column mod-sums (lane = d)
  {
    const float* sv = w ? sov : siv;
    float s = 0.f;
    for (int l = 0; l < SC; l++){
      int sw = lane ^ (l & 31);
      s += bf2f(ldsT[l*64 + sw]) * sv[l];
    }
    if (w == 0) sumQsi[bhc*64 + lane] = s;
    else        sumKso[bhc*64 + lane] = s;
  }
}

// ---------------- fused conserved_sink/source -> sall, csrc + exp chunk sums ----------------
// Same 2-wave split structure as siso (wave0=q-side/sall, wave1=k-side/csrc+csSum).
__global__ __launch_bounds__(128) void cons_fused_kernel(
    const u16* __restrict__ q, const u16* __restrict__ k,
    const float* __restrict__ si, const float* __restrict__ so,
    const float* __restrict__ sumQsiX, const float* __restrict__ sumKsoX,
    float* __restrict__ csrc, float* __restrict__ sall, float* __restrict__ csSum)
{
  __shared__ u16 cq[64*64];
  __shared__ u16 ck[64*64];
  __shared__ float siv[64], sov[64];
  int bhc = blockIdx.x; int bh = bhc >> 6, sc = bhc & 63;
  int b = bh >> 4, h = bh & 15;
  int tid = threadIdx.x, w = tid >> 6, lane = tid & 63;
  size_t gbase = ((size_t)(b*L_ + sc*SC))*DM + h*D_;
  size_t lb = (size_t)bh*L_ + sc*SC;
  const u16* src = w ? k : q;
  u16* ldsT = w ? ck : cq;
  if (w == 0) siv[lane] = si[lb + lane];
  else        sov[lane] = so[lb + lane];
  // P0: stage raw tile, swizzled
  {
    int r8 = lane >> 3, c8 = (lane & 7) * 8;
    #pragma unroll
    for (int j = 0; j < 8; j++){
      int l = j*8 + r8;
      uint4 u = *(const uint4*)(src + gbase + (size_t)l*DM + c8);
      const u16* up = (const u16*)&u;
      #pragma unroll
      for (int e = 0; e < 8; e++)
        ldsT[l*64 + ((c8 + e) ^ (l & 31))] = up[e];
    }
  }
  __syncthreads();
  // P1: weighted column cumsum in place. wave0: q*siv (carry sumQsiX); wave1: k*sov (carry sumKsoX)
  {
    const float* sv = w ? sov : siv;
    float run = w ? sumKsoX[bhc*64 + lane] : sumQsiX[bhc*64 + lane];
    for (int l = 0; l < SC; l++){
      int sw = lane ^ (l & 31);
      run += bf2f(ldsT[l*64 + sw]) * sv[l];
      ldsT[l*64 + sw] = f2bf(run);
    }
  }
  __syncthreads();
  // P2: row dots. wave0: (q+eps)·(ck+eps) -> sall ; wave1: (k+eps)·(cq+eps) -> csrc, csSum
  {
    int l = lane;
    const u16* row = src + gbase + (size_t)l*DM;
    uint4 rr[8];
    #pragma unroll
    for (int j=0;j<8;j++) rr[j] = ((const uint4*)row)[j];
    const u16* rp = (const u16*)rr;
    const u16* other = w ? cq : ck;
    float acc = 0.f;
    #pragma unroll
    for (int d = 0; d < 64; d++){
      int sw = d ^ (l & 31);
      acc += (bf2f(rp[d])+EPSF) * (bf2f(other[l*64+sw])+EPSF);
    }
    float inv = 1.0f / (float)(sc*SC + l + 1);
    if (w == 0){
      sall[lb+l] = sigmoidf_(acc * inv);
    } else {
      float cs = acc * inv;
      csrc[lb+l] = cs;
      float e = __expf(cs);
      #pragma unroll
      for (int off = 32; off > 0; off >>= 1) e += __shfl_xor(e, off);
      if (lane == 0) csSum[bhc] = e;
    }
  }
}

// ---------------- source_competition (csOff via wave-parallel reduce of csSum) ----------------
__global__ __launch_bounds__(64) void scomp_kernel(
    const float* __restrict__ csrc, const float* __restrict__ csSum,
    float* __restrict__ scomp){
  int bhc = blockIdx.x; int bh = bhc >> 6, sc = bhc & 63;
  int lane = threadIdx.x;
  float v2 = (lane < sc) ? csSum[bh*NSC + lane] : 0.f;
  #pragma unroll
  for (int o = 32; o > 0; o >>= 1) v2 += __shfl_xor(v2, o);
  float off = v2;
  size_t idx = (size_t)bh * L_ + sc * SC + lane;
  float cs = __expf(csrc[idx]);
  float run = cs;
  #pragma unroll
  for (int o = 1; o < 64; o <<= 1){
    float t = __shfl_up(run, o);
    if (lane >= o) run += t;
  }
  scomp[idx] = cs / (off + run) * (float)(sc*SC + lane + 1);
}

// ---------------- per-chunk VK sums via MFMA (R12, measured good) ----------------
__global__ __launch_bounds__(256) void vk_chunk_kernel(
    const u16* __restrict__ k, const u16* __restrict__ v,
    const float* __restrict__ scomp, float* __restrict__ vkc){
  __shared__ __align__(16) u16 vt[64*128];   // (v*scomp)^T [m][l] swz
  __shared__ __align__(16) u16 kt[64*128];   // k^T [d][l] swz
  int bhc = blockIdx.x; int bh = bhc >> 5, c = bhc & 31;
  int b = bh >> 4, h = bh & 15;
  int tid = threadIdx.x, wave = tid >> 6, lane = tid & 63;
  size_t gbase = ((size_t)(b * L_ + c * CS)) * DM + h * D_;
  size_t sbase = (size_t)bh * L_ + c * CS;
  {
    int r = tid >> 1;            // source row l = 0..127
    int cc = (tid & 1) * 32;     // d-half
    float vscale = scomp[sbase + r];
    #pragma unroll
    for (int j = 0; j < 4; j++){
      uint4 ku = *(const uint4*)(k + gbase + (size_t)r * DM + cc + j*8);
      uint4 vu = *(const uint4*)(v + gbase + (size_t)r * DM + cc + j*8);
      const u16* kp = (const u16*)&ku; const u16* vp = (const u16*)&vu;
      #pragma unroll
      for (int e = 0; e < 8; e++){
        int m = cc + j*8 + e;
        int idx = m*128 + ((((r >> 3) ^ (m & 7)) << 3) | (r & 7));
        vt[idx] = f2bf(bf2f(vp[e]) * vscale);
        kt[idx] = kp[e];
      }
    }
  }
  __syncthreads();
  int fr = lane & 15, q = lane >> 4;
  int mt = wave;                 // m-tile (16 rows) per wave
  f32x4 acc[4];
  #pragma unroll
  for (int i = 0; i < 4; i++) acc[i] = (f32x4){0.f,0.f,0.f,0.f};
  #pragma unroll
  for (int ks = 0; ks < 4; ks++){
    int lc = ks*4 + q;           // logical 16B l-chunk
    int off = ((lc ^ (fr & 7)) << 3);
    s16x8 av = *(const s16x8*)&vt[(mt*16 + fr)*128 + off];
    #pragma unroll
    for (int nt = 0; nt < 4; nt++){
      s16x8 bk = *(const s16x8*)&kt[(nt*16 + fr)*128 + off];
      acc[nt] = mfma16(av, bk, acc[nt]);
    }
  }
  float* outp = vkc + (size_t)bhc * (D_*D_);
  #pragma unroll
  for (int nt = 0; nt < 4; nt++)
    #pragma unroll
    for (int r = 0; r < 4; r++)
      outp[(mt*16 + q*4 + r)*64 + nt*16 + fr] = acc[nt][r];
}

// ---------------- exclusive scan of VK over chunks: fp32 in -> bf16 prefix out ----------------
__global__ __launch_bounds__(256) void vk_scan_kernel(const float* __restrict__ vkc, u16* __restrict__ vkb){
  int idx = blockIdx.x * 256 + threadIdx.x;   // over BH*4096
  int bh = idx >> 12;
  int e  = idx & 4095;
  size_t base = ((size_t)bh * NC) * 4096 + e;
  float run = 0.f;
  for (int g = 0; g < NC; g += 16){
    float tv[16];
    #pragma unroll
    for (int j = 0; j < 16; j++) tv[j] = vkc[base + (size_t)(g + j) * 4096];
    #pragma unroll
    for (int j = 0; j < 16; j++){
      vkb[base + (size_t)(g + j) * 4096] = f2bf(run);
      run += tv[j];
    }
  }
}

// ---------------- causal attention per (bh, chunk) — R13 (swizzled, measured good) ----------------
__global__ __launch_bounds__(256) void attn_kernel(
    const u16* __restrict__ q, const u16* __restrict__ k, const u16* __restrict__ v,
    const float* __restrict__ si, const float* __restrict__ scomp, const float* __restrict__ salloc,
    const u16* __restrict__ vkb, u16* __restrict__ attnout)
{
  __shared__ __align__(16) u16 qs[128*64];    // qmod rows [l][d] swz
  __shared__ __align__(16) u16 ks2[128*64];   // k rows    [j][d] swz
  __shared__ __align__(16) u16 vts[64*128];   // (v*scomp)^T [m][j] swz
  __shared__ __align__(16) u16 vks[64*64];    // VKprev [m][d] swz
  __shared__ __align__(16) u16 ss[128*64];    // masked S half [l][j-in-64] swz
  int bhc = blockIdx.x; int bh = bhc >> 5, c = bhc & 31;
  int b = bh >> 4, h = bh & 15;
  int tid = threadIdx.x, wave = tid >> 6, lane = tid & 63;
  size_t gbase = ((size_t)(b * L_ + c * CS)) * DM + h * D_;
  size_t sbase = (size_t)bh * L_ + c * CS;
  {
    int r = tid >> 1;
    int cc = (tid & 1) * 32;
    int l = c * CS + r;
    float qscale = si[sbase + r] / (float)(l + 1);
    float vscale = scomp[sbase + r];
    #pragma unroll
    for (int j = 0; j < 4; j++){
      int d0 = cc + j*8;
      uint4 qu = *(const uint4*)(q + gbase + (size_t)r * DM + d0);
      uint4 kuv = *(const uint4*)(k + gbase + (size_t)r * DM + d0);
      uint4 vu = *(const uint4*)(v + gbase + (size_t)r * DM + d0);
      const u16* qp = (const u16*)&qu; const u16* vp = (const u16*)&vu;
      u16 tmp[8];
      #pragma unroll
      for (int e = 0; e < 8; e++) tmp[e] = f2bf(bf2f(qp[e]) * qscale);
      int csw = ((d0 >> 3) ^ (r & 7)) << 3;           // swizzled d-chunk
      *(uint4*)&qs[r*64 + csw]  = *(uint4*)tmp;
      *(uint4*)&ks2[r*64 + csw] = kuv;
      #pragma unroll
      for (int e = 0; e < 8; e++){
        int m = d0 + e;
        int jsw = (((r >> 3) ^ (m & 7)) << 3) | (r & 7);  // swizzled j position
        vts[m*128 + jsw] = f2bf(bf2f(vp[e]) * vscale);
      }
    }
    const u16* vkp = vkb + (size_t)bhc * (D_*D_) + tid * 16;
    int m = tid >> 2, dq = (tid & 3) * 2;               // two d-chunks per thread
    int o0 = ((dq     ^ (m & 7)) << 3);
    int o1 = (((dq+1) ^ (m & 7)) << 3);
    *(uint4*)&vks[m*64 + o0] = *(const uint4*)(vkp);
    *(uint4*)&vks[m*64 + o1] = *(const uint4*)(vkp + 8);
  }
  __syncthreads();
  int t0 = wave, t1 = 7 - wave;   // balanced l-tile pair per wave
  int fr = lane & 15, qh = lane >> 4;
  int f7 = fr & 7;
  f32x4 acc[2][4];
  #pragma unroll
  for (int i=0;i<2;i++)
    #pragma unroll
    for (int j=0;j<4;j++) acc[i][j] = (f32x4){0.f,0.f,0.f,0.f};
  s16x8 aq[2][2];
  #pragma unroll
  for (int ti = 0; ti < 2; ti++){
    int t = ti ? t1 : t0;
    #pragma unroll
    for (int kk = 0; kk < 2; kk++){
      int oc = (((kk*4 + qh) ^ f7) << 3);
      aq[ti][kk] = *(const s16x8*)&qs[(t*16 + fr)*64 + oc];
    }
  }
  // inter-chunk: qmod @ VKprev^T
  #pragma unroll
  for (int mt = 0; mt < 4; mt++){
    #pragma unroll
    for (int kk = 0; kk < 2; kk++){
      int oc = (((kk*4 + qh) ^ f7) << 3);
      s16x8 bv = *(const s16x8*)&vks[(mt*16 + fr)*64 + oc];
      acc[0][mt] = mfma16(aq[0][kk], bv, acc[0][mt]);
      acc[1][mt] = mfma16(aq[1][kk], bv, acc[1][mt]);
    }
  }
  // intra-chunk, two 64-j halves
  for (int jt2 = 0; jt2 < 2; jt2++){
    __syncthreads();
    #pragma unroll
    for (int ti = 0; ti < 2; ti++){
      int t = ti ? t1 : t0;
      #pragma unroll
      for (int u = 0; u < 4; u++){
        int jj = jt2*4 + u;
        f32x4 sacc = (f32x4){0.f,0.f,0.f,0.f};
        if (jj <= t){
          #pragma unroll
          for (int kk = 0; kk < 2; kk++){
            int oc = (((kk*4 + qh) ^ f7) << 3);
            s16x8 bkf = *(const s16x8*)&ks2[(jj*16 + fr)*64 + oc];
            sacc = mfma16(aq[ti][kk], bkf, sacc);
          }
        }
        int lrow = t*16 + qh*4;
        int jcol = jj*16 + fr;
        int cst = u*2 + (fr >> 3);          // strip-local logical chunk
        #pragma unroll
        for (int r = 0; r < 4; r++){
          float sv = (jcol <= lrow + r) ? sacc[r] : 0.f;
          int row = lrow + r;
          ss[row*64 + (((cst ^ (row & 7)) << 3) | f7)] = f2bf(sv);
        }
      }
    }
    __syncthreads();
    #pragma unroll
    for (int ti = 0; ti < 2; ti++){
      int t = ti ? t1 : t0;
      #pragma unroll
      for (int ks = 0; ks < 2; ks++){
        if (jt2*64 + ks*32 <= t*16 + 15){
          int ocs = (((ks*4 + qh) ^ f7) << 3);
          s16x8 as = *(const s16x8*)&ss[(t*16 + fr)*64 + ocs];
          #pragma unroll
          for (int mt = 0; mt < 4; mt++){
            int lc = jt2*8 + ks*4 + qh;
            int ocv = ((lc ^ f7) << 3);
            s16x8 bvv = *(const s16x8*)&vts[(mt*16 + fr)*128 + ocv];
            acc[ti][mt] = mfma16(as, bvv, acc[ti][mt]);
          }
        }
      }
    }
  }
  // epilogue: * sink_allocation, write bf16 [B,L,DM]
  #pragma unroll
  for (int ti = 0; ti < 2; ti++){
    int t = ti ? t1 : t0;
    int lrow = t*16 + qh*4;
    #pragma unroll
    for (int r = 0; r < 4; r++){
      float sa = salloc[sbase + lrow + r];
      size_t orow = ((size_t)(b * L_ + c * CS + lrow + r)) * DM + h * D_;
      #pragma unroll
      for (int mt = 0; mt < 4; mt++){
        attnout[orow + mt*16 + fr] = f2bf(acc[ti][mt][r] * sa);
      }
    }
  }
}

extern "C" void kernel_launch(void* const* d_in, const int* in_sizes, int n_in,
                              void* d_out, int out_size, void* d_ws, size_t ws_size,
                              hipStream_t stream){
  (void)in_sizes; (void)n_in; (void)out_size; (void)ws_size;
  const float* x  = (const float*)d_in[0];
  const float* Wq = (const float*)d_in[1];
  const float* bq = (const float*)d_in[2];
  const float* Wk = (const float*)d_in[3];
  const float* bk = (const float*)d_in[4];
  const float* Wv = (const float*)d_in[5];
  const float* bv = (const float*)d_in[6];
  const float* Wo = (const float*)d_in[7];
  const float* bo = (const float*)d_in[8];

  char* p = (char*)d_ws;
  auto carve = [&](size_t bytes) -> void* {
    void* r = (void*)p; p += (bytes + 255) & ~(size_t)255; return r;
  };
  u16* xb    = (u16*)carve((size_t)N_*DM*2);
  u16* wqkvT = (u16*)carve((size_t)3*DM*DM*2);
  u16* woT   = (u16*)carve((size_t)DM*DM*2);
  u16* qb  = (u16*)carve((size_t)N_*DM*2);
  u16* kb  = (u16*)carve((size_t)N_*DM*2);
  u16* vb  = (u16*)carve((size_t)N_*DM*2);
  u16* ao  = (u16*)carve((size_t)N_*DM*2);
  float* si   = (float*)carve((size_t)BH*L_*4);
  float* so   = (float*)carve((size_t)BH*L_*4);
  float* csrc = (float*)carve((size_t)BH*L_*4);
  float* sall = (float*)carve((size_t)BH*L_*4);
  float* scmp = (float*)carve((size_t)BH*L_*4);
  float* sumQ   = (float*)carve((size_t)BH*NSC*D_*4);
  float* sumK   = (float*)carve((size_t)BH*NSC*D_*4);
  float* sumQsi = (float*)carve((size_t)BH*NSC*D_*4);
  float* sumKso = (float*)carve((size_t)BH*NSC*D_*4);
  float* csSum  = (float*)carve((size_t)BH*NSC*4);
  float* vkc    = (float*)carve((size_t)BH*NC*(size_t)(D_*D_)*4);
  u16*   vkb    = (u16*)carve((size_t)BH*NC*(size_t)(D_*D_)*2);

  // 1. conversions
  cvt_kernel<<<(N_*DM/4 + 255)/256, 256, 0, stream>>>(x, xb, N_*DM/4);
  transpose_w4_kernel<<<dim3(DM/64, DM/64, 4), 256, 0, stream>>>(Wq, Wk, Wv, Wo, wqkvT, woT);
  // 2. fused q,k,v projection (one 16384x3072x1024 GEMM) + per-scan-chunk sums
  gemm256_kernel<1><<<dim3((N_/256)*(3*DM/256)), 512, 0, stream>>>(
      xb, wqkvT, bq, bk, bv, qb, kb, vb, nullptr, sumQ, sumK, 3*DM/256);
  // 3. normalizer pipeline
  scan2_kernel<<<BH, 64, 0, stream>>>(sumQ, sumK);
  siso_fused_kernel<<<BH*NSC, 128, 0, stream>>>(qb, kb, sumQ, sumK, si, so, sumQsi, sumKso);
  scan2_kernel<<<BH, 64, 0, stream>>>(sumQsi, sumKso);
  cons_fused_kernel<<<BH*NSC, 128, 0, stream>>>(qb, kb, si, so, sumQsi, sumKso, csrc, sall, csSum);
  scomp_kernel<<<BH*NSC, 64, 0, stream>>>(csrc, csSum, scmp);
  // 4. causal linear attention
  vk_chunk_kernel<<<BH*NC, 256, 0, stream>>>(kb, vb, scmp, vkc);
  vk_scan_kernel<<<(BH*D_*D_)/256, 256, 0, stream>>>(vkc, vkb);
  attn_kernel<<<BH*NC, 256, 0, stream>>>(qb, kb, vb, si, scmp, sall, vkb, ao);
  // 5. output projection
  gemm256_kernel<0><<<dim3((N_/256)*(DM/256)), 512, 0, stream>>>(
      ao, woT, bo, bo, bo, nullptr, nullptr, nullptr, (float*)d_out, nullptr, nullptr, DM/256);
}

// Round 15
// 316.291 us; speedup vs baseline: 1.2274x; 1.0365x over previous
//
#include <hip/hip_runtime.h>
#include <stdint.h>

// Problem constants (fixed by setup_inputs)
#define B_ 4
#define L_ 4096
#define DM 1024
#define H_ 16
#define D_ 64
#define BH (B_*H_)      // 64
#define N_ (B_*L_)      // 16384
#define CS 128          // chunk size for causal attention
#define NC (L_/CS)      // 32
#define SC 64           // chunk size for normalizer scans
#define NSC (L_/SC)     // 64
#define EPSF 1e-6f

typedef unsigned short u16;
typedef unsigned int   u32;
typedef __attribute__((ext_vector_type(8))) short s16x8;
typedef __attribute__((ext_vector_type(4))) float f32x4;

__device__ __forceinline__ float bf2f(u16 u){
  union { u32 i; float f; } v; v.i = ((u32)u) << 16; return v.f;
}
__device__ __forceinline__ u16 f2bf(float f){
  union { float f; u32 i; } v; v.f = f;
  u32 i = v.i;
  return (u16)((i + 0x7fffu + ((i >> 16) & 1u)) >> 16);  // RNE
}
__device__ __forceinline__ void gload16(const void* g, void* l){
  __builtin_amdgcn_global_load_lds(
      (const __attribute__((address_space(1))) u32*)g,
      (__attribute__((address_space(3))) u32*)l, 16, 0, 0);
}
__device__ __forceinline__ f32x4 mfma16(s16x8 a, s16x8 b, f32x4 c){
  return __builtin_amdgcn_mfma_f32_16x16x32_bf16(a, b, c, 0, 0, 0);
}
__device__ __forceinline__ float sigmoidf_(float x){ return 1.0f/(1.0f+__expf(-x)); }

// ---------------- prep: fp32->bf16 cvt + 4x W transpose (one launch) ----------------
__global__ __launch_bounds__(256) void prep_kernel(
    const float* __restrict__ x,
    const float* __restrict__ Wq, const float* __restrict__ Wk,
    const float* __restrict__ Wv, const float* __restrict__ Wo,
    u16* __restrict__ xb, u16* __restrict__ wqkvT, u16* __restrict__ woT){
  __shared__ float t[64][65];
  int bid = blockIdx.x;
  if (bid < 16384){
    int i = bid * 256 + threadIdx.x;          // over N_*DM/4 = 4194304
    float4 v = ((const float4*)x)[i];
    union { u16 s[4]; uint2 u; } o;
    o.s[0]=f2bf(v.x); o.s[1]=f2bf(v.y); o.s[2]=f2bf(v.z); o.s[3]=f2bf(v.w);
    ((uint2*)xb)[i] = o.u;
    return;
  }
  int w = bid - 16384;
  int z = w >> 8, w2 = w & 255;
  const float* W = (z==0) ? Wq : (z==1) ? Wk : (z==2) ? Wv : Wo;
  u16* WT = (z<3) ? (wqkvT + (size_t)z*DM*DM) : woT;
  int n0 = (w2 & 15) * 64, k0 = (w2 >> 4) * 64;
  int tx = threadIdx.x & 63, ty = threadIdx.x >> 6;
  #pragma unroll
  for (int s = 0; s < 64; s += 4)
    t[ty + s][tx] = W[(size_t)(k0 + ty + s) * DM + n0 + tx];
  __syncthreads();
  #pragma unroll
  for (int s = 0; s < 64; s += 4)
    WT[(size_t)(n0 + ty + s) * DM + k0 + tx] = f2bf(t[tx][ty + s]);
}

// ---------------- 256x256 counted-vmcnt MFMA GEMM (K=1024 fixed) — R3/R10 structure ----------------
// Measured-best: 133.6-134.2 us (QKV), MfmaUtil ~32.5%, 0 bank conflicts. PARKED:
// at K=1024 (16 K-tiles) three schedules converge at ~770 TF; 8-phase null twice.
template<int QKV>
__global__ __launch_bounds__(512, 2) void gemm256_kernel(
    const u16* __restrict__ A, const u16* __restrict__ BT,
    const float* __restrict__ biasq, const float* __restrict__ biask, const float* __restrict__ biasv,
    u16* __restrict__ oq, u16* __restrict__ ok, u16* __restrict__ ov,
    float* __restrict__ outf,
    float* __restrict__ sumQ, float* __restrict__ sumK, int NBY)
{
  // LDS: A slot0 [0,32K), A slot1 [32K,64K), B slot0 [64K,96K), B slot1 [96K,128K)
  __shared__ __align__(16) u16 smem[65536];
  char* smb = (char*)smem;
  int tid = threadIdx.x;
  int wave = tid >> 6, lane = tid & 63;
  int wm = wave >> 2, wn = wave & 3;          // 2 x 4 wave grid
  int nwg = gridDim.x;
  int q8 = nwg >> 3;
  int id = blockIdx.x;
  int id2 = (id & 7) * q8 + (id >> 3);
  int bx = id2 / NBY, by = id2 % NBY;
  int m0 = bx * 256, n0 = by * 256;
  int srcq = (tid & 7) ^ ((tid >> 3) & 7);
  const u16* aRow = A  + (size_t)(m0 + (tid >> 3)) * 1024 + srcq * 8;
  const u16* bRow = BT + (size_t)(n0 + (tid >> 3)) * 1024 + srcq * 8;

  f32x4 acc[8][4];
  #pragma unroll
  for (int i=0;i<8;i++)
    #pragma unroll
    for (int j=0;j<4;j++) acc[i][j] = (f32x4){0.f,0.f,0.f,0.f};

  int fr = lane & 15, q = lane >> 4;
  int aoff0 = fr*128 + (((q ^ (lane&3)) + 4*((lane>>2)&1)) << 4);
  int aoff1 = fr*128 + (((q ^ (lane&3)) + 4*(1 ^ ((lane>>2)&1))) << 4);

  #define STAGE(s, t) { \
    _Pragma("unroll") \
    for (int i_ = 0; i_ < 4; i_++){ \
      gload16(aRow + (size_t)(t)*64 + (size_t)i_*65536, smb + (s)*32768 + i_*8192 + tid*16); \
      gload16(bRow + (size_t)(t)*64 + (size_t)i_*65536, smb + 65536 + (s)*32768 + i_*8192 + tid*16); \
    } }

  #define COMPUTE(s) { \
    const char* Ab_ = smb + (s)*32768 + wm*16384; \
    const char* Bb_ = smb + 65536 + (s)*32768 + wn*8192; \
    _Pragma("unroll") \
    for (int kk_ = 0; kk_ < 2; kk_++){ \
      int off_ = kk_ ? aoff1 : aoff0; \
      s16x8 af_[8], bf_[4]; \
      _Pragma("unroll") \
      for (int mi_ = 0; mi_ < 8; mi_++) af_[mi_] = *(const s16x8*)(Ab_ + mi_*2048 + off_); \
      _Pragma("unroll") \
      for (int ni_ = 0; ni_ < 4; ni_++) bf_[ni_] = *(const s16x8*)(Bb_ + ni_*2048 + off_); \
      _Pragma("unroll") \
      for (int mi_ = 0; mi_ < 8; mi_++) \
        _Pragma("unroll") \
        for (int ni_ = 0; ni_ < 4; ni_++) \
          acc[mi_][ni_] = mfma16(af_[mi_], bf_[ni_], acc[mi_][ni_]); \
    } }

  STAGE(0, 0)
  STAGE(1, 1)
  for (int t = 0; t < 14; t++){
    asm volatile("s_waitcnt vmcnt(8)" ::: "memory");
    __builtin_amdgcn_s_barrier();
    asm volatile("" ::: "memory");
    COMPUTE(t & 1)
    asm volatile("s_waitcnt lgkmcnt(0)" ::: "memory");
    __builtin_amdgcn_s_barrier();
    asm volatile("" ::: "memory");
    STAGE(t & 1, t + 2)
  }
  asm volatile("s_waitcnt vmcnt(8)" ::: "memory");
  __builtin_amdgcn_s_barrier();
  asm volatile("" ::: "memory");
  COMPUTE(0)
  asm volatile("s_waitcnt vmcnt(0)" ::: "memory");
  __builtin_amdgcn_s_barrier();
  asm volatile("" ::: "memory");
  COMPUTE(1)

  // epilogue
  int colblk = n0 + wn*64;
  int which  = QKV ? (colblk >> 10) : 0;          // 0=q 1=k 2=v
  int cl0    = QKV ? (colblk & 1023) : colblk;
  const float* bias = QKV ? (which==0 ? biasq : (which==1 ? biask : biasv)) : biasq;
  u16* outp = QKV ? (which==0 ? oq : (which==1 ? ok : ov)) : (u16*)0;
  float cs0[4] = {0.f,0.f,0.f,0.f}, cs1[4] = {0.f,0.f,0.f,0.f};
  #pragma unroll
  for (int mi = 0; mi < 8; mi++){
    int row = m0 + wm*128 + mi*16 + (lane>>4)*4;
    #pragma unroll
    for (int ni = 0; ni < 4; ni++){
      int cl = cl0 + ni*16 + fr;
      float bv = bias[cl];
      #pragma unroll
      for (int r = 0; r < 4; r++){
        float val = acc[mi][ni][r] + bv;
        if (QKV){
          if (which < 2) val = sigmoidf_(val);
          outp[(size_t)(row + r) * 1024 + cl] = f2bf(val);
          if (which < 2){ if (mi < 4) cs0[ni] += val; else cs1[ni] += val; }
        } else {
          outf[(size_t)(row + r) * 1024 + cl] = val;
        }
      }
    }
  }
  if (QKV && which < 2){
    float* sums = (which==0) ? sumQ : sumK;
    int bh = (m0 >> 12) * H_ + ((colblk & 1023) >> 6);
    int sc0 = ((m0 & 4095) >> 6) + wm*2;
    #pragma unroll
    for (int h2 = 0; h2 < 2; h2++){
      #pragma unroll
      for (int ni = 0; ni < 4; ni++){
        float s = h2 ? cs1[ni] : cs0[ni];
        s += __shfl_xor(s, 16);
        s += __shfl_xor(s, 32);
        if (lane < 16) sums[((size_t)bh*NSC + sc0 + h2)*64 + ni*16 + fr] = s;
      }
    }
  }
  #undef STAGE
  #undef COMPUTE
}

// ---------------- exclusive scan over scan-chunk axis (2 arrays, in place) ----------------
__global__ __launch_bounds__(64) void scan2_kernel(float* __restrict__ A, float* __restrict__ Bv){
  int bh = blockIdx.x, d = threadIdx.x;
  float ra = 0.f, rb = 0.f;
  for (int g = 0; g < NSC; g += 16){
    float ta[16], tb[16];
    #pragma unroll
    for (int j = 0; j < 16; j++){
      size_t o = ((size_t)bh * NSC + g + j) * 64 + d;
      ta[j] = A[o]; tb[j] = Bv[o];
    }
    #pragma unroll
    for (int j = 0; j < 16; j++){
      size_t o = ((size_t)bh * NSC + g + j) * 64 + d;
      A[o] = ra; Bv[o] = rb;
      ra += ta[j]; rb += tb[j];
    }
  }
}

// ---------------- fused sink_incoming/source_outgoing + mod chunk sums (R14) ----------------
__global__ __launch_bounds__(128) void siso_fused_kernel(
    const u16* __restrict__ q, const u16* __restrict__ k,
    const float* __restrict__ sumQx, const float* __restrict__ sumKx,
    float* __restrict__ si, float* __restrict__ so,
    float* __restrict__ sumQsi, float* __restrict__ sumKso)
{
  __shared__ u16 cq[64*64];
  __shared__ u16 ck[64*64];
  __shared__ float siv[64], sov[64];
  int bhc = blockIdx.x; int bh = bhc >> 6, sc = bhc & 63;
  int b = bh >> 4, h = bh & 15;
  int tid = threadIdx.x, w = tid >> 6, lane = tid & 63;
  size_t gbase = ((size_t)(b*L_ + sc*SC))*DM + h*D_;
  size_t lb = (size_t)bh*L_ + sc*SC;
  const u16* src = w ? k : q;
  u16* ldsT = w ? ck : cq;
  // P0: stage raw tile, swizzled
  {
    int r8 = lane >> 3, c8 = (lane & 7) * 8;
    #pragma unroll
    for (int j = 0; j < 8; j++){
      int l = j*8 + r8;
      uint4 u = *(const uint4*)(src + gbase + (size_t)l*DM + c8);
      const u16* up = (const u16*)&u;
      #pragma unroll
      for (int e = 0; e < 8; e++)
        ldsT[l*64 + ((c8 + e) ^ (l & 31))] = up[e];
    }
  }
  __syncthreads();
  // P1: column cumsum in place (lane = d)
  {
    float run = w ? sumKx[bhc*64 + lane] : sumQx[bhc*64 + lane];
    for (int l = 0; l < SC; l++){
      int sw = lane ^ (l & 31);
      run += bf2f(ldsT[l*64 + sw]);
      ldsT[l*64 + sw] = f2bf(run);
    }
  }
  __syncthreads();
  // P2: row dots
  uint4 rowreg[8];
  {
    int l = lane;
    const u16* row = src + gbase + (size_t)l*DM;
    #pragma unroll
    for (int j=0;j<8;j++) rowreg[j] = ((const uint4*)row)[j];
    const u16* rp = (const u16*)rowreg;
    const u16* other = w ? cq : ck;
    float acc = 0.f;
    #pragma unroll
    for (int d = 0; d < 64; d++){
      int sw = d ^ (l & 31);
      acc += (bf2f(rp[d])+EPSF) * (bf2f(other[l*64+sw])+EPSF);
    }
    float n = (float)(sc*SC + l + 1);
    float vv = n / acc;
    if (w == 0){ si[lb+l] = vv; siv[l] = vv; }
    else       { so[lb+l] = vv; sov[l] = vv; }
  }
  __syncthreads();
  // P2b: raw rows back over dead cumsums
  {
    int l = lane;
    const u16* rp = (const u16*)rowreg;
    #pragma unroll
    for (int d = 0; d < 64; d++)
      ldsT[l*64 + (d ^ (l & 31))] = rp[d];
  }
  __syncthreads();
  // P3: column mod-sums (lane = d)
  {
    const float* sv = w ? sov : siv;
    float s = 0.f;
    for (int l = 0; l < SC; l++){
      int sw = lane ^ (l & 31);
      s += bf2f(ldsT[l*64 + sw]) * sv[l];
    }
    if (w == 0) sumQsi[bhc*64 + lane] = s;
    else        sumKso[bhc*64 + lane] = s;
  }
}

// ---------------- fused conserved_sink/source -> sall, csrc + exp chunk sums (R14) ----------------
__global__ __launch_bounds__(128) void cons_fused_kernel(
    const u16* __restrict__ q, const u16* __restrict__ k,
    const float* __restrict__ si, const float* __restrict__ so,
    const float* __restrict__ sumQsiX, const float* __restrict__ sumKsoX,
    float* __restrict__ csrc, float* __restrict__ sall, float* __restrict__ csSum)
{
  __shared__ u16 cq[64*64];
  __shared__ u16 ck[64*64];
  __shared__ float siv[64], sov[64];
  int bhc = blockIdx.x; int bh = bhc >> 6, sc = bhc & 63;
  int b = bh >> 4, h = bh & 15;
  int tid = threadIdx.x, w = tid >> 6, lane = tid & 63;
  size_t gbase = ((size_t)(b*L_ + sc*SC))*DM + h*D_;
  size_t lb = (size_t)bh*L_ + sc*SC;
  const u16* src = w ? k : q;
  u16* ldsT = w ? ck : cq;
  if (w == 0) siv[lane] = si[lb + lane];
  else        sov[lane] = so[lb + lane];
  // P0: stage raw tile, swizzled
  {
    int r8 = lane >> 3, c8 = (lane & 7) * 8;
    #pragma unroll
    for (int j = 0; j < 8; j++){
      int l = j*8 + r8;
      uint4 u = *(const uint4*)(src + gbase + (size_t)l*DM + c8);
      const u16* up = (const u16*)&u;
      #pragma unroll
      for (int e = 0; e < 8; e++)
        ldsT[l*64 + ((c8 + e) ^ (l & 31))] = up[e];
    }
  }
  __syncthreads();
  // P1: weighted column cumsum in place
  {
    const float* sv = w ? sov : siv;
    float run = w ? sumKsoX[bhc*64 + lane] : sumQsiX[bhc*64 + lane];
    for (int l = 0; l < SC; l++){
      int sw = lane ^ (l & 31);
      run += bf2f(ldsT[l*64 + sw]) * sv[l];
      ldsT[l*64 + sw] = f2bf(run);
    }
  }
  __syncthreads();
  // P2: row dots
  {
    int l = lane;
    const u16* row = src + gbase + (size_t)l*DM;
    uint4 rr[8];
    #pragma unroll
    for (int j=0;j<8;j++) rr[j] = ((const uint4*)row)[j];
    const u16* rp = (const u16*)rr;
    const u16* other = w ? cq : ck;
    float acc = 0.f;
    #pragma unroll
    for (int d = 0; d < 64; d++){
      int sw = d ^ (l & 31);
      acc += (bf2f(rp[d])+EPSF) * (bf2f(other[l*64+sw])+EPSF);
    }
    float inv = 1.0f / (float)(sc*SC + l + 1);
    if (w == 0){
      sall[lb+l] = sigmoidf_(acc * inv);
    } else {
      float cs = acc * inv;
      csrc[lb+l] = cs;
      float e = __expf(cs);
      #pragma unroll
      for (int off = 32; off > 0; off >>= 1) e += __shfl_xor(e, off);
      if (lane == 0) csSum[bhc] = e;
    }
  }
}

// ---------------- per-chunk VK sums via MFMA, with source_competition fused in ----------------
// Waves 0-1 first compute scmp for this chunk's two scan-chunks (identical arithmetic
// to the old scomp_kernel -> bit-identical), write to global (attn reads it) and LDS.
__global__ __launch_bounds__(256) void vk_chunk_kernel(
    const u16* __restrict__ k, const u16* __restrict__ v,
    const float* __restrict__ csrc, const float* __restrict__ csSum,
    float* __restrict__ scomp, float* __restrict__ vkc){
  __shared__ __align__(16) u16 vt[64*128];   // (v*scomp)^T [m][l] swz
  __shared__ __align__(16) u16 kt[64*128];   // k^T [d][l] swz
  __shared__ float scmpv[128];
  int bhc = blockIdx.x; int bh = bhc >> 5, c = bhc & 31;
  int b = bh >> 4, h = bh & 15;
  int tid = threadIdx.x, wave = tid >> 6, lane = tid & 63;
  size_t gbase = ((size_t)(b * L_ + c * CS)) * DM + h * D_;
  // Phase A: scmp for scan-chunks sc = 2c + {0,1}
  if (wave < 2){
    int sc = c*2 + wave;
    float v2 = (lane < sc) ? csSum[bh*NSC + lane] : 0.f;
    #pragma unroll
    for (int o = 32; o > 0; o >>= 1) v2 += __shfl_xor(v2, o);
    float off = v2;
    size_t idx = (size_t)bh * L_ + sc * SC + lane;
    float cs = __expf(csrc[idx]);
    float run = cs;
    #pragma unroll
    for (int o = 1; o < 64; o <<= 1){
      float t = __shfl_up(run, o);
      if (lane >= o) run += t;
    }
    float sm = cs / (off + run) * (float)(sc*SC + lane + 1);
    scomp[idx] = sm;
    scmpv[wave*64 + lane] = sm;
  }
  __syncthreads();
  // Phase B: stage transposed tiles (v scaled by scmp from LDS)
  {
    int r = tid >> 1;            // source row l = 0..127
    int cc = (tid & 1) * 32;     // d-half
    float vscale = scmpv[r];
    #pragma unroll
    for (int j = 0; j < 4; j++){
      uint4 ku = *(const uint4*)(k + gbase + (size_t)r * DM + cc + j*8);
      uint4 vu = *(const uint4*)(v + gbase + (size_t)r * DM + cc + j*8);
      const u16* kp = (const u16*)&ku; const u16* vp = (const u16*)&vu;
      #pragma unroll
      for (int e = 0; e < 8; e++){
        int m = cc + j*8 + e;
        int idx = m*128 + ((((r >> 3) ^ (m & 7)) << 3) | (r & 7));
        vt[idx] = f2bf(bf2f(vp[e]) * vscale);
        kt[idx] = kp[e];
      }
    }
  }
  __syncthreads();
  int fr = lane & 15, q = lane >> 4;
  int mt = wave;                 // m-tile (16 rows) per wave
  f32x4 acc[4];
  #pragma unroll
  for (int i = 0; i < 4; i++) acc[i] = (f32x4){0.f,0.f,0.f,0.f};
  #pragma unroll
  for (int ks = 0; ks < 4; ks++){
    int lc = ks*4 + q;           // logical 16B l-chunk
    int off = ((lc ^ (fr & 7)) << 3);
    s16x8 av = *(const s16x8*)&vt[(mt*16 + fr)*128 + off];
    #pragma unroll
    for (int nt = 0; nt < 4; nt++){
      s16x8 bk = *(const s16x8*)&kt[(nt*16 + fr)*128 + off];
      acc[nt] = mfma16(av, bk, acc[nt]);
    }
  }
  float* outp = vkc + (size_t)bhc * (D_*D_);
  #pragma unroll
  for (int nt = 0; nt < 4; nt++)
    #pragma unroll
    for (int r = 0; r < 4; r++)
      outp[(mt*16 + q*4 + r)*64 + nt*16 + fr] = acc[nt][r];
}

// ---------------- exclusive scan of VK over chunks: fp32 in -> bf16 prefix out ----------------
__global__ __launch_bounds__(256) void vk_scan_kernel(const float* __restrict__ vkc, u16* __restrict__ vkb){
  int idx = blockIdx.x * 256 + threadIdx.x;   // over BH*4096
  int bh = idx >> 12;
  int e  = idx & 4095;
  size_t base = ((size_t)bh * NC) * 4096 + e;
  float run = 0.f;
  for (int g = 0; g < NC; g += 16){
    float tv[16];
    #pragma unroll
    for (int j = 0; j < 16; j++) tv[j] = vkc[base + (size_t)(g + j) * 4096];
    #pragma unroll
    for (int j = 0; j < 16; j++){
      vkb[base + (size_t)(g + j) * 4096] = f2bf(run);
      run += tv[j];
    }
  }
}

// ---------------- causal attention per (bh, chunk) — R13 (swizzled, measured good) ----------------
__global__ __launch_bounds__(256) void attn_kernel(
    const u16* __restrict__ q, const u16* __restrict__ k, const u16* __restrict__ v,
    const float* __restrict__ si, const float* __restrict__ scomp, const float* __restrict__ salloc,
    const u16* __restrict__ vkb, u16* __restrict__ attnout)
{
  __shared__ __align__(16) u16 qs[128*64];    // qmod rows [l][d] swz
  __shared__ __align__(16) u16 ks2[128*64];   // k rows    [j][d] swz
  __shared__ __align__(16) u16 vts[64*128];   // (v*scomp)^T [m][j] swz
  __shared__ __align__(16) u16 vks[64*64];    // VKprev [m][d] swz
  __shared__ __align__(16) u16 ss[128*64];    // masked S half [l][j-in-64] swz
  int bhc = blockIdx.x; int bh = bhc >> 5, c = bhc & 31;
  int b = bh >> 4, h = bh & 15;
  int tid = threadIdx.x, wave = tid >> 6, lane = tid & 63;
  size_t gbase = ((size_t)(b * L_ + c * CS)) * DM + h * D_;
  size_t sbase = (size_t)bh * L_ + c * CS;
  {
    int r = tid >> 1;
    int cc = (tid & 1) * 32;
    int l = c * CS + r;
    float qscale = si[sbase + r] / (float)(l + 1);
    float vscale = scomp[sbase + r];
    #pragma unroll
    for (int j = 0; j < 4; j++){
      int d0 = cc + j*8;
      uint4 qu = *(const uint4*)(q + gbase + (size_t)r * DM + d0);
      uint4 kuv = *(const uint4*)(k + gbase + (size_t)r * DM + d0);
      uint4 vu = *(const uint4*)(v + gbase + (size_t)r * DM + d0);
      const u16* qp = (const u16*)&qu; const u16* vp = (const u16*)&vu;
      u16 tmp[8];
      #pragma unroll
      for (int e = 0; e < 8; e++) tmp[e] = f2bf(bf2f(qp[e]) * qscale);
      int csw = ((d0 >> 3) ^ (r & 7)) << 3;           // swizzled d-chunk
      *(uint4*)&qs[r*64 + csw]  = *(uint4*)tmp;
      *(uint4*)&ks2[r*64 + csw] = kuv;
      #pragma unroll
      for (int e = 0; e < 8; e++){
        int m = d0 + e;
        int jsw = (((r >> 3) ^ (m & 7)) << 3) | (r & 7);  // swizzled j position
        vts[m*128 + jsw] = f2bf(bf2f(vp[e]) * vscale);
      }
    }
    const u16* vkp = vkb + (size_t)bhc * (D_*D_) + tid * 16;
    int m = tid >> 2, dq = (tid & 3) * 2;               // two d-chunks per thread
    int o0 = ((dq     ^ (m & 7)) << 3);
    int o1 = (((dq+1) ^ (m & 7)) << 3);
    *(uint4*)&vks[m*64 + o0] = *(const uint4*)(vkp);
    *(uint4*)&vks[m*64 + o1] = *(const uint4*)(vkp + 8);
  }
  __syncthreads();
  int t0 = wave, t1 = 7 - wave;   // balanced l-tile pair per wave
  int fr = lane & 15, qh = lane >> 4;
  int f7 = fr & 7;
  f32x4 acc[2][4];
  #pragma unroll
  for (int i=0;i<2;i++)
    #pragma unroll
    for (int j=0;j<4;j++) acc[i][j] = (f32x4){0.f,0.f,0.f,0.f};
  s16x8 aq[2][2];
  #pragma unroll
  for (int ti = 0; ti < 2; ti++){
    int t = ti ? t1 : t0;
    #pragma unroll
    for (int kk = 0; kk < 2; kk++){
      int oc = (((kk*4 + qh) ^ f7) << 3);
      aq[ti][kk] = *(const s16x8*)&qs[(t*16 + fr)*64 + oc];
    }
  }
  // inter-chunk: qmod @ VKprev^T
  #pragma unroll
  for (int mt = 0; mt < 4; mt++){
    #pragma unroll
    for (int kk = 0; kk < 2; kk++){
      int oc = (((kk*4 + qh) ^ f7) << 3);
      s16x8 bv = *(const s16x8*)&vks[(mt*16 + fr)*64 + oc];
      acc[0][mt] = mfma16(aq[0][kk], bv, acc[0][mt]);
      acc[1][mt] = mfma16(aq[1][kk], bv, acc[1][mt]);
    }
  }
  // intra-chunk, two 64-j halves
  for (int jt2 = 0; jt2 < 2; jt2++){
    __syncthreads();
    #pragma unroll
    for (int ti = 0; ti < 2; ti++){
      int t = ti ? t1 : t0;
      #pragma unroll
      for (int u = 0; u < 4; u++){
        int jj = jt2*4 + u;
        f32x4 sacc = (f32x4){0.f,0.f,0.f,0.f};
        if (jj <= t){
          #pragma unroll
          for (int kk = 0; kk < 2; kk++){
            int oc = (((kk*4 + qh) ^ f7) << 3);
            s16x8 bkf = *(const s16x8*)&ks2[(jj*16 + fr)*64 + oc];
            sacc = mfma16(aq[ti][kk], bkf, sacc);
          }
        }
        int lrow = t*16 + qh*4;
        int jcol = jj*16 + fr;
        int cst = u*2 + (fr >> 3);          // strip-local logical chunk
        #pragma unroll
        for (int r = 0; r < 4; r++){
          float sv = (jcol <= lrow + r) ? sacc[r] : 0.f;
          int row = lrow + r;
          ss[row*64 + (((cst ^ (row & 7)) << 3) | f7)] = f2bf(sv);
        }
      }
    }
    __syncthreads();
    #pragma unroll
    for (int ti = 0; ti < 2; ti++){
      int t = ti ? t1 : t0;
      #pragma unroll
      for (int ks = 0; ks < 2; ks++){
        if (jt2*64 + ks*32 <= t*16 + 15){
          int ocs = (((ks*4 + qh) ^ f7) << 3);
          s16x8 as = *(const s16x8*)&ss[(t*16 + fr)*64 + ocs];
          #pragma unroll
          for (int mt = 0; mt < 4; mt++){
            int lc = jt2*8 + ks*4 + qh;
            int ocv = ((lc ^ f7) << 3);
            s16x8 bvv = *(const s16x8*)&vts[(mt*16 + fr)*128 + ocv];
            acc[ti][mt] = mfma16(as, bvv, acc[ti][mt]);
          }
        }
      }
    }
  }
  // epilogue: * sink_allocation, write bf16 [B,L,DM]
  #pragma unroll
  for (int ti = 0; ti < 2; ti++){
    int t = ti ? t1 : t0;
    int lrow = t*16 + qh*4;
    #pragma unroll
    for (int r = 0; r < 4; r++){
      float sa = salloc[sbase + lrow + r];
      size_t orow = ((size_t)(b * L_ + c * CS + lrow + r)) * DM + h * D_;
      #pragma unroll
      for (int mt = 0; mt < 4; mt++){
        attnout[orow + mt*16 + fr] = f2bf(acc[ti][mt][r] * sa);
      }
    }
  }
}

extern "C" void kernel_launch(void* const* d_in, const int* in_sizes, int n_in,
                              void* d_out, int out_size, void* d_ws, size_t ws_size,
                              hipStream_t stream){
  (void)in_sizes; (void)n_in; (void)out_size; (void)ws_size;
  const float* x  = (const float*)d_in[0];
  const float* Wq = (const float*)d_in[1];
  const float* bq = (const float*)d_in[2];
  const float* Wk = (const float*)d_in[3];
  const float* bk = (const float*)d_in[4];
  const float* Wv = (const float*)d_in[5];
  const float* bv = (const float*)d_in[6];
  const float* Wo = (const float*)d_in[7];
  const float* bo = (const float*)d_in[8];

  char* p = (char*)d_ws;
  auto carve = [&](size_t bytes) -> void* {
    void* r = (void*)p; p += (bytes + 255) & ~(size_t)255; return r;
  };
  u16* xb    = (u16*)carve((size_t)N_*DM*2);
  u16* wqkvT = (u16*)carve((size_t)3*DM*DM*2);
  u16* woT   = (u16*)carve((size_t)DM*DM*2);
  u16* qb  = (u16*)carve((size_t)N_*DM*2);
  u16* kb  = (u16*)carve((size_t)N_*DM*2);
  u16* vb  = (u16*)carve((size_t)N_*DM*2);
  u16* ao  = (u16*)carve((size_t)N_*DM*2);
  float* si   = (float*)carve((size_t)BH*L_*4);
  float* so   = (float*)carve((size_t)BH*L_*4);
  float* csrc = (float*)carve((size_t)BH*L_*4);
  float* sall = (float*)carve((size_t)BH*L_*4);
  float* scmp = (float*)carve((size_t)BH*L_*4);
  float* sumQ   = (float*)carve((size_t)BH*NSC*D_*4);
  float* sumK   = (float*)carve((size_t)BH*NSC*D_*4);
  float* sumQsi = (float*)carve((size_t)BH*NSC*D_*4);
  float* sumKso = (float*)carve((size_t)BH*NSC*D_*4);
  float* csSum  = (float*)carve((size_t)BH*NSC*4);
  float* vkc    = (float*)carve((size_t)BH*NC*(size_t)(D_*D_)*4);
  u16*   vkb    = (u16*)carve((size_t)BH*NC*(size_t)(D_*D_)*2);

  // 1. prep: cvt + 4 weight transposes (one launch)
  prep_kernel<<<16384 + 4*256, 256, 0, stream>>>(x, Wq, Wk, Wv, Wo, xb, wqkvT, woT);
  // 2. fused q,k,v projection (one 16384x3072x1024 GEMM) + per-scan-chunk sums
  gemm256_kernel<1><<<dim3((N_/256)*(3*DM/256)), 512, 0, stream>>>(
      xb, wqkvT, bq, bk, bv, qb, kb, vb, nullptr, sumQ, sumK, 3*DM/256);
  // 3. normalizer pipeline
  scan2_kernel<<<BH, 64, 0, stream>>>(sumQ, sumK);
  siso_fused_kernel<<<BH*NSC, 128, 0, stream>>>(qb, kb, sumQ, sumK, si, so, sumQsi, sumKso);
  scan2_kernel<<<BH, 64, 0, stream>>>(sumQsi, sumKso);
  cons_fused_kernel<<<BH*NSC, 128, 0, stream>>>(qb, kb, si, so, sumQsi, sumKso, csrc, sall, csSum);
  // 4. causal linear attention (scomp fused into vk_chunk)
  vk_chunk_kernel<<<BH*NC, 256, 0, stream>>>(kb, vb, csrc, csSum, scmp, vkc);
  vk_scan_kernel<<<(BH*D_*D_)/256, 256, 0, stream>>>(vkc, vkb);
  attn_kernel<<<BH*NC, 256, 0, stream>>>(qb, kb, vb, si, scmp, sall, vkb, ao);
  // 5. output projection
  gemm256_kernel<0><<<dim3((N_/256)*(DM/256)), 512, 0, stream>>>(
      ao, woT, bo, bo, bo, nullptr, nullptr, nullptr, (float*)d_out, nullptr, nullptr, DM/256);
}

// Round 16
// 313.286 us; speedup vs baseline: 1.2392x; 1.0096x over previous
//
#include <hip/hip_runtime.h>
#include <stdint.h>

// Problem constants (fixed by setup_inputs)
#define B_ 4
#define L_ 4096
#define DM 1024
#define H_ 16
#define D_ 64
#define BH (B_*H_)      // 64
#define N_ (B_*L_)      // 16384
#define CS 128          // chunk size for causal attention
#define NC (L_/CS)      // 32
#define SC 64           // chunk size for normalizer scans
#define NSC (L_/SC)     // 64
#define EPSF 1e-6f

typedef unsigned short u16;
typedef unsigned int   u32;
typedef __attribute__((ext_vector_type(8))) short s16x8;
typedef __attribute__((ext_vector_type(4))) float f32x4;

__device__ __forceinline__ float bf2f(u16 u){
  union { u32 i; float f; } v; v.i = ((u32)u) << 16; return v.f;
}
__device__ __forceinline__ u16 f2bf(float f){
  union { float f; u32 i; } v; v.f = f;
  u32 i = v.i;
  return (u16)((i + 0x7fffu + ((i >> 16) & 1u)) >> 16);  // RNE
}
__device__ __forceinline__ void gload16(const void* g, void* l){
  __builtin_amdgcn_global_load_lds(
      (const __attribute__((address_space(1))) u32*)g,
      (__attribute__((address_space(3))) u32*)l, 16, 0, 0);
}
__device__ __forceinline__ f32x4 mfma16(s16x8 a, s16x8 b, f32x4 c){
  return __builtin_amdgcn_mfma_f32_16x16x32_bf16(a, b, c, 0, 0, 0);
}
__device__ __forceinline__ float sigmoidf_(float x){ return 1.0f/(1.0f+__expf(-x)); }

// Masked ordered prefix-reduction over chunk sums (L2-resident, register-group
// loads -> parallel latency; accumulation in ascending chunk order = bit-identical
// to the old scan2 sequential order). R6's version was a serial dependent chain;
// this is the R9-proven pattern.
__device__ __forceinline__ float prefix_sum64(const float* __restrict__ sums,
                                              int bh, int sc, int lane){
  float run = 0.f;
  for (int g = 0; g < NSC; g += 16){
    float tv[16];
    #pragma unroll
    for (int j = 0; j < 16; j++)
      tv[j] = sums[((size_t)bh*NSC + g + j)*64 + lane];
    #pragma unroll
    for (int j = 0; j < 16; j++)
      if (g + j < sc) run += tv[j];
  }
  return run;
}

// ---------------- prep: fp32->bf16 cvt + 4x W transpose (one launch) ----------------
__global__ __launch_bounds__(256) void prep_kernel(
    const float* __restrict__ x,
    const float* __restrict__ Wq, const float* __restrict__ Wk,
    const float* __restrict__ Wv, const float* __restrict__ Wo,
    u16* __restrict__ xb, u16* __restrict__ wqkvT, u16* __restrict__ woT){
  __shared__ float t[64][65];
  int bid = blockIdx.x;
  if (bid < 16384){
    int i = bid * 256 + threadIdx.x;          // over N_*DM/4 = 4194304
    float4 v = ((const float4*)x)[i];
    union { u16 s[4]; uint2 u; } o;
    o.s[0]=f2bf(v.x); o.s[1]=f2bf(v.y); o.s[2]=f2bf(v.z); o.s[3]=f2bf(v.w);
    ((uint2*)xb)[i] = o.u;
    return;
  }
  int w = bid - 16384;
  int z = w >> 8, w2 = w & 255;
  const float* W = (z==0) ? Wq : (z==1) ? Wk : (z==2) ? Wv : Wo;
  u16* WT = (z<3) ? (wqkvT + (size_t)z*DM*DM) : woT;
  int n0 = (w2 & 15) * 64, k0 = (w2 >> 4) * 64;
  int tx = threadIdx.x & 63, ty = threadIdx.x >> 6;
  #pragma unroll
  for (int s = 0; s < 64; s += 4)
    t[ty + s][tx] = W[(size_t)(k0 + ty + s) * DM + n0 + tx];
  __syncthreads();
  #pragma unroll
  for (int s = 0; s < 64; s += 4)
    WT[(size_t)(n0 + ty + s) * DM + k0 + tx] = f2bf(t[tx][ty + s]);
}

// ---------------- 256x256 counted-vmcnt MFMA GEMM (K=1024 fixed) — R3/R10 structure ----------------
// Measured-best: 133.6-134.2 us (QKV), MfmaUtil ~32.5%, 0 bank conflicts. PARKED.
template<int QKV>
__global__ __launch_bounds__(512, 2) void gemm256_kernel(
    const u16* __restrict__ A, const u16* __restrict__ BT,
    const float* __restrict__ biasq, const float* __restrict__ biask, const float* __restrict__ biasv,
    u16* __restrict__ oq, u16* __restrict__ ok, u16* __restrict__ ov,
    float* __restrict__ outf,
    float* __restrict__ sumQ, float* __restrict__ sumK, int NBY)
{
  // LDS: A slot0 [0,32K), A slot1 [32K,64K), B slot0 [64K,96K), B slot1 [96K,128K)
  __shared__ __align__(16) u16 smem[65536];
  char* smb = (char*)smem;
  int tid = threadIdx.x;
  int wave = tid >> 6, lane = tid & 63;
  int wm = wave >> 2, wn = wave & 3;          // 2 x 4 wave grid
  int nwg = gridDim.x;
  int q8 = nwg >> 3;
  int id = blockIdx.x;
  int id2 = (id & 7) * q8 + (id >> 3);
  int bx = id2 / NBY, by = id2 % NBY;
  int m0 = bx * 256, n0 = by * 256;
  int srcq = (tid & 7) ^ ((tid >> 3) & 7);
  const u16* aRow = A  + (size_t)(m0 + (tid >> 3)) * 1024 + srcq * 8;
  const u16* bRow = BT + (size_t)(n0 + (tid >> 3)) * 1024 + srcq * 8;

  f32x4 acc[8][4];
  #pragma unroll
  for (int i=0;i<8;i++)
    #pragma unroll
    for (int j=0;j<4;j++) acc[i][j] = (f32x4){0.f,0.f,0.f,0.f};

  int fr = lane & 15, q = lane >> 4;
  int aoff0 = fr*128 + (((q ^ (lane&3)) + 4*((lane>>2)&1)) << 4);
  int aoff1 = fr*128 + (((q ^ (lane&3)) + 4*(1 ^ ((lane>>2)&1))) << 4);

  #define STAGE(s, t) { \
    _Pragma("unroll") \
    for (int i_ = 0; i_ < 4; i_++){ \
      gload16(aRow + (size_t)(t)*64 + (size_t)i_*65536, smb + (s)*32768 + i_*8192 + tid*16); \
      gload16(bRow + (size_t)(t)*64 + (size_t)i_*65536, smb + 65536 + (s)*32768 + i_*8192 + tid*16); \
    } }

  #define COMPUTE(s) { \
    const char* Ab_ = smb + (s)*32768 + wm*16384; \
    const char* Bb_ = smb + 65536 + (s)*32768 + wn*8192; \
    _Pragma("unroll") \
    for (int kk_ = 0; kk_ < 2; kk_++){ \
      int off_ = kk_ ? aoff1 : aoff0; \
      s16x8 af_[8], bf_[4]; \
      _Pragma("unroll") \
      for (int mi_ = 0; mi_ < 8; mi_++) af_[mi_] = *(const s16x8*)(Ab_ + mi_*2048 + off_); \
      _Pragma("unroll") \
      for (int ni_ = 0; ni_ < 4; ni_++) bf_[ni_] = *(const s16x8*)(Bb_ + ni_*2048 + off_); \
      _Pragma("unroll") \
      for (int mi_ = 0; mi_ < 8; mi_++) \
        _Pragma("unroll") \
        for (int ni_ = 0; ni_ < 4; ni_++) \
          acc[mi_][ni_] = mfma16(af_[mi_], bf_[ni_], acc[mi_][ni_]); \
    } }

  STAGE(0, 0)
  STAGE(1, 1)
  for (int t = 0; t < 14; t++){
    asm volatile("s_waitcnt vmcnt(8)" ::: "memory");
    __builtin_amdgcn_s_barrier();
    asm volatile("" ::: "memory");
    COMPUTE(t & 1)
    asm volatile("s_waitcnt lgkmcnt(0)" ::: "memory");
    __builtin_amdgcn_s_barrier();
    asm volatile("" ::: "memory");
    STAGE(t & 1, t + 2)
  }
  asm volatile("s_waitcnt vmcnt(8)" ::: "memory");
  __builtin_amdgcn_s_barrier();
  asm volatile("" ::: "memory");
  COMPUTE(0)
  asm volatile("s_waitcnt vmcnt(0)" ::: "memory");
  __builtin_amdgcn_s_barrier();
  asm volatile("" ::: "memory");
  COMPUTE(1)

  // epilogue
  int colblk = n0 + wn*64;
  int which  = QKV ? (colblk >> 10) : 0;          // 0=q 1=k 2=v
  int cl0    = QKV ? (colblk & 1023) : colblk;
  const float* bias = QKV ? (which==0 ? biasq : (which==1 ? biask : biasv)) : biasq;
  u16* outp = QKV ? (which==0 ? oq : (which==1 ? ok : ov)) : (u16*)0;
  float cs0[4] = {0.f,0.f,0.f,0.f}, cs1[4] = {0.f,0.f,0.f,0.f};
  #pragma unroll
  for (int mi = 0; mi < 8; mi++){
    int row = m0 + wm*128 + mi*16 + (lane>>4)*4;
    #pragma unroll
    for (int ni = 0; ni < 4; ni++){
      int cl = cl0 + ni*16 + fr;
      float bv = bias[cl];
      #pragma unroll
      for (int r = 0; r < 4; r++){
        float val = acc[mi][ni][r] + bv;
        if (QKV){
          if (which < 2) val = sigmoidf_(val);
          outp[(size_t)(row + r) * 1024 + cl] = f2bf(val);
          if (which < 2){ if (mi < 4) cs0[ni] += val; else cs1[ni] += val; }
        } else {
          outf[(size_t)(row + r) * 1024 + cl] = val;
        }
      }
    }
  }
  if (QKV && which < 2){
    float* sums = (which==0) ? sumQ : sumK;
    int bh = (m0 >> 12) * H_ + ((colblk & 1023) >> 6);
    int sc0 = ((m0 & 4095) >> 6) + wm*2;
    #pragma unroll
    for (int h2 = 0; h2 < 2; h2++){
      #pragma unroll
      for (int ni = 0; ni < 4; ni++){
        float s = h2 ? cs1[ni] : cs0[ni];
        s += __shfl_xor(s, 16);
        s += __shfl_xor(s, 32);
        if (lane < 16) sums[((size_t)bh*NSC + sc0 + h2)*64 + ni*16 + fr] = s;
      }
    }
  }
  #undef STAGE
  #undef COMPUTE
}

// ---------------- fused sink_incoming/source_outgoing + mod chunk sums ----------------
// 2-wave split (wave0=q, wave1=k). Exclusive chunk-prefix computed inline via
// prefix_sum64 (replaces the scan2 launch; bit-identical order).
__global__ __launch_bounds__(128) void siso_fused_kernel(
    const u16* __restrict__ q, const u16* __restrict__ k,
    const float* __restrict__ sumQ, const float* __restrict__ sumK,
    float* __restrict__ si, float* __restrict__ so,
    float* __restrict__ sumQsi, float* __restrict__ sumKso)
{
  __shared__ u16 cq[64*64];
  __shared__ u16 ck[64*64];
  __shared__ float siv[64], sov[64];
  int bhc = blockIdx.x; int bh = bhc >> 6, sc = bhc & 63;
  int b = bh >> 4, h = bh & 15;
  int tid = threadIdx.x, w = tid >> 6, lane = tid & 63;
  size_t gbase = ((size_t)(b*L_ + sc*SC))*DM + h*D_;
  size_t lb = (size_t)bh*L_ + sc*SC;
  const u16* src = w ? k : q;
  u16* ldsT = w ? ck : cq;
  // carry-in prefix (issued early; independent loads)
  float run = prefix_sum64(w ? sumK : sumQ, bh, sc, lane);
  // P0: stage raw tile, swizzled
  {
    int r8 = lane >> 3, c8 = (lane & 7) * 8;
    #pragma unroll
    for (int j = 0; j < 8; j++){
      int l = j*8 + r8;
      uint4 u = *(const uint4*)(src + gbase + (size_t)l*DM + c8);
      const u16* up = (const u16*)&u;
      #pragma unroll
      for (int e = 0; e < 8; e++)
        ldsT[l*64 + ((c8 + e) ^ (l & 31))] = up[e];
    }
  }
  __syncthreads();
  // P1: column cumsum in place (lane = d)
  {
    for (int l = 0; l < SC; l++){
      int sw = lane ^ (l & 31);
      run += bf2f(ldsT[l*64 + sw]);
      ldsT[l*64 + sw] = f2bf(run);
    }
  }
  __syncthreads();
  // P2: row dots
  uint4 rowreg[8];
  {
    int l = lane;
    const u16* row = src + gbase + (size_t)l*DM;
    #pragma unroll
    for (int j=0;j<8;j++) rowreg[j] = ((const uint4*)row)[j];
    const u16* rp = (const u16*)rowreg;
    const u16* other = w ? cq : ck;
    float acc = 0.f;
    #pragma unroll
    for (int d = 0; d < 64; d++){
      int sw = d ^ (l & 31);
      acc += (bf2f(rp[d])+EPSF) * (bf2f(other[l*64+sw])+EPSF);
    }
    float n = (float)(sc*SC + l + 1);
    float vv = n / acc;
    if (w == 0){ si[lb+l] = vv; siv[l] = vv; }
    else       { so[lb+l] = vv; sov[l] = vv; }
  }
  __syncthreads();
  // P2b: raw rows back over dead cumsums
  {
    int l = lane;
    const u16* rp = (const u16*)rowreg;
    #pragma unroll
    for (int d = 0; d < 64; d++)
      ldsT[l*64 + (d ^ (l & 31))] = rp[d];
  }
  __syncthreads();
  // P3: column mod-sums (lane = d)
  {
    const float* sv = w ? sov : siv;
    float s = 0.f;
    for (int l = 0; l < SC; l++){
      int sw = lane ^ (l & 31);
      s += bf2f(ldsT[l*64 + sw]) * sv[l];
    }
    if (w == 0) sumQsi[bhc*64 + lane] = s;
    else        sumKso[bhc*64 + lane] = s;
  }
}

// ---------------- fused conserved_sink/source -> sall, csrc + exp chunk sums ----------------
// Same 2-wave split; chunk-prefix of sumQsi/sumKso computed inline (raw sums in).
__global__ __launch_bounds__(128) void cons_fused_kernel(
    const u16* __restrict__ q, const u16* __restrict__ k,
    const float* __restrict__ si, const float* __restrict__ so,
    const float* __restrict__ sumQsi, const float* __restrict__ sumKso,
    float* __restrict__ csrc, float* __restrict__ sall, float* __restrict__ csSum)
{
  __shared__ u16 cq[64*64];
  __shared__ u16 ck[64*64];
  __shared__ float siv[64], sov[64];
  int bhc = blockIdx.x; int bh = bhc >> 6, sc = bhc & 63;
  int b = bh >> 4, h = bh & 15;
  int tid = threadIdx.x, w = tid >> 6, lane = tid & 63;
  size_t gbase = ((size_t)(b*L_ + sc*SC))*DM + h*D_;
  size_t lb = (size_t)bh*L_ + sc*SC;
  const u16* src = w ? k : q;
  u16* ldsT = w ? ck : cq;
  if (w == 0) siv[lane] = si[lb + lane];
  else        sov[lane] = so[lb + lane];
  float run = prefix_sum64(w ? sumKso : sumQsi, bh, sc, lane);
  // P0: stage raw tile, swizzled
  {
    int r8 = lane >> 3, c8 = (lane & 7) * 8;
    #pragma unroll
    for (int j = 0; j < 8; j++){
      int l = j*8 + r8;
      uint4 u = *(const uint4*)(src + gbase + (size_t)l*DM + c8);
      const u16* up = (const u16*)&u;
      #pragma unroll
      for (int e = 0; e < 8; e++)
        ldsT[l*64 + ((c8 + e) ^ (l & 31))] = up[e];
    }
  }
  __syncthreads();
  // P1: weighted column cumsum in place
  {
    const float* sv = w ? sov : siv;
    for (int l = 0; l < SC; l++){
      int sw = lane ^ (l & 31);
      run += bf2f(ldsT[l*64 + sw]) * sv[l];
      ldsT[l*64 + sw] = f2bf(run);
    }
  }
  __syncthreads();
  // P2: row dots
  {
    int l = lane;
    const u16* row = src + gbase + (size_t)l*DM;
    uint4 rr[8];
    #pragma unroll
    for (int j=0;j<8;j++) rr[j] = ((const uint4*)row)[j];
    const u16* rp = (const u16*)rr;
    const u16* other = w ? cq : ck;
    float acc = 0.f;
    #pragma unroll
    for (int d = 0; d < 64; d++){
      int sw = d ^ (l & 31);
      acc += (bf2f(rp[d])+EPSF) * (bf2f(other[l*64+sw])+EPSF);
    }
    float inv = 1.0f / (float)(sc*SC + l + 1);
    if (w == 0){
      sall[lb+l] = sigmoidf_(acc * inv);
    } else {
      float cs = acc * inv;
      csrc[lb+l] = cs;
      float e = __expf(cs);
      #pragma unroll
      for (int off = 32; off > 0; off >>= 1) e += __shfl_xor(e, off);
      if (lane == 0) csSum[bhc] = e;
    }
  }
}

// ---------------- per-chunk VK sums via MFMA, with source_competition fused in ----------------
__global__ __launch_bounds__(256) void vk_chunk_kernel(
    const u16* __restrict__ k, const u16* __restrict__ v,
    const float* __restrict__ csrc, const float* __restrict__ csSum,
    float* __restrict__ scomp, float* __restrict__ vkc){
  __shared__ __align__(16) u16 vt[64*128];   // (v*scomp)^T [m][l] swz
  __shared__ __align__(16) u16 kt[64*128];   // k^T [d][l] swz
  __shared__ float scmpv[128];
  int bhc = blockIdx.x; int bh = bhc >> 5, c = bhc & 31;
  int b = bh >> 4, h = bh & 15;
  int tid = threadIdx.x, wave = tid >> 6, lane = tid & 63;
  size_t gbase = ((size_t)(b * L_ + c * CS)) * DM + h * D_;
  // Phase A: scmp for scan-chunks sc = 2c + {0,1}
  if (wave < 2){
    int sc = c*2 + wave;
    float v2 = (lane < sc) ? csSum[bh*NSC + lane] : 0.f;
    #pragma unroll
    for (int o = 32; o > 0; o >>= 1) v2 += __shfl_xor(v2, o);
    float off = v2;
    size_t idx = (size_t)bh * L_ + sc * SC + lane;
    float cs = __expf(csrc[idx]);
    float run = cs;
    #pragma unroll
    for (int o = 1; o < 64; o <<= 1){
      float t = __shfl_up(run, o);
      if (lane >= o) run += t;
    }
    float sm = cs / (off + run) * (float)(sc*SC + lane + 1);
    scomp[idx] = sm;
    scmpv[wave*64 + lane] = sm;
  }
  __syncthreads();
  // Phase B: stage transposed tiles (v scaled by scmp from LDS)
  {
    int r = tid >> 1;            // source row l = 0..127
    int cc = (tid & 1) * 32;     // d-half
    float vscale = scmpv[r];
    #pragma unroll
    for (int j = 0; j < 4; j++){
      uint4 ku = *(const uint4*)(k + gbase + (size_t)r * DM + cc + j*8);
      uint4 vu = *(const uint4*)(v + gbase + (size_t)r * DM + cc + j*8);
      const u16* kp = (const u16*)&ku; const u16* vp = (const u16*)&vu;
      #pragma unroll
      for (int e = 0; e < 8; e++){
        int m = cc + j*8 + e;
        int idx = m*128 + ((((r >> 3) ^ (m & 7)) << 3) | (r & 7));
        vt[idx] = f2bf(bf2f(vp[e]) * vscale);
        kt[idx] = kp[e];
      }
    }
  }
  __syncthreads();
  int fr = lane & 15, q = lane >> 4;
  int mt = wave;                 // m-tile (16 rows) per wave
  f32x4 acc[4];
  #pragma unroll
  for (int i = 0; i < 4; i++) acc[i] = (f32x4){0.f,0.f,0.f,0.f};
  #pragma unroll
  for (int ks = 0; ks < 4; ks++){
    int lc = ks*4 + q;           // logical 16B l-chunk
    int off = ((lc ^ (fr & 7)) << 3);
    s16x8 av = *(const s16x8*)&vt[(mt*16 + fr)*128 + off];
    #pragma unroll
    for (int nt = 0; nt < 4; nt++){
      s16x8 bk = *(const s16x8*)&kt[(nt*16 + fr)*128 + off];
      acc[nt] = mfma16(av, bk, acc[nt]);
    }
  }
  float* outp = vkc + (size_t)bhc * (D_*D_);
  #pragma unroll
  for (int nt = 0; nt < 4; nt++)
    #pragma unroll
    for (int r = 0; r < 4; r++)
      outp[(mt*16 + q*4 + r)*64 + nt*16 + fr] = acc[nt][r];
}

// ---------------- exclusive scan of VK over chunks: fp32 in -> bf16 prefix out ----------------
__global__ __launch_bounds__(256) void vk_scan_kernel(const float* __restrict__ vkc, u16* __restrict__ vkb){
  int idx = blockIdx.x * 256 + threadIdx.x;   // over BH*4096
  int bh = idx >> 12;
  int e  = idx & 4095;
  size_t base = ((size_t)bh * NC) * 4096 + e;
  float run = 0.f;
  for (int g = 0; g < NC; g += 16){
    float tv[16];
    #pragma unroll
    for (int j = 0; j < 16; j++) tv[j] = vkc[base + (size_t)(g + j) * 4096];
    #pragma unroll
    for (int j = 0; j < 16; j++){
      vkb[base + (size_t)(g + j) * 4096] = f2bf(run);
      run += tv[j];
    }
  }
}

// ---------------- causal attention per (bh, chunk) — R13 (swizzled, measured good) ----------------
__global__ __launch_bounds__(256) void attn_kernel(
    const u16* __restrict__ q, const u16* __restrict__ k, const u16* __restrict__ v,
    const float* __restrict__ si, const float* __restrict__ scomp, const float* __restrict__ salloc,
    const u16* __restrict__ vkb, u16* __restrict__ attnout)
{
  __shared__ __align__(16) u16 qs[128*64];    // qmod rows [l][d] swz
  __shared__ __align__(16) u16 ks2[128*64];   // k rows    [j][d] swz
  __shared__ __align__(16) u16 vts[64*128];   // (v*scomp)^T [m][j] swz
  __shared__ __align__(16) u16 vks[64*64];    // VKprev [m][d] swz
  __shared__ __align__(16) u16 ss[128*64];    // masked S half [l][j-in-64] swz
  int bhc = blockIdx.x; int bh = bhc >> 5, c = bhc & 31;
  int b = bh >> 4, h = bh & 15;
  int tid = threadIdx.x, wave = tid >> 6, lane = tid & 63;
  size_t gbase = ((size_t)(b * L_ + c * CS)) * DM + h * D_;
  size_t sbase = (size_t)bh * L_ + c * CS;
  {
    int r = tid >> 1;
    int cc = (tid & 1) * 32;
    int l = c * CS + r;
    float qscale = si[sbase + r] / (float)(l + 1);
    float vscale = scomp[sbase + r];
    #pragma unroll
    for (int j = 0; j < 4; j++){
      int d0 = cc + j*8;
      uint4 qu = *(const uint4*)(q + gbase + (size_t)r * DM + d0);
      uint4 kuv = *(const uint4*)(k + gbase + (size_t)r * DM + d0);
      uint4 vu = *(const uint4*)(v + gbase + (size_t)r * DM + d0);
      const u16* qp = (const u16*)&qu; const u16* vp = (const u16*)&vu;
      u16 tmp[8];
      #pragma unroll
      for (int e = 0; e < 8; e++) tmp[e] = f2bf(bf2f(qp[e]) * qscale);
      int csw = ((d0 >> 3) ^ (r & 7)) << 3;           // swizzled d-chunk
      *(uint4*)&qs[r*64 + csw]  = *(uint4*)tmp;
      *(uint4*)&ks2[r*64 + csw] = kuv;
      #pragma unroll
      for (int e = 0; e < 8; e++){
        int m = d0 + e;
        int jsw = (((r >> 3) ^ (m & 7)) << 3) | (r & 7);  // swizzled j position
        vts[m*128 + jsw] = f2bf(bf2f(vp[e]) * vscale);
      }
    }
    const u16* vkp = vkb + (size_t)bhc * (D_*D_) + tid * 16;
    int m = tid >> 2, dq = (tid & 3) * 2;               // two d-chunks per thread
    int o0 = ((dq     ^ (m & 7)) << 3);
    int o1 = (((dq+1) ^ (m & 7)) << 3);
    *(uint4*)&vks[m*64 + o0] = *(const uint4*)(vkp);
    *(uint4*)&vks[m*64 + o1] = *(const uint4*)(vkp + 8);
  }
  __syncthreads();
  int t0 = wave, t1 = 7 - wave;   // balanced l-tile pair per wave
  int fr = lane & 15, qh = lane >> 4;
  int f7 = fr & 7;
  f32x4 acc[2][4];
  #pragma unroll
  for (int i=0;i<2;i++)
    #pragma unroll
    for (int j=0;j<4;j++) acc[i][j] = (f32x4){0.f,0.f,0.f,0.f};
  s16x8 aq[2][2];
  #pragma unroll
  for (int ti = 0; ti < 2; ti++){
    int t = ti ? t1 : t0;
    #pragma unroll
    for (int kk = 0; kk < 2; kk++){
      int oc = (((kk*4 + qh) ^ f7) << 3);
      aq[ti][kk] = *(const s16x8*)&qs[(t*16 + fr)*64 + oc];
    }
  }
  // inter-chunk: qmod @ VKprev^T
  #pragma unroll
  for (int mt = 0; mt < 4; mt++){
    #pragma unroll
    for (int kk = 0; kk < 2; kk++){
      int oc = (((kk*4 + qh) ^ f7) << 3);
      s16x8 bv = *(const s16x8*)&vks[(mt*16 + fr)*64 + oc];
      acc[0][mt] = mfma16(aq[0][kk], bv, acc[0][mt]);
      acc[1][mt] = mfma16(aq[1][kk], bv, acc[1][mt]);
    }
  }
  // intra-chunk, two 64-j halves
  for (int jt2 = 0; jt2 < 2; jt2++){
    __syncthreads();
    #pragma unroll
    for (int ti = 0; ti < 2; ti++){
      int t = ti ? t1 : t0;
      #pragma unroll
      for (int u = 0; u < 4; u++){
        int jj = jt2*4 + u;
        f32x4 sacc = (f32x4){0.f,0.f,0.f,0.f};
        if (jj <= t){
          #pragma unroll
          for (int kk = 0; kk < 2; kk++){
            int oc = (((kk*4 + qh) ^ f7) << 3);
            s16x8 bkf = *(const s16x8*)&ks2[(jj*16 + fr)*64 + oc];
            sacc = mfma16(aq[ti][kk], bkf, sacc);
          }
        }
        int lrow = t*16 + qh*4;
        int jcol = jj*16 + fr;
        int cst = u*2 + (fr >> 3);          // strip-local logical chunk
        #pragma unroll
        for (int r = 0; r < 4; r++){
          float sv = (jcol <= lrow + r) ? sacc[r] : 0.f;
          int row = lrow + r;
          ss[row*64 + (((cst ^ (row & 7)) << 3) | f7)] = f2bf(sv);
        }
      }
    }
    __syncthreads();
    #pragma unroll
    for (int ti = 0; ti < 2; ti++){
      int t = ti ? t1 : t0;
      #pragma unroll
      for (int ks = 0; ks < 2; ks++){
        if (jt2*64 + ks*32 <= t*16 + 15){
          int ocs = (((ks*4 + qh) ^ f7) << 3);
          s16x8 as = *(const s16x8*)&ss[(t*16 + fr)*64 + ocs];
          #pragma unroll
          for (int mt = 0; mt < 4; mt++){
            int lc = jt2*8 + ks*4 + qh;
            int ocv = ((lc ^ f7) << 3);
            s16x8 bvv = *(const s16x8*)&vts[(mt*16 + fr)*128 + ocv];
            acc[ti][mt] = mfma16(as, bvv, acc[ti][mt]);
          }
        }
      }
    }
  }
  // epilogue: * sink_allocation, write bf16 [B,L,DM]
  #pragma unroll
  for (int ti = 0; ti < 2; ti++){
    int t = ti ? t1 : t0;
    int lrow = t*16 + qh*4;
    #pragma unroll
    for (int r = 0; r < 4; r++){
      float sa = salloc[sbase + lrow + r];
      size_t orow = ((size_t)(b * L_ + c * CS + lrow + r)) * DM + h * D_;
      #pragma unroll
      for (int mt = 0; mt < 4; mt++){
        attnout[orow + mt*16 + fr] = f2bf(acc[ti][mt][r] * sa);
      }
    }
  }
}

extern "C" void kernel_launch(void* const* d_in, const int* in_sizes, int n_in,
                              void* d_out, int out_size, void* d_ws, size_t ws_size,
                              hipStream_t stream){
  (void)in_sizes; (void)n_in; (void)out_size; (void)ws_size;
  const float* x  = (const float*)d_in[0];
  const float* Wq = (const float*)d_in[1];
  const float* bq = (const float*)d_in[2];
  const float* Wk = (const float*)d_in[3];
  const float* bk = (const float*)d_in[4];
  const float* Wv = (const float*)d_in[5];
  const float* bv = (const float*)d_in[6];
  const float* Wo = (const float*)d_in[7];
  const float* bo = (const float*)d_in[8];

  char* p = (char*)d_ws;
  auto carve = [&](size_t bytes) -> void* {
    void* r = (void*)p; p += (bytes + 255) & ~(size_t)255; return r;
  };
  u16* xb    = (u16*)carve((size_t)N_*DM*2);
  u16* wqkvT = (u16*)carve((size_t)3*DM*DM*2);
  u16* woT   = (u16*)carve((size_t)DM*DM*2);
  u16* qb  = (u16*)carve((size_t)N_*DM*2);
  u16* kb  = (u16*)carve((size_t)N_*DM*2);
  u16* vb  = (u16*)carve((size_t)N_*DM*2);
  u16* ao  = (u16*)carve((size_t)N_*DM*2);
  float* si   = (float*)carve((size_t)BH*L_*4);
  float* so   = (float*)carve((size_t)BH*L_*4);
  float* csrc = (float*)carve((size_t)BH*L_*4);
  float* sall = (float*)carve((size_t)BH*L_*4);
  float* scmp = (float*)carve((size_t)BH*L_*4);
  float* sumQ   = (float*)carve((size_t)BH*NSC*D_*4);
  float* sumK   = (float*)carve((size_t)BH*NSC*D_*4);
  float* sumQsi = (float*)carve((size_t)BH*NSC*D_*4);
  float* sumKso = (float*)carve((size_t)BH*NSC*D_*4);
  float* csSum  = (float*)carve((size_t)BH*NSC*4);
  float* vkc    = (float*)carve((size_t)BH*NC*(size_t)(D_*D_)*4);
  u16*   vkb    = (u16*)carve((size_t)BH*NC*(size_t)(D_*D_)*2);

  // 1. prep: cvt + 4 weight transposes (one launch)
  prep_kernel<<<16384 + 4*256, 256, 0, stream>>>(x, Wq, Wk, Wv, Wo, xb, wqkvT, woT);
  // 2. fused q,k,v projection (one 16384x3072x1024 GEMM) + per-scan-chunk sums
  gemm256_kernel<1><<<dim3((N_/256)*(3*DM/256)), 512, 0, stream>>>(
      xb, wqkvT, bq, bk, bv, qb, kb, vb, nullptr, sumQ, sumK, 3*DM/256);
  // 3. normalizer pipeline (chunk prefixes inlined; no scan2 launches)
  siso_fused_kernel<<<BH*NSC, 128, 0, stream>>>(qb, kb, sumQ, sumK, si, so, sumQsi, sumKso);
  cons_fused_kernel<<<BH*NSC, 128, 0, stream>>>(qb, kb, si, so, sumQsi, sumKso, csrc, sall, csSum);
  // 4. causal linear attention (scomp fused into vk_chunk)
  vk_chunk_kernel<<<BH*NC, 256, 0, stream>>>(kb, vb, csrc, csSum, scmp, vkc);
  vk_scan_kernel<<<(BH*D_*D_)/256, 256, 0, stream>>>(vkc, vkb);
  attn_kernel<<<BH*NC, 256, 0, stream>>>(qb, kb, vb, si, scmp, sall, vkb, ao);
  // 5. output projection
  gemm256_kernel<0><<<dim3((N_/256)*(DM/256)), 512, 0, stream>>>(
      ao, woT, bo, bo, bo, nullptr, nullptr, nullptr, (float*)d_out, nullptr, nullptr, DM/256);
}

// Round 17
// 307.107 us; speedup vs baseline: 1.2641x; 1.0201x over previous
//
#include <hip/hip_runtime.h>
#include <stdint.h>

// Problem constants (fixed by setup_inputs)
#define B_ 4
#define L_ 4096
#define DM 1024
#define H_ 16
#define D_ 64
#define BH (B_*H_)      // 64
#define N_ (B_*L_)      // 16384
#define CS 128          // chunk size for causal attention
#define NC (L_/CS)      // 32
#define SC 64           // chunk size for normalizer scans
#define NSC (L_/SC)     // 64
#define EPSF 1e-6f

typedef unsigned short u16;
typedef unsigned int   u32;
typedef __attribute__((ext_vector_type(8))) short s16x8;
typedef __attribute__((ext_vector_type(4))) float f32x4;

__device__ __forceinline__ float bf2f(u16 u){
  union { u32 i; float f; } v; v.i = ((u32)u) << 16; return v.f;
}
__device__ __forceinline__ u16 f2bf(float f){
  union { float f; u32 i; } v; v.f = f;
  u32 i = v.i;
  return (u16)((i + 0x7fffu + ((i >> 16) & 1u)) >> 16);  // RNE
}
__device__ __forceinline__ void gload16(const void* g, void* l){
  __builtin_amdgcn_global_load_lds(
      (const __attribute__((address_space(1))) u32*)g,
      (__attribute__((address_space(3))) u32*)l, 16, 0, 0);
}
__device__ __forceinline__ f32x4 mfma16(s16x8 a, s16x8 b, f32x4 c){
  return __builtin_amdgcn_mfma_f32_16x16x32_bf16(a, b, c, 0, 0, 0);
}
__device__ __forceinline__ float sigmoidf_(float x){ return 1.0f/(1.0f+__expf(-x)); }

// Masked ordered prefix-reduction over chunk sums (R16, measured good).
__device__ __forceinline__ float prefix_sum64(const float* __restrict__ sums,
                                              int bh, int sc, int lane){
  float run = 0.f;
  for (int g = 0; g < NSC; g += 16){
    float tv[16];
    #pragma unroll
    for (int j = 0; j < 16; j++)
      tv[j] = sums[((size_t)bh*NSC + g + j)*64 + lane];
    #pragma unroll
    for (int j = 0; j < 16; j++)
      if (g + j < sc) run += tv[j];
  }
  return run;
}

// ---------------- prep: fp32->bf16 cvt + 4x W transpose (one launch) ----------------
__global__ __launch_bounds__(256) void prep_kernel(
    const float* __restrict__ x,
    const float* __restrict__ Wq, const float* __restrict__ Wk,
    const float* __restrict__ Wv, const float* __restrict__ Wo,
    u16* __restrict__ xb, u16* __restrict__ wqkvT, u16* __restrict__ woT){
  __shared__ float t[64][65];
  int bid = blockIdx.x;
  if (bid < 16384){
    int i = bid * 256 + threadIdx.x;          // over N_*DM/4 = 4194304
    float4 v = ((const float4*)x)[i];
    union { u16 s[4]; uint2 u; } o;
    o.s[0]=f2bf(v.x); o.s[1]=f2bf(v.y); o.s[2]=f2bf(v.z); o.s[3]=f2bf(v.w);
    ((uint2*)xb)[i] = o.u;
    return;
  }
  int w = bid - 16384;
  int z = w >> 8, w2 = w & 255;
  const float* W = (z==0) ? Wq : (z==1) ? Wk : (z==2) ? Wv : Wo;
  u16* WT = (z<3) ? (wqkvT + (size_t)z*DM*DM) : woT;
  int n0 = (w2 & 15) * 64, k0 = (w2 >> 4) * 64;
  int tx = threadIdx.x & 63, ty = threadIdx.x >> 6;
  #pragma unroll
  for (int s = 0; s < 64; s += 4)
    t[ty + s][tx] = W[(size_t)(k0 + ty + s) * DM + n0 + tx];
  __syncthreads();
  #pragma unroll
  for (int s = 0; s < 64; s += 4)
    WT[(size_t)(n0 + ty + s) * DM + k0 + tx] = f2bf(t[tx][ty + s]);
}

// ---------------- 256x256 counted-vmcnt MFMA GEMM (K=1024 fixed) — R3/R10 structure ----------------
// Measured-best: 133.6-134.2 us (QKV), MfmaUtil ~32.5%, 0 bank conflicts. PARKED.
template<int QKV>
__global__ __launch_bounds__(512, 2) void gemm256_kernel(
    const u16* __restrict__ A, const u16* __restrict__ BT,
    const float* __restrict__ biasq, const float* __restrict__ biask, const float* __restrict__ biasv,
    u16* __restrict__ oq, u16* __restrict__ ok, u16* __restrict__ ov,
    float* __restrict__ outf,
    float* __restrict__ sumQ, float* __restrict__ sumK, int NBY)
{
  // LDS: A slot0 [0,32K), A slot1 [32K,64K), B slot0 [64K,96K), B slot1 [96K,128K)
  __shared__ __align__(16) u16 smem[65536];
  char* smb = (char*)smem;
  int tid = threadIdx.x;
  int wave = tid >> 6, lane = tid & 63;
  int wm = wave >> 2, wn = wave & 3;          // 2 x 4 wave grid
  int nwg = gridDim.x;
  int q8 = nwg >> 3;
  int id = blockIdx.x;
  int id2 = (id & 7) * q8 + (id >> 3);
  int bx = id2 / NBY, by = id2 % NBY;
  int m0 = bx * 256, n0 = by * 256;
  int srcq = (tid & 7) ^ ((tid >> 3) & 7);
  const u16* aRow = A  + (size_t)(m0 + (tid >> 3)) * 1024 + srcq * 8;
  const u16* bRow = BT + (size_t)(n0 + (tid >> 3)) * 1024 + srcq * 8;

  f32x4 acc[8][4];
  #pragma unroll
  for (int i=0;i<8;i++)
    #pragma unroll
    for (int j=0;j<4;j++) acc[i][j] = (f32x4){0.f,0.f,0.f,0.f};

  int fr = lane & 15, q = lane >> 4;
  int aoff0 = fr*128 + (((q ^ (lane&3)) + 4*((lane>>2)&1)) << 4);
  int aoff1 = fr*128 + (((q ^ (lane&3)) + 4*(1 ^ ((lane>>2)&1))) << 4);

  #define STAGE(s, t) { \
    _Pragma("unroll") \
    for (int i_ = 0; i_ < 4; i_++){ \
      gload16(aRow + (size_t)(t)*64 + (size_t)i_*65536, smb + (s)*32768 + i_*8192 + tid*16); \
      gload16(bRow + (size_t)(t)*64 + (size_t)i_*65536, smb + 65536 + (s)*32768 + i_*8192 + tid*16); \
    } }

  #define COMPUTE(s) { \
    const char* Ab_ = smb + (s)*32768 + wm*16384; \
    const char* Bb_ = smb + 65536 + (s)*32768 + wn*8192; \
    _Pragma("unroll") \
    for (int kk_ = 0; kk_ < 2; kk_++){ \
      int off_ = kk_ ? aoff1 : aoff0; \
      s16x8 af_[8], bf_[4]; \
      _Pragma("unroll") \
      for (int mi_ = 0; mi_ < 8; mi_++) af_[mi_] = *(const s16x8*)(Ab_ + mi_*2048 + off_); \
      _Pragma("unroll") \
      for (int ni_ = 0; ni_ < 4; ni_++) bf_[ni_] = *(const s16x8*)(Bb_ + ni_*2048 + off_); \
      _Pragma("unroll") \
      for (int mi_ = 0; mi_ < 8; mi_++) \
        _Pragma("unroll") \
        for (int ni_ = 0; ni_ < 4; ni_++) \
          acc[mi_][ni_] = mfma16(af_[mi_], bf_[ni_], acc[mi_][ni_]); \
    } }

  STAGE(0, 0)
  STAGE(1, 1)
  for (int t = 0; t < 14; t++){
    asm volatile("s_waitcnt vmcnt(8)" ::: "memory");
    __builtin_amdgcn_s_barrier();
    asm volatile("" ::: "memory");
    COMPUTE(t & 1)
    asm volatile("s_waitcnt lgkmcnt(0)" ::: "memory");
    __builtin_amdgcn_s_barrier();
    asm volatile("" ::: "memory");
    STAGE(t & 1, t + 2)
  }
  asm volatile("s_waitcnt vmcnt(8)" ::: "memory");
  __builtin_amdgcn_s_barrier();
  asm volatile("" ::: "memory");
  COMPUTE(0)
  asm volatile("s_waitcnt vmcnt(0)" ::: "memory");
  __builtin_amdgcn_s_barrier();
  asm volatile("" ::: "memory");
  COMPUTE(1)

  // epilogue
  int colblk = n0 + wn*64;
  int which  = QKV ? (colblk >> 10) : 0;          // 0=q 1=k 2=v
  int cl0    = QKV ? (colblk & 1023) : colblk;
  const float* bias = QKV ? (which==0 ? biasq : (which==1 ? biask : biasv)) : biasq;
  u16* outp = QKV ? (which==0 ? oq : (which==1 ? ok : ov)) : (u16*)0;
  float cs0[4] = {0.f,0.f,0.f,0.f}, cs1[4] = {0.f,0.f,0.f,0.f};
  #pragma unroll
  for (int mi = 0; mi < 8; mi++){
    int row = m0 + wm*128 + mi*16 + (lane>>4)*4;
    #pragma unroll
    for (int ni = 0; ni < 4; ni++){
      int cl = cl0 + ni*16 + fr;
      float bv = bias[cl];
      #pragma unroll
      for (int r = 0; r < 4; r++){
        float val = acc[mi][ni][r] + bv;
        if (QKV){
          if (which < 2) val = sigmoidf_(val);
          outp[(size_t)(row + r) * 1024 + cl] = f2bf(val);
          if (which < 2){ if (mi < 4) cs0[ni] += val; else cs1[ni] += val; }
        } else {
          outf[(size_t)(row + r) * 1024 + cl] = val;
        }
      }
    }
  }
  if (QKV && which < 2){
    float* sums = (which==0) ? sumQ : sumK;
    int bh = (m0 >> 12) * H_ + ((colblk & 1023) >> 6);
    int sc0 = ((m0 & 4095) >> 6) + wm*2;
    #pragma unroll
    for (int h2 = 0; h2 < 2; h2++){
      #pragma unroll
      for (int ni = 0; ni < 4; ni++){
        float s = h2 ? cs1[ni] : cs0[ni];
        s += __shfl_xor(s, 16);
        s += __shfl_xor(s, 32);
        if (lane < 16) sums[((size_t)bh*NSC + sc0 + h2)*64 + ni*16 + fr] = s;
      }
    }
  }
  #undef STAGE
  #undef COMPUTE
}

// ---------------- fused sink_incoming/source_outgoing + mod chunk sums (R16) ----------------
__global__ __launch_bounds__(128) void siso_fused_kernel(
    const u16* __restrict__ q, const u16* __restrict__ k,
    const float* __restrict__ sumQ, const float* __restrict__ sumK,
    float* __restrict__ si, float* __restrict__ so,
    float* __restrict__ sumQsi, float* __restrict__ sumKso)
{
  __shared__ u16 cq[64*64];
  __shared__ u16 ck[64*64];
  __shared__ float siv[64], sov[64];
  int bhc = blockIdx.x; int bh = bhc >> 6, sc = bhc & 63;
  int b = bh >> 4, h = bh & 15;
  int tid = threadIdx.x, w = tid >> 6, lane = tid & 63;
  size_t gbase = ((size_t)(b*L_ + sc*SC))*DM + h*D_;
  size_t lb = (size_t)bh*L_ + sc*SC;
  const u16* src = w ? k : q;
  u16* ldsT = w ? ck : cq;
  float run = prefix_sum64(w ? sumK : sumQ, bh, sc, lane);
  // P0: stage raw tile, swizzled
  {
    int r8 = lane >> 3, c8 = (lane & 7) * 8;
    #pragma unroll
    for (int j = 0; j < 8; j++){
      int l = j*8 + r8;
      uint4 u = *(const uint4*)(src + gbase + (size_t)l*DM + c8);
      const u16* up = (const u16*)&u;
      #pragma unroll
      for (int e = 0; e < 8; e++)
        ldsT[l*64 + ((c8 + e) ^ (l & 31))] = up[e];
    }
  }
  __syncthreads();
  // P1: column cumsum in place (lane = d)
  {
    for (int l = 0; l < SC; l++){
      int sw = lane ^ (l & 31);
      run += bf2f(ldsT[l*64 + sw]);
      ldsT[l*64 + sw] = f2bf(run);
    }
  }
  __syncthreads();
  // P2: row dots
  uint4 rowreg[8];
  {
    int l = lane;
    const u16* row = src + gbase + (size_t)l*DM;
    #pragma unroll
    for (int j=0;j<8;j++) rowreg[j] = ((const uint4*)row)[j];
    const u16* rp = (const u16*)rowreg;
    const u16* other = w ? cq : ck;
    float acc = 0.f;
    #pragma unroll
    for (int d = 0; d < 64; d++){
      int sw = d ^ (l & 31);
      acc += (bf2f(rp[d])+EPSF) * (bf2f(other[l*64+sw])+EPSF);
    }
    float n = (float)(sc*SC + l + 1);
    float vv = n / acc;
    if (w == 0){ si[lb+l] = vv; siv[l] = vv; }
    else       { so[lb+l] = vv; sov[l] = vv; }
  }
  __syncthreads();
  // P2b: raw rows back over dead cumsums
  {
    int l = lane;
    const u16* rp = (const u16*)rowreg;
    #pragma unroll
    for (int d = 0; d < 64; d++)
      ldsT[l*64 + (d ^ (l & 31))] = rp[d];
  }
  __syncthreads();
  // P3: column mod-sums (lane = d)
  {
    const float* sv = w ? sov : siv;
    float s = 0.f;
    for (int l = 0; l < SC; l++){
      int sw = lane ^ (l & 31);
      s += bf2f(ldsT[l*64 + sw]) * sv[l];
    }
    if (w == 0) sumQsi[bhc*64 + lane] = s;
    else        sumKso[bhc*64 + lane] = s;
  }
}

// ---------------- fused conserved_sink/source -> sall, csrc + exp chunk sums (R16) ----------------
__global__ __launch_bounds__(128) void cons_fused_kernel(
    const u16* __restrict__ q, const u16* __restrict__ k,
    const float* __restrict__ si, const float* __restrict__ so,
    const float* __restrict__ sumQsi, const float* __restrict__ sumKso,
    float* __restrict__ csrc, float* __restrict__ sall, float* __restrict__ csSum)
{
  __shared__ u16 cq[64*64];
  __shared__ u16 ck[64*64];
  __shared__ float siv[64], sov[64];
  int bhc = blockIdx.x; int bh = bhc >> 6, sc = bhc & 63;
  int b = bh >> 4, h = bh & 15;
  int tid = threadIdx.x, w = tid >> 6, lane = tid & 63;
  size_t gbase = ((size_t)(b*L_ + sc*SC))*DM + h*D_;
  size_t lb = (size_t)bh*L_ + sc*SC;
  const u16* src = w ? k : q;
  u16* ldsT = w ? ck : cq;
  if (w == 0) siv[lane] = si[lb + lane];
  else        sov[lane] = so[lb + lane];
  float run = prefix_sum64(w ? sumKso : sumQsi, bh, sc, lane);
  // P0: stage raw tile, swizzled
  {
    int r8 = lane >> 3, c8 = (lane & 7) * 8;
    #pragma unroll
    for (int j = 0; j < 8; j++){
      int l = j*8 + r8;
      uint4 u = *(const uint4*)(src + gbase + (size_t)l*DM + c8);
      const u16* up = (const u16*)&u;
      #pragma unroll
      for (int e = 0; e < 8; e++)
        ldsT[l*64 + ((c8 + e) ^ (l & 31))] = up[e];
    }
  }
  __syncthreads();
  // P1: weighted column cumsum in place
  {
    const float* sv = w ? sov : siv;
    for (int l = 0; l < SC; l++){
      int sw = lane ^ (l & 31);
      run += bf2f(ldsT[l*64 + sw]) * sv[l];
      ldsT[l*64 + sw] = f2bf(run);
    }
  }
  __syncthreads();
  // P2: row dots
  {
    int l = lane;
    const u16* row = src + gbase + (size_t)l*DM;
    uint4 rr[8];
    #pragma unroll
    for (int j=0;j<8;j++) rr[j] = ((const uint4*)row)[j];
    const u16* rp = (const u16*)rr;
    const u16* other = w ? cq : ck;
    float acc = 0.f;
    #pragma unroll
    for (int d = 0; d < 64; d++){
      int sw = d ^ (l & 31);
      acc += (bf2f(rp[d])+EPSF) * (bf2f(other[l*64+sw])+EPSF);
    }
    float inv = 1.0f / (float)(sc*SC + l + 1);
    if (w == 0){
      sall[lb+l] = sigmoidf_(acc * inv);
    } else {
      float cs = acc * inv;
      csrc[lb+l] = cs;
      float e = __expf(cs);
      #pragma unroll
      for (int off = 32; off > 0; off >>= 1) e += __shfl_xor(e, off);
      if (lane == 0) csSum[bhc] = e;
    }
  }
}

// ---------------- per-chunk VK sums via MFMA + scomp fused; bf16 chunk output ----------------
__global__ __launch_bounds__(256) void vk_chunk_kernel(
    const u16* __restrict__ k, const u16* __restrict__ v,
    const float* __restrict__ csrc, const float* __restrict__ csSum,
    float* __restrict__ scomp, u16* __restrict__ vkc16){
  __shared__ __align__(16) u16 vt[64*128];   // (v*scomp)^T [m][l] swz
  __shared__ __align__(16) u16 kt[64*128];   // k^T [d][l] swz
  __shared__ float scmpv[128];
  int bhc = blockIdx.x; int bh = bhc >> 5, c = bhc & 31;
  int b = bh >> 4, h = bh & 15;
  int tid = threadIdx.x, wave = tid >> 6, lane = tid & 63;
  size_t gbase = ((size_t)(b * L_ + c * CS)) * DM + h * D_;
  // Phase A: scmp for scan-chunks sc = 2c + {0,1}
  if (wave < 2){
    int sc = c*2 + wave;
    float v2 = (lane < sc) ? csSum[bh*NSC + lane] : 0.f;
    #pragma unroll
    for (int o = 32; o > 0; o >>= 1) v2 += __shfl_xor(v2, o);
    float off = v2;
    size_t idx = (size_t)bh * L_ + sc * SC + lane;
    float cs = __expf(csrc[idx]);
    float run = cs;
    #pragma unroll
    for (int o = 1; o < 64; o <<= 1){
      float t = __shfl_up(run, o);
      if (lane >= o) run += t;
    }
    float sm = cs / (off + run) * (float)(sc*SC + lane + 1);
    scomp[idx] = sm;
    scmpv[wave*64 + lane] = sm;
  }
  __syncthreads();
  // Phase B: stage transposed tiles (v scaled by scmp from LDS)
  {
    int r = tid >> 1;            // source row l = 0..127
    int cc = (tid & 1) * 32;     // d-half
    float vscale = scmpv[r];
    #pragma unroll
    for (int j = 0; j < 4; j++){
      uint4 ku = *(const uint4*)(k + gbase + (size_t)r * DM + cc + j*8);
      uint4 vu = *(const uint4*)(v + gbase + (size_t)r * DM + cc + j*8);
      const u16* kp = (const u16*)&ku; const u16* vp = (const u16*)&vu;
      #pragma unroll
      for (int e = 0; e < 8; e++){
        int m = cc + j*8 + e;
        int idx = m*128 + ((((r >> 3) ^ (m & 7)) << 3) | (r & 7));
        vt[idx] = f2bf(bf2f(vp[e]) * vscale);
        kt[idx] = kp[e];
      }
    }
  }
  __syncthreads();
  int fr = lane & 15, q = lane >> 4;
  int mt = wave;                 // m-tile (16 rows) per wave
  f32x4 acc[4];
  #pragma unroll
  for (int i = 0; i < 4; i++) acc[i] = (f32x4){0.f,0.f,0.f,0.f};
  #pragma unroll
  for (int ks = 0; ks < 4; ks++){
    int lc = ks*4 + q;           // logical 16B l-chunk
    int off = ((lc ^ (fr & 7)) << 3);
    s16x8 av = *(const s16x8*)&vt[(mt*16 + fr)*128 + off];
    #pragma unroll
    for (int nt = 0; nt < 4; nt++){
      s16x8 bk = *(const s16x8*)&kt[(nt*16 + fr)*128 + off];
      acc[nt] = mfma16(av, bk, acc[nt]);
    }
  }
  u16* outp = vkc16 + (size_t)bhc * (D_*D_);
  #pragma unroll
  for (int nt = 0; nt < 4; nt++)
    #pragma unroll
    for (int r = 0; r < 4; r++)
      outp[(mt*16 + q*4 + r)*64 + nt*16 + fr] = f2bf(acc[nt][r]);
}

// ---------------- exclusive scan of VK over chunks: bf16 in -> bf16 prefix out ----------------
__global__ __launch_bounds__(256) void vk_scan_kernel(const u16* __restrict__ vkc16, u16* __restrict__ vkb){
  int idx = blockIdx.x * 256 + threadIdx.x;   // over BH*4096
  int bh = idx >> 12;
  int e  = idx & 4095;
  size_t base = ((size_t)bh * NC) * 4096 + e;
  float run = 0.f;
  for (int g = 0; g < NC; g += 16){
    u16 tv[16];
    #pragma unroll
    for (int j = 0; j < 16; j++) tv[j] = vkc16[base + (size_t)(g + j) * 4096];
    #pragma unroll
    for (int j = 0; j < 16; j++){
      vkb[base + (size_t)(g + j) * 4096] = f2bf(run);
      run += bf2f(tv[j]);
    }
  }
}

// ---------------- causal attention per (bh, chunk) ----------------
// R13 swizzled tiles + restructured sync: qs is dead after the per-wave aq register
// loads -> reused as the jt2=0 S-strip buffer (ss0). 4 barriers (was 5) and the
// jt2=1 QK compute overlaps the jt2=0 PV (disjoint buffers, no barrier between).
__global__ __launch_bounds__(256) void attn_kernel(
    const u16* __restrict__ q, const u16* __restrict__ k, const u16* __restrict__ v,
    const float* __restrict__ si, const float* __restrict__ scomp, const float* __restrict__ salloc,
    const u16* __restrict__ vkb, u16* __restrict__ attnout)
{
  __shared__ __align__(16) u16 qs[128*64];    // qmod rows [l][d] swz; reused as ss0
  __shared__ __align__(16) u16 ks2[128*64];   // k rows    [j][d] swz
  __shared__ __align__(16) u16 vts[64*128];   // (v*scomp)^T [m][j] swz
  __shared__ __align__(16) u16 vks[64*64];    // VKprev [m][d] swz
  __shared__ __align__(16) u16 ss[128*64];    // S strip for jt2=1 (ss1)
  int bhc = blockIdx.x; int bh = bhc >> 5, c = bhc & 31;
  int b = bh >> 4, h = bh & 15;
  int tid = threadIdx.x, wave = tid >> 6, lane = tid & 63;
  size_t gbase = ((size_t)(b * L_ + c * CS)) * DM + h * D_;
  size_t sbase = (size_t)bh * L_ + c * CS;
  {
    int r = tid >> 1;
    int cc = (tid & 1) * 32;
    int l = c * CS + r;
    float qscale = si[sbase + r] / (float)(l + 1);
    float vscale = scomp[sbase + r];
    #pragma unroll
    for (int j = 0; j < 4; j++){
      int d0 = cc + j*8;
      uint4 qu = *(const uint4*)(q + gbase + (size_t)r * DM + d0);
      uint4 kuv = *(const uint4*)(k + gbase + (size_t)r * DM + d0);
      uint4 vu = *(const uint4*)(v + gbase + (size_t)r * DM + d0);
      const u16* qp = (const u16*)&qu; const u16* vp = (const u16*)&vu;
      u16 tmp[8];
      #pragma unroll
      for (int e = 0; e < 8; e++) tmp[e] = f2bf(bf2f(qp[e]) * qscale);
      int csw = ((d0 >> 3) ^ (r & 7)) << 3;           // swizzled d-chunk
      *(uint4*)&qs[r*64 + csw]  = *(uint4*)tmp;
      *(uint4*)&ks2[r*64 + csw] = kuv;
      #pragma unroll
      for (int e = 0; e < 8; e++){
        int m = d0 + e;
        int jsw = (((r >> 3) ^ (m & 7)) << 3) | (r & 7);  // swizzled j position
        vts[m*128 + jsw] = f2bf(bf2f(vp[e]) * vscale);
      }
    }
    const u16* vkp = vkb + (size_t)bhc * (D_*D_) + tid * 16;
    int m = tid >> 2, dq = (tid & 3) * 2;               // two d-chunks per thread
    int o0 = ((dq     ^ (m & 7)) << 3);
    int o1 = (((dq+1) ^ (m & 7)) << 3);
    *(uint4*)&vks[m*64 + o0] = *(const uint4*)(vkp);
    *(uint4*)&vks[m*64 + o1] = *(const uint4*)(vkp + 8);
  }
  __syncthreads();                 // B0: staging visible
  int t0 = wave, t1 = 7 - wave;    // balanced l-tile pair per wave
  int fr = lane & 15, qh = lane >> 4;
  int f7 = fr & 7;
  f32x4 acc[2][4];
  #pragma unroll
  for (int i=0;i<2;i++)
    #pragma unroll
    for (int j=0;j<4;j++) acc[i][j] = (f32x4){0.f,0.f,0.f,0.f};
  s16x8 aq[2][2];
  #pragma unroll
  for (int ti = 0; ti < 2; ti++){
    int t = ti ? t1 : t0;
    #pragma unroll
    for (int kk = 0; kk < 2; kk++){
      int oc = (((kk*4 + qh) ^ f7) << 3);
      aq[ti][kk] = *(const s16x8*)&qs[(t*16 + fr)*64 + oc];
    }
  }
  __syncthreads();                 // B-A: all aq loads done; qs region now dead
  // inter-chunk MFMA + QK half0 (S -> qs region); scheduler interleaves freely
  #pragma unroll
  for (int mt = 0; mt < 4; mt++){
    #pragma unroll
    for (int kk = 0; kk < 2; kk++){
      int oc = (((kk*4 + qh) ^ f7) << 3);
      s16x8 bv = *(const s16x8*)&vks[(mt*16 + fr)*64 + oc];
      acc[0][mt] = mfma16(aq[0][kk], bv, acc[0][mt]);
      acc[1][mt] = mfma16(aq[1][kk], bv, acc[1][mt]);
    }
  }
  #define QK_HALF(jt2, dst) \
    _Pragma("unroll") \
    for (int ti = 0; ti < 2; ti++){ \
      int t = ti ? t1 : t0; \
      _Pragma("unroll") \
      for (int u = 0; u < 4; u++){ \
        int jj = (jt2)*4 + u; \
        f32x4 sacc = (f32x4){0.f,0.f,0.f,0.f}; \
        if (jj <= t){ \
          _Pragma("unroll") \
          for (int kk = 0; kk < 2; kk++){ \
            int oc = (((kk*4 + qh) ^ f7) << 3); \
            s16x8 bkf = *(const s16x8*)&ks2[(jj*16 + fr)*64 + oc]; \
            sacc = mfma16(aq[ti][kk], bkf, sacc); \
          } \
        } \
        int lrow = t*16 + qh*4; \
        int jcol = jj*16 + fr; \
        int cst = u*2 + (fr >> 3); \
        _Pragma("unroll") \
        for (int r = 0; r < 4; r++){ \
          float sv = (jcol <= lrow + r) ? sacc[r] : 0.f; \
          int row = lrow + r; \
          dst[row*64 + (((cst ^ (row & 7)) << 3) | f7)] = f2bf(sv); \
        } \
      } \
    }
  #define PV_HALF(jt2, srcb) \
    _Pragma("unroll") \
    for (int ti = 0; ti < 2; ti++){ \
      int t = ti ? t1 : t0; \
      _Pragma("unroll") \
      for (int ks = 0; ks < 2; ks++){ \
        if ((jt2)*64 + ks*32 <= t*16 + 15){ \
          int ocs = (((ks*4 + qh) ^ f7) << 3); \
          s16x8 as = *(const s16x8*)&srcb[(t*16 + fr)*64 + ocs]; \
          _Pragma("unroll") \
          for (int mt = 0; mt < 4; mt++){ \
            int lc = (jt2)*8 + ks*4 + qh; \
            int ocv = ((lc ^ f7) << 3); \
            s16x8 bvv = *(const s16x8*)&vts[(mt*16 + fr)*128 + ocv]; \
            acc[ti][mt] = mfma16(as, bvv, acc[ti][mt]); \
          } \
        } \
      } \
    }
  QK_HALF(0, qs)
  __syncthreads();                 // B-B: ss0 (qs region) complete
  QK_HALF(1, ss)                   // overlaps PV0 below (disjoint buffers)
  PV_HALF(0, qs)
  __syncthreads();                 // B-C: ss1 complete, PV0 done
  PV_HALF(1, ss)
  #undef QK_HALF
  #undef PV_HALF
  // epilogue: * sink_allocation, write bf16 [B,L,DM]
  #pragma unroll
  for (int ti = 0; ti < 2; ti++){
    int t = ti ? t1 : t0;
    int lrow = t*16 + qh*4;
    #pragma unroll
    for (int r = 0; r < 4; r++){
      float sa = salloc[sbase + lrow + r];
      size_t orow = ((size_t)(b * L_ + c * CS + lrow + r)) * DM + h * D_;
      #pragma unroll
      for (int mt = 0; mt < 4; mt++){
        attnout[orow + mt*16 + fr] = f2bf(acc[ti][mt][r] * sa);
      }
    }
  }
}

extern "C" void kernel_launch(void* const* d_in, const int* in_sizes, int n_in,
                              void* d_out, int out_size, void* d_ws, size_t ws_size,
                              hipStream_t stream){
  (void)in_sizes; (void)n_in; (void)out_size; (void)ws_size;
  const float* x  = (const float*)d_in[0];
  const float* Wq = (const float*)d_in[1];
  const float* bq = (const float*)d_in[2];
  const float* Wk = (const float*)d_in[3];
  const float* bk = (const float*)d_in[4];
  const float* Wv = (const float*)d_in[5];
  const float* bv = (const float*)d_in[6];
  const float* Wo = (const float*)d_in[7];
  const float* bo = (const float*)d_in[8];

  char* p = (char*)d_ws;
  auto carve = [&](size_t bytes) -> void* {
    void* r = (void*)p; p += (bytes + 255) & ~(size_t)255; return r;
  };
  u16* xb    = (u16*)carve((size_t)N_*DM*2);
  u16* wqkvT = (u16*)carve((size_t)3*DM*DM*2);
  u16* woT   = (u16*)carve((size_t)DM*DM*2);
  u16* qb  = (u16*)carve((size_t)N_*DM*2);
  u16* kb  = (u16*)carve((size_t)N_*DM*2);
  u16* vb  = (u16*)carve((size_t)N_*DM*2);
  u16* ao  = (u16*)carve((size_t)N_*DM*2);
  float* si   = (float*)carve((size_t)BH*L_*4);
  float* so   = (float*)carve((size_t)BH*L_*4);
  float* csrc = (float*)carve((size_t)BH*L_*4);
  float* sall = (float*)carve((size_t)BH*L_*4);
  float* scmp = (float*)carve((size_t)BH*L_*4);
  float* sumQ   = (float*)carve((size_t)BH*NSC*D_*4);
  float* sumK   = (float*)carve((size_t)BH*NSC*D_*4);
  float* sumQsi = (float*)carve((size_t)BH*NSC*D_*4);
  float* sumKso = (float*)carve((size_t)BH*NSC*D_*4);
  float* csSum  = (float*)carve((size_t)BH*NSC*4);
  u16*   vkc16  = (u16*)carve((size_t)BH*NC*(size_t)(D_*D_)*2);
  u16*   vkb    = (u16*)carve((size_t)BH*NC*(size_t)(D_*D_)*2);

  // 1. prep: cvt + 4 weight transposes (one launch)
  prep_kernel<<<16384 + 4*256, 256, 0, stream>>>(x, Wq, Wk, Wv, Wo, xb, wqkvT, woT);
  // 2. fused q,k,v projection (one 16384x3072x1024 GEMM) + per-scan-chunk sums
  gemm256_kernel<1><<<dim3((N_/256)*(3*DM/256)), 512, 0, stream>>>(
      xb, wqkvT, bq, bk, bv, qb, kb, vb, nullptr, sumQ, sumK, 3*DM/256);
  // 3. normalizer pipeline (chunk prefixes inlined)
  siso_fused_kernel<<<BH*NSC, 128, 0, stream>>>(qb, kb, sumQ, sumK, si, so, sumQsi, sumKso);
  cons_fused_kernel<<<BH*NSC, 128, 0, stream>>>(qb, kb, si, so, sumQsi, sumKso, csrc, sall, csSum);
  // 4. causal linear attention (scomp fused into vk_chunk; bf16 VK chain)
  vk_chunk_kernel<<<BH*NC, 256, 0, stream>>>(kb, vb, csrc, csSum, scmp, vkc16);
  vk_scan_kernel<<<(BH*D_*D_)/256, 256, 0, stream>>>(vkc16, vkb);
  attn_kernel<<<BH*NC, 256, 0, stream>>>(qb, kb, vb, si, scmp, sall, vkb, ao);
  // 5. output projection
  gemm256_kernel<0><<<dim3((N_/256)*(DM/256)), 512, 0, stream>>>(
      ao, woT, bo, bo, bo, nullptr, nullptr, nullptr, (float*)d_out, nullptr, nullptr, DM/256);
}